// Round 2
// baseline (6937.094 us; speedup 1.0000x reference)
//
#include <hip/hip_runtime.h>
#include <math.h>

// ---------------------------------------------------------------------------
// CapsuleRoutingSelfAttention — fp32, batch-sequential to keep workspace small.
// B=4, S=Q=K=1024, E=512, H=8, D=64, capsule dim H*K=8192.
//
// Per-batch workspace (floats), reused across the 4 batches:
//   U   [Q,H*K]  8388608   scores in u-layout; later overwritten by w
//   sH  [Q,H*K]  8388608   horizontal routing s/v
//   Qb  [Q,512]   524288
//   Kb  [Q,512]   524288
//   Vb  [Q,512]   524288
//   vV  [Q,1024] 1048576   vertical routing output
//   bH  [Q,Q]    1048576   horizontal routing logits
//   cH  [Q,Q]    1048576   causal softmax of bH
//   ctx [Q,512]   524288
// total = 22,020,096 floats = 84 MiB  (must be <= ws_size)
// ---------------------------------------------------------------------------

#define SQ_EPS 1e-8f

__device__ __forceinline__ float wredSum(float v) {
#pragma unroll
  for (int off = 32; off > 0; off >>= 1) v += __shfl_xor(v, off);
  return v;
}
__device__ __forceinline__ float wredMax(float v) {
#pragma unroll
  for (int off = 32; off > 0; off >>= 1) v = fmaxf(v, __shfl_xor(v, off));
  return v;
}
// block = 256 threads = 4 waves
__device__ __forceinline__ float blockSum(float v, volatile float* red) {
  v = wredSum(v);
  int wid = threadIdx.x >> 6;
  __syncthreads();
  if ((threadIdx.x & 63) == 0) red[wid] = v;
  __syncthreads();
  return red[0] + red[1] + red[2] + red[3];
}
__device__ __forceinline__ float blockMax(float v, volatile float* red) {
  v = wredMax(v);
  int wid = threadIdx.x >> 6;
  __syncthreads();
  if ((threadIdx.x & 63) == 0) red[wid] = v;
  __syncthreads();
  return fmaxf(fmaxf(red[0], red[1]), fmaxf(red[2], red[3]));
}

__global__ __launch_bounds__(256) void fill_zero_kernel(float* __restrict__ p) {
  int i = (blockIdx.x * 256 + threadIdx.x) * 4;
  float4 z = {0.f, 0.f, 0.f, 0.f};
  *(float4*)&p[i] = z;
}

// ---------------------------------------------------------------------------
// Generic tiled fp32 GEMM.  C = alpha * A x op(B) + beta * C (+ bias[col]).
// A is [M,K] row-major (lda). TRANSB=0: B is [K,N] (ldb); TRANSB=1: B is [N,K].
// TRI=0 none; TRI=1: K-loop limited to k < row0+BM (A-cols zero beyond row
// index); TRI=2: skip output blocks entirely above the diagonal.
// blockIdx.z = z2 with per-axis strides sA2/sB2/sC2 (head axis).
// 256 threads as 16x16, each computes TM x TN (TM=BM/16, TN=BN/16).
// All dims divisible by tile sizes for every call here.
// ---------------------------------------------------------------------------
template <int BM, int BN, int BK, bool TRANSB, int TRI>
__global__ __launch_bounds__(256) void gemm_f32(
    const float* __restrict__ A, const float* __restrict__ B,
    float* __restrict__ C, const float* __restrict__ bias,
    int K, int lda, int ldb, int ldc,
    long long sA2, long long sB2, long long sC2, float alpha, float beta) {
  constexpr int TM = BM / 16;
  constexpr int TN = BN / 16;
  constexpr int LA = BM + 4;
  constexpr int LB = BN + 4;
  __shared__ float As[BK][LA];
  __shared__ float Bs[BK][LB];

  int z2 = blockIdx.z;
  A += z2 * sA2;
  B += z2 * sB2;
  C += z2 * sC2;

  int row0 = blockIdx.y * BM;
  int col0 = blockIdx.x * BN;
  if (TRI == 2 && col0 >= row0 + BM) return;

  int tid = (int)threadIdx.x;
  int tx = tid & 15, ty = tid >> 4;

  constexpr int AKC = BK / 4;  // float4 chunks per BK
  int arow = tid / AKC;
  int akc = (tid - arow * AKC) * 4;
  int brow, bcol;
  if constexpr (TRANSB) {
    brow = tid / AKC;
    bcol = (tid - brow * AKC) * 4;
  } else {
    brow = tid / (BN / 4);
    bcol = (tid - brow * (BN / 4)) * 4;
  }

  float acc[TM][TN];
#pragma unroll
  for (int i = 0; i < TM; i++)
#pragma unroll
    for (int j = 0; j < TN; j++) acc[i][j] = 0.f;

  int Kend = (TRI == 1) ? (row0 + BM < K ? row0 + BM : K) : K;

  const float* Aptr = A + (long long)(row0 + arow) * lda + akc;
  const float* Bptr;
  if constexpr (TRANSB)
    Bptr = B + (long long)(col0 + brow) * ldb + bcol;
  else
    Bptr = B + (long long)brow * ldb + col0 + bcol;

  for (int kb = 0; kb < Kend; kb += BK) {
    float4 av = *(const float4*)(Aptr + kb);
    float4 bv;
    if constexpr (TRANSB)
      bv = *(const float4*)(Bptr + kb);
    else
      bv = *(const float4*)(Bptr + (long long)kb * ldb);
    __syncthreads();
    As[akc + 0][arow] = av.x;
    As[akc + 1][arow] = av.y;
    As[akc + 2][arow] = av.z;
    As[akc + 3][arow] = av.w;
    if constexpr (TRANSB) {
      Bs[bcol + 0][brow] = bv.x;
      Bs[bcol + 1][brow] = bv.y;
      Bs[bcol + 2][brow] = bv.z;
      Bs[bcol + 3][brow] = bv.w;
    } else {
      *(float4*)&Bs[brow][bcol] = bv;
    }
    __syncthreads();

#pragma unroll
    for (int k = 0; k < BK; k++) {
      float a[TM], b[TN];
#pragma unroll
      for (int c = 0; c < TM / 4; c++) {
        float4 q = *(float4*)&As[k][ty * TM + c * 4];
        a[c * 4 + 0] = q.x; a[c * 4 + 1] = q.y;
        a[c * 4 + 2] = q.z; a[c * 4 + 3] = q.w;
      }
#pragma unroll
      for (int c = 0; c < TN / 4; c++) {
        float4 q = *(float4*)&Bs[k][c * 64 + tx * 4];
        b[c * 4 + 0] = q.x; b[c * 4 + 1] = q.y;
        b[c * 4 + 2] = q.z; b[c * 4 + 3] = q.w;
      }
#pragma unroll
      for (int i = 0; i < TM; i++)
#pragma unroll
        for (int j = 0; j < TN; j++) acc[i][j] = fmaf(a[i], b[j], acc[i][j]);
    }
  }

#pragma unroll
  for (int i = 0; i < TM; i++) {
    long long r = row0 + ty * TM + i;
#pragma unroll
    for (int c = 0; c < TN / 4; c++) {
      int col = col0 + c * 64 + tx * 4;
      float4 val;
      val.x = alpha * acc[i][c * 4 + 0];
      val.y = alpha * acc[i][c * 4 + 1];
      val.z = alpha * acc[i][c * 4 + 2];
      val.w = alpha * acc[i][c * 4 + 3];
      if (beta != 0.f) {
        float4 old = *(float4*)&C[r * ldc + col];
        val.x += beta * old.x; val.y += beta * old.y;
        val.z += beta * old.z; val.w += beta * old.w;
      }
      if (bias) {
        float4 bb = *(const float4*)&bias[col];
        val.x += bb.x; val.y += bb.y; val.z += bb.z; val.w += bb.w;
      }
      *(float4*)&C[r * ldc + col] = val;
    }
  }
}

// ---------------------------------------------------------------------------
// Vertical routing, fused: one block per q-row. U row (8x1024) in LDS.
// 3 routing iterations in-kernel; writes final v to vV[q,1024].
// ---------------------------------------------------------------------------
__global__ __launch_bounds__(256) void vertical_routing_kernel(
    const float* __restrict__ U, float* __restrict__ vV) {
  __shared__ float Ur[8 * 1024];
  __shared__ float red[4];
  __shared__ float red8[32];
  int bq = blockIdx.x;
  int t = (int)threadIdx.x;
  const float* Ub = U + (long long)bq * 8192;
#pragma unroll
  for (int r = 0; r < 8; r++)
    *(float4*)&Ur[(t + 256 * r) * 4] = *(const float4*)&Ub[(t + 256 * r) * 4];
  __syncthreads();

  float bh[8] = {0.f, 0.f, 0.f, 0.f, 0.f, 0.f, 0.f, 0.f};
  int k0 = t * 4;
  float4 v4 = {0.f, 0.f, 0.f, 0.f};
  for (int it = 0; it < 3; ++it) {
    float m = bh[0];
#pragma unroll
    for (int h = 1; h < 8; h++) m = fmaxf(m, bh[h]);
    float c[8], zz = 0.f;
#pragma unroll
    for (int h = 0; h < 8; h++) {
      c[h] = expf(bh[h] - m);
      zz += c[h];
    }
    float inv = 1.f / zz;
    float4 s4 = {0.f, 0.f, 0.f, 0.f};
#pragma unroll
    for (int h = 0; h < 8; h++) {
      float4 u = *(float4*)&Ur[h * 1024 + k0];
      float ch = c[h] * inv;
      s4.x = fmaf(ch, u.x, s4.x); s4.y = fmaf(ch, u.y, s4.y);
      s4.z = fmaf(ch, u.z, s4.z); s4.w = fmaf(ch, u.w, s4.w);
    }
    float sq =
        blockSum(s4.x * s4.x + s4.y * s4.y + s4.z * s4.z + s4.w * s4.w, red);
    float sc = (sq / (1.f + sq)) / sqrtf(sq + SQ_EPS);
    v4.x = sc * s4.x; v4.y = sc * s4.y; v4.z = sc * s4.z; v4.w = sc * s4.w;
    if (it < 2) {  // last agreement update is dead
      float p[8];
#pragma unroll
      for (int h = 0; h < 8; h++) {
        float4 u = *(float4*)&Ur[h * 1024 + k0];
        p[h] = u.x * v4.x + u.y * v4.y + u.z * v4.z + u.w * v4.w;
      }
      __syncthreads();
#pragma unroll
      for (int h = 0; h < 8; h++) {
        float w = wredSum(p[h]);
        if ((t & 63) == 0) red8[(t >> 6) * 8 + h] = w;
      }
      __syncthreads();
#pragma unroll
      for (int h = 0; h < 8; h++)
        bh[h] += red8[h] + red8[8 + h] + red8[16 + h] + red8[24 + h];
    }
  }
  *(float4*)&vV[(long long)bq * 1024 + k0] = v4;
}

// causal row softmax: cH[i,j] = softmax_{j<=i}(bH[i,j]), zeros for j>i
__global__ __launch_bounds__(256) void softmax_causal_kernel(
    const float* __restrict__ bH, float* __restrict__ cH) {
  __shared__ float red[4];
  int i = blockIdx.x;
  long long base = (long long)i * 1024;
  int t = (int)threadIdx.x, k0 = t * 4;
  float4 x = *(const float4*)&bH[base + k0];
  bool m0 = (k0 + 0) <= i, m1 = (k0 + 1) <= i, m2 = (k0 + 2) <= i,
       m3 = (k0 + 3) <= i;
  float mx = -3.0e38f;
  if (m0) mx = fmaxf(mx, x.x);
  if (m1) mx = fmaxf(mx, x.y);
  if (m2) mx = fmaxf(mx, x.z);
  if (m3) mx = fmaxf(mx, x.w);
  mx = blockMax(mx, red);
  float e0 = m0 ? expf(x.x - mx) : 0.f;
  float e1 = m1 ? expf(x.y - mx) : 0.f;
  float e2 = m2 ? expf(x.z - mx) : 0.f;
  float e3 = m3 ? expf(x.w - mx) : 0.f;
  float zz = blockSum(e0 + e1 + e2 + e3, red);
  float inv = 1.f / zz;
  float4 o = {e0 * inv, e1 * inv, e2 * inv, e3 * inv};
  *(float4*)&cH[base + k0] = o;
}

// squash rows of length 8192 in place
__global__ __launch_bounds__(256) void squash_rows8192_kernel(
    float* __restrict__ Sm) {
  __shared__ float red[4];
  long long base = (long long)blockIdx.x * 8192;
  int t = (int)threadIdx.x;
  float4 vr[8];
  float sq = 0.f;
#pragma unroll
  for (int r = 0; r < 8; r++) {
    vr[r] = *(float4*)&Sm[base + (t + 256 * r) * 4];
    sq += vr[r].x * vr[r].x + vr[r].y * vr[r].y + vr[r].z * vr[r].z +
          vr[r].w * vr[r].w;
  }
  sq = blockSum(sq, red);
  float sc = (sq / (1.f + sq)) / sqrtf(sq + SQ_EPS);
#pragma unroll
  for (int r = 0; r < 8; r++) {
    float4 o = {sc * vr[r].x, sc * vr[r].y, sc * vr[r].z, sc * vr[r].w};
    *(float4*)&Sm[base + (t + 256 * r) * 4] = o;
  }
}

// enhanced = U + vV + vH; w = softmax_k(enhanced); write w into U in place.
// one block per (q,h) row of 1024.
__global__ __launch_bounds__(256) void enh_softmax_kernel(
    float* __restrict__ U, const float* __restrict__ vV,
    const float* __restrict__ vH) {
  __shared__ float red[4];
  int idx = blockIdx.x;  // Q*H
  int h = idx & 7;
  int bq = idx >> 3;
  float* Urow = U + (long long)bq * 8192 + h * 1024;
  const float* va = vV + (long long)bq * 1024;
  const float* vb = vH + (long long)bq * 8192 + h * 1024;
  int t = (int)threadIdx.x, k0 = t * 4;
  float4 x = *(float4*)&Urow[k0];
  float4 a = *(const float4*)&va[k0];
  float4 b = *(const float4*)&vb[k0];
  x.x += a.x + b.x; x.y += a.y + b.y; x.z += a.z + b.z; x.w += a.w + b.w;
  float mx = blockMax(fmaxf(fmaxf(x.x, x.y), fmaxf(x.z, x.w)), red);
  float e0 = expf(x.x - mx), e1 = expf(x.y - mx), e2 = expf(x.z - mx),
        e3 = expf(x.w - mx);
  float zz = blockSum(e0 + e1 + e2 + e3, red);
  float inv = 1.f / zz;
  float4 o = {e0 * inv, e1 * inv, e2 * inv, e3 * inv};
  *(float4*)&Urow[k0] = o;
}

// ---------------------------------------------------------------------------
extern "C" void kernel_launch(void* const* d_in, const int* in_sizes, int n_in,
                              void* d_out, int out_size, void* d_ws,
                              size_t ws_size, hipStream_t stream) {
  (void)in_sizes; (void)n_in; (void)out_size; (void)ws_size;
  const float* x = (const float*)d_in[0];
  const float* Wq = (const float*)d_in[1];
  const float* bq = (const float*)d_in[2];
  const float* Wk = (const float*)d_in[3];
  const float* bk = (const float*)d_in[4];
  const float* Wv = (const float*)d_in[5];
  const float* bv = (const float*)d_in[6];
  const float* Wo = (const float*)d_in[7];
  const float* bo = (const float*)d_in[8];
  float* out = (float*)d_out;
  float* ws = (float*)d_ws;

  float* U = ws;                  //  8388608
  float* sH = ws + 8388608;       //  8388608
  float* Qb = ws + 16777216;      //   524288
  float* Kb = ws + 17301504;      //   524288
  float* Vb = ws + 17825792;      //   524288
  float* vV = ws + 18350080;      //  1048576
  float* bH = ws + 19398656;      //  1048576
  float* cH = ws + 20447232;      //  1048576
  float* ctx = ws + 21495808;     //   524288
  // total 22020096 floats = 84 MiB

  for (int b = 0; b < 4; ++b) {
    const float* xb = x + (long long)b * 524288;

    // 1. QKV projections for this batch: [1024,512] x [512,512] + bias
    gemm_f32<128, 128, 8, false, 0><<<dim3(4, 8, 1), 256, 0, stream>>>(
        xb, Wq, Qb, bq, 512, 512, 512, 512, 0, 0, 0, 1.f, 0.f);
    gemm_f32<128, 128, 8, false, 0><<<dim3(4, 8, 1), 256, 0, stream>>>(
        xb, Wk, Kb, bk, 512, 512, 512, 512, 0, 0, 0, 1.f, 0.f);
    gemm_f32<128, 128, 8, false, 0><<<dim3(4, 8, 1), 256, 0, stream>>>(
        xb, Wv, Vb, bv, 512, 512, 512, 512, 0, 0, 0, 1.f, 0.f);

    // 2. scores into u-layout: U[i,(h,k)] = (1/8) Qb[i,h*64:].Kb[k,h*64:]
    gemm_f32<128, 128, 8, true, 0><<<dim3(8, 8, 8), 256, 0, stream>>>(
        Qb, Kb, U, nullptr, 64, 512, 512, 8192, 64LL, 64LL, 1024LL, 0.125f,
        0.f);

    // 3. vertical routing (3 iters fused) -> vV
    vertical_routing_kernel<<<dim3(1024), 256, 0, stream>>>(U, vV);

    // 4. horizontal routing
    fill_zero_kernel<<<dim3(1024), 256, 0, stream>>>(bH);
    for (int it = 0; it < 3; ++it) {
      softmax_causal_kernel<<<dim3(1024), 256, 0, stream>>>(bH, cH);
      // s = c x u  [M=1024, N=8192, K=1024], causal K-limit
      gemm_f32<128, 128, 8, false, 1><<<dim3(64, 8, 1), 256, 0, stream>>>(
          cH, U, sH, nullptr, 1024, 1024, 8192, 8192, 0, 0, 0, 1.f, 0.f);
      squash_rows8192_kernel<<<dim3(1024), 256, 0, stream>>>(sH);
      if (it < 2) {  // final agreement update is dead
        // bH += v x u^T  [M=1024, N=1024, K=8192], skip above-diagonal blocks
        gemm_f32<64, 64, 16, true, 2><<<dim3(16, 16, 1), 256, 0, stream>>>(
            sH, U, bH, nullptr, 8192, 8192, 8192, 1024, 0, 0, 0, 1.f, 1.f);
      }
    }

    // 5. enhanced + softmax -> w written into U in place
    enh_softmax_kernel<<<dim3(8192), 256, 0, stream>>>(U, vV, sH);

    // 6. ctx[i,(h,d)] = sum_k w[i,(h,k)] * Vb[k,(h,d)]
    gemm_f32<64, 64, 16, false, 0><<<dim3(1, 16, 8), 256, 0, stream>>>(
        U, Vb, ctx, nullptr, 1024, 8192, 512, 512, 1024LL, 64LL, 64LL, 1.f,
        0.f);

    // 7. out = ctx x Wo + bo
    gemm_f32<128, 128, 8, false, 0><<<dim3(4, 8, 1), 256, 0, stream>>>(
        ctx, Wo, out + (long long)b * 524288, bo, 512, 512, 512, 512, 0, 0, 0,
        1.f, 0.f);
  }
}

// Round 3
// 3109.601 us; speedup vs baseline: 2.2309x; 2.2309x over previous
//
#include <hip/hip_runtime.h>
#include <math.h>

// ---------------------------------------------------------------------------
// CapsuleRoutingSelfAttention — batch-sequential; routing GEMMs on bf16 MFMA.
// B=4, S=Q=K=1024, E=512, H=8, D=64, capsule dim H*K=8192.
//
// Per-batch workspace (float units), reused across the 4 batches:
//   U     [Q,8192] f32   8388608   scores in u-layout; later overwritten by w
//   sv16  [Q,8192] bf16  4194304   horizontal routing s/v (bf16)
//   uT16  [8192,Q] bf16  4194304   u transposed, bf16 (MFMA B-operand)
//   Qb    [Q,512]  f32    524288
//   Kb    [Q,512]  f32    524288
//   Vb    [Q,512]  f32    524288
//   vV    [Q,1024] f32   1048576   vertical routing output
//   bH    [Q,Q]    f32   1048576   horizontal routing logits
//   cH16  [Q,Q]    bf16   524288   causal softmax of bH (bf16)
//   ctx   [Q,512]  f32    524288
// total = 21,495,808 floats = 82 MiB
// ---------------------------------------------------------------------------

#define SQ_EPS 1e-8f

typedef __attribute__((ext_vector_type(4))) int i32x4;    // 8 bf16
typedef __attribute__((ext_vector_type(4))) float f32x4;

__device__ __forceinline__ float bf2f(unsigned int u) {
  union { unsigned int i; float f; } x;
  x.i = u << 16;
  return x.f;
}
__device__ __forceinline__ unsigned short f2bf(float f) {
  union { float f; unsigned int i; } x;
  x.f = f;
  unsigned int r = x.i + 0x7fffu + ((x.i >> 16) & 1u);
  return (unsigned short)(r >> 16);
}

__device__ __forceinline__ f32x4 mfma_bf16(i32x4 a, i32x4 b, f32x4 c) {
  asm("v_mfma_f32_16x16x32_bf16 %0, %1, %2, %0" : "+v"(c) : "v"(a), "v"(b));
  return c;
}

__device__ __forceinline__ float wredSum(float v) {
#pragma unroll
  for (int off = 32; off > 0; off >>= 1) v += __shfl_xor(v, off);
  return v;
}
__device__ __forceinline__ float wredMax(float v) {
#pragma unroll
  for (int off = 32; off > 0; off >>= 1) v = fmaxf(v, __shfl_xor(v, off));
  return v;
}
__device__ __forceinline__ float blockSum(float v, volatile float* red) {
  v = wredSum(v);
  int wid = threadIdx.x >> 6;
  __syncthreads();
  if ((threadIdx.x & 63) == 0) red[wid] = v;
  __syncthreads();
  return red[0] + red[1] + red[2] + red[3];
}
__device__ __forceinline__ float blockMax(float v, volatile float* red) {
  v = wredMax(v);
  int wid = threadIdx.x >> 6;
  __syncthreads();
  if ((threadIdx.x & 63) == 0) red[wid] = v;
  __syncthreads();
  return fmaxf(fmaxf(red[0], red[1]), fmaxf(red[2], red[3]));
}

__global__ __launch_bounds__(256) void fill_zero_kernel(float* __restrict__ p) {
  int i = (blockIdx.x * 256 + threadIdx.x) * 4;
  float4 z = {0.f, 0.f, 0.f, 0.f};
  *(float4*)&p[i] = z;
}

// ---------------------------------------------------------------------------
// fp32 tiled GEMM (unchanged from round 1; used for proj/scores/ctx/out).
// ---------------------------------------------------------------------------
template <int BM, int BN, int BK, bool TRANSB, int TRI>
__global__ __launch_bounds__(256) void gemm_f32(
    const float* __restrict__ A, const float* __restrict__ B,
    float* __restrict__ C, const float* __restrict__ bias,
    int K, int lda, int ldb, int ldc,
    long long sA2, long long sB2, long long sC2, float alpha, float beta) {
  constexpr int TM = BM / 16;
  constexpr int TN = BN / 16;
  constexpr int LA = BM + 4;
  constexpr int LB = BN + 4;
  __shared__ float As[BK][LA];
  __shared__ float Bs[BK][LB];

  int z2 = blockIdx.z;
  A += z2 * sA2;
  B += z2 * sB2;
  C += z2 * sC2;

  int row0 = blockIdx.y * BM;
  int col0 = blockIdx.x * BN;
  if (TRI == 2 && col0 >= row0 + BM) return;

  int tid = (int)threadIdx.x;
  int tx = tid & 15, ty = tid >> 4;

  constexpr int AKC = BK / 4;
  int arow = tid / AKC;
  int akc = (tid - arow * AKC) * 4;
  int brow, bcol;
  if constexpr (TRANSB) {
    brow = tid / AKC;
    bcol = (tid - brow * AKC) * 4;
  } else {
    brow = tid / (BN / 4);
    bcol = (tid - brow * (BN / 4)) * 4;
  }

  float acc[TM][TN];
#pragma unroll
  for (int i = 0; i < TM; i++)
#pragma unroll
    for (int j = 0; j < TN; j++) acc[i][j] = 0.f;

  int Kend = (TRI == 1) ? (row0 + BM < K ? row0 + BM : K) : K;

  const float* Aptr = A + (long long)(row0 + arow) * lda + akc;
  const float* Bptr;
  if constexpr (TRANSB)
    Bptr = B + (long long)(col0 + brow) * ldb + bcol;
  else
    Bptr = B + (long long)brow * ldb + col0 + bcol;

  for (int kb = 0; kb < Kend; kb += BK) {
    float4 av = *(const float4*)(Aptr + kb);
    float4 bv;
    if constexpr (TRANSB)
      bv = *(const float4*)(Bptr + kb);
    else
      bv = *(const float4*)(Bptr + (long long)kb * ldb);
    __syncthreads();
    As[akc + 0][arow] = av.x;
    As[akc + 1][arow] = av.y;
    As[akc + 2][arow] = av.z;
    As[akc + 3][arow] = av.w;
    if constexpr (TRANSB) {
      Bs[bcol + 0][brow] = bv.x;
      Bs[bcol + 1][brow] = bv.y;
      Bs[bcol + 2][brow] = bv.z;
      Bs[bcol + 3][brow] = bv.w;
    } else {
      *(float4*)&Bs[brow][bcol] = bv;
    }
    __syncthreads();

#pragma unroll
    for (int k = 0; k < BK; k++) {
      float a[TM], b[TN];
#pragma unroll
      for (int c = 0; c < TM / 4; c++) {
        float4 q = *(float4*)&As[k][ty * TM + c * 4];
        a[c * 4 + 0] = q.x; a[c * 4 + 1] = q.y;
        a[c * 4 + 2] = q.z; a[c * 4 + 3] = q.w;
      }
#pragma unroll
      for (int c = 0; c < TN / 4; c++) {
        float4 q = *(float4*)&Bs[k][c * 64 + tx * 4];
        b[c * 4 + 0] = q.x; b[c * 4 + 1] = q.y;
        b[c * 4 + 2] = q.z; b[c * 4 + 3] = q.w;
      }
#pragma unroll
      for (int i = 0; i < TM; i++)
#pragma unroll
        for (int j = 0; j < TN; j++) acc[i][j] = fmaf(a[i], b[j], acc[i][j]);
    }
  }

#pragma unroll
  for (int i = 0; i < TM; i++) {
    long long r = row0 + ty * TM + i;
#pragma unroll
    for (int c = 0; c < TN / 4; c++) {
      int col = col0 + c * 64 + tx * 4;
      float4 val;
      val.x = alpha * acc[i][c * 4 + 0];
      val.y = alpha * acc[i][c * 4 + 1];
      val.z = alpha * acc[i][c * 4 + 2];
      val.w = alpha * acc[i][c * 4 + 3];
      if (beta != 0.f) {
        float4 old = *(float4*)&C[r * ldc + col];
        val.x += beta * old.x; val.y += beta * old.y;
        val.z += beta * old.z; val.w += beta * old.w;
      }
      if (bias) {
        float4 bb = *(const float4*)&bias[col];
        val.x += bb.x; val.y += bb.y; val.z += bb.z; val.w += bb.w;
      }
      *(float4*)&C[r * ldc + col] = val;
    }
  }
}

// ---------------------------------------------------------------------------
// Transpose U [1024,8192] f32 -> uT16 [8192,1024] bf16. 64x64 tiles via LDS.
// ---------------------------------------------------------------------------
__global__ __launch_bounds__(256) void transpose_bf16_kernel(
    const float* __restrict__ U, unsigned short* __restrict__ uT) {
  __shared__ unsigned short T[64][72];
  int i0 = blockIdx.x * 64;  // 0..960
  int c0 = blockIdx.y * 64;  // 0..8128
  int t = (int)threadIdx.x;
  int r = t >> 2;            // row within tile (i), 0..63
  int q0 = (t & 3) * 16;     // col start (c)
#pragma unroll
  for (int cc = 0; cc < 4; cc++) {
    float4 v = *(const float4*)&U[(long long)(i0 + r) * 8192 + c0 + q0 + cc * 4];
    T[q0 + cc * 4 + 0][r] = f2bf(v.x);
    T[q0 + cc * 4 + 1][r] = f2bf(v.y);
    T[q0 + cc * 4 + 2][r] = f2bf(v.z);
    T[q0 + cc * 4 + 3][r] = f2bf(v.w);
  }
  __syncthreads();
  int orow = t >> 2;
#pragma unroll
  for (int w = 0; w < 2; w++) {
    int oc = ((t & 3) * 2 + w) * 8;
    i32x4 val = *(i32x4*)&T[orow][oc];
    *(i32x4*)&uT[(long long)(c0 + orow) * 1024 + i0 + oc] = val;
  }
}

// ---------------------------------------------------------------------------
// s-GEMM (bf16 MFMA): sv16[i,c] = sum_j cH16[i,j] * u[j,c],   u via uT16[c,j].
// M=1024, N=8192, K=j limited causally to row0+128. Tile 128x128x32, 4 waves.
// ---------------------------------------------------------------------------
__global__ __launch_bounds__(256) void gemm_s_bf16(
    const unsigned short* __restrict__ Abf,   // cH16 [1024,1024]
    const unsigned short* __restrict__ BT,    // uT16 [8192,1024]
    unsigned short* __restrict__ Cout) {      // sv16 [1024,8192]
  __shared__ unsigned short Alds[128][56];    // 112B rows: 16B-aligned, 2-way
  __shared__ unsigned short Blds[128][56];
  int row0 = blockIdx.y * 128;
  int col0 = blockIdx.x * 128;
  int t = (int)threadIdx.x, lane = t & 63, wave = t >> 6;
  int wm = wave >> 1, wn = wave & 1;
  int Kend = row0 + 128;  // causal (<=1024)

  f32x4 acc[4][4];
#pragma unroll
  for (int i = 0; i < 4; i++)
#pragma unroll
    for (int j = 0; j < 4; j++) acc[i][j] = (f32x4){0.f, 0.f, 0.f, 0.f};

  int ar = t >> 2;           // 0..63
  int aq = (t & 3) * 8;      // bf16 chunk start within BK=32

  for (int kb = 0; kb < Kend; kb += 32) {
    i32x4 a0 = *(const i32x4*)&Abf[(long long)(row0 + ar) * 1024 + kb + aq];
    i32x4 a1 = *(const i32x4*)&Abf[(long long)(row0 + ar + 64) * 1024 + kb + aq];
    i32x4 b0 = *(const i32x4*)&BT[(long long)(col0 + ar) * 1024 + kb + aq];
    i32x4 b1 = *(const i32x4*)&BT[(long long)(col0 + ar + 64) * 1024 + kb + aq];
    __syncthreads();
    *(i32x4*)&Alds[ar][aq] = a0;
    *(i32x4*)&Alds[ar + 64][aq] = a1;
    *(i32x4*)&Blds[ar][aq] = b0;
    *(i32x4*)&Blds[ar + 64][aq] = b1;
    __syncthreads();

    int rr = lane & 15, koff = (lane >> 4) * 8;
    i32x4 af[4], bfv[4];
#pragma unroll
    for (int fm = 0; fm < 4; fm++)
      af[fm] = *(i32x4*)&Alds[wm * 64 + fm * 16 + rr][koff];
#pragma unroll
    for (int fn = 0; fn < 4; fn++)
      bfv[fn] = *(i32x4*)&Blds[wn * 64 + fn * 16 + rr][koff];
#pragma unroll
    for (int fm = 0; fm < 4; fm++)
#pragma unroll
      for (int fn = 0; fn < 4; fn++)
        acc[fm][fn] = mfma_bf16(af[fm], bfv[fn], acc[fm][fn]);
  }

  int rq = lane >> 4, rr = lane & 15;
#pragma unroll
  for (int fm = 0; fm < 4; fm++) {
#pragma unroll
    for (int fn = 0; fn < 4; fn++) {
      int col = col0 + wn * 64 + fn * 16 + rr;
#pragma unroll
      for (int r = 0; r < 4; r++) {
        int row = row0 + wm * 64 + fm * 16 + rq * 4 + r;
        Cout[(long long)row * 8192 + col] = f2bf(acc[fm][fn][r]);
      }
    }
  }
}

// ---------------------------------------------------------------------------
// b-update (bf16 MFMA): bH[i,j] += sum_c v[i,c] * u[j,c].
// A = sv16 [1024,8192] row-major; B via uT16 [8192,1024] ([K,N], scatter-staged).
// Tile 64x64x64, 4 waves (each 32x32). Skip blocks above the diagonal.
// ---------------------------------------------------------------------------
__global__ __launch_bounds__(256) void gemm_b_bf16(
    const unsigned short* __restrict__ V,     // sv16 [1024,8192]
    const unsigned short* __restrict__ BT,    // uT16 [8192,1024]
    float* __restrict__ bH) {                 // [1024,1024] +=
  int row0 = blockIdx.y * 64;
  int col0 = blockIdx.x * 64;
  if (col0 > row0) return;
  __shared__ unsigned short Alds[64][88];     // 176B rows: 16B-aligned, 2-way
  __shared__ unsigned short Blds[64][88];
  int t = (int)threadIdx.x, lane = t & 63, wave = t >> 6;
  int wm = wave >> 1, wn = wave & 1;

  f32x4 acc[2][2];
#pragma unroll
  for (int i = 0; i < 2; i++)
#pragma unroll
    for (int j = 0; j < 2; j++) acc[i][j] = (f32x4){0.f, 0.f, 0.f, 0.f};

  int ar = t >> 3;          // 0..31
  int aq = (t & 7) * 8;     // chunk start within 64

  for (int kb = 0; kb < 8192; kb += 64) {
    i32x4 a0 = *(const i32x4*)&V[(long long)(row0 + ar) * 8192 + kb + aq];
    i32x4 a1 = *(const i32x4*)&V[(long long)(row0 + ar + 32) * 8192 + kb + aq];
    i32x4 b0 = *(const i32x4*)&BT[(long long)(kb + ar) * 1024 + col0 + aq];
    i32x4 b1 = *(const i32x4*)&BT[(long long)(kb + ar + 32) * 1024 + col0 + aq];
    __syncthreads();
    *(i32x4*)&Alds[ar][aq] = a0;
    *(i32x4*)&Alds[ar + 32][aq] = a1;
#pragma unroll
    for (int m = 0; m < 8; m++) {
      unsigned int w = (unsigned int)b0[m >> 1];
      Blds[aq + m][ar] = (m & 1) ? (unsigned short)(w >> 16)
                                 : (unsigned short)(w & 0xffff);
    }
#pragma unroll
    for (int m = 0; m < 8; m++) {
      unsigned int w = (unsigned int)b1[m >> 1];
      Blds[aq + m][ar + 32] = (m & 1) ? (unsigned short)(w >> 16)
                                      : (unsigned short)(w & 0xffff);
    }
    __syncthreads();

    int rr = lane & 15, koff = (lane >> 4) * 8;
#pragma unroll
    for (int ks = 0; ks < 2; ks++) {
      i32x4 af0 = *(i32x4*)&Alds[wm * 32 + 0 + rr][ks * 32 + koff];
      i32x4 af1 = *(i32x4*)&Alds[wm * 32 + 16 + rr][ks * 32 + koff];
      i32x4 bf0 = *(i32x4*)&Blds[wn * 32 + 0 + rr][ks * 32 + koff];
      i32x4 bf1 = *(i32x4*)&Blds[wn * 32 + 16 + rr][ks * 32 + koff];
      acc[0][0] = mfma_bf16(af0, bf0, acc[0][0]);
      acc[0][1] = mfma_bf16(af0, bf1, acc[0][1]);
      acc[1][0] = mfma_bf16(af1, bf0, acc[1][0]);
      acc[1][1] = mfma_bf16(af1, bf1, acc[1][1]);
    }
  }

  int rq = lane >> 4, rr = lane & 15;
#pragma unroll
  for (int fm = 0; fm < 2; fm++) {
#pragma unroll
    for (int fn = 0; fn < 2; fn++) {
      int j = col0 + wn * 32 + fn * 16 + rr;
#pragma unroll
      for (int r = 0; r < 4; r++) {
        int i = row0 + wm * 32 + fm * 16 + rq * 4 + r;
        bH[(long long)i * 1024 + j] += acc[fm][fn][r];
      }
    }
  }
}

// ---------------------------------------------------------------------------
// Vertical routing, fused (reads U f32, writes vV f32). Unchanged.
// ---------------------------------------------------------------------------
__global__ __launch_bounds__(256) void vertical_routing_kernel(
    const float* __restrict__ U, float* __restrict__ vV) {
  __shared__ float Ur[8 * 1024];
  __shared__ float red[4];
  __shared__ float red8[32];
  int bq = blockIdx.x;
  int t = (int)threadIdx.x;
  const float* Ub = U + (long long)bq * 8192;
#pragma unroll
  for (int r = 0; r < 8; r++)
    *(float4*)&Ur[(t + 256 * r) * 4] = *(const float4*)&Ub[(t + 256 * r) * 4];
  __syncthreads();

  float bh[8] = {0.f, 0.f, 0.f, 0.f, 0.f, 0.f, 0.f, 0.f};
  int k0 = t * 4;
  float4 v4 = {0.f, 0.f, 0.f, 0.f};
  for (int it = 0; it < 3; ++it) {
    float m = bh[0];
#pragma unroll
    for (int h = 1; h < 8; h++) m = fmaxf(m, bh[h]);
    float c[8], zz = 0.f;
#pragma unroll
    for (int h = 0; h < 8; h++) {
      c[h] = expf(bh[h] - m);
      zz += c[h];
    }
    float inv = 1.f / zz;
    float4 s4 = {0.f, 0.f, 0.f, 0.f};
#pragma unroll
    for (int h = 0; h < 8; h++) {
      float4 u = *(float4*)&Ur[h * 1024 + k0];
      float ch = c[h] * inv;
      s4.x = fmaf(ch, u.x, s4.x); s4.y = fmaf(ch, u.y, s4.y);
      s4.z = fmaf(ch, u.z, s4.z); s4.w = fmaf(ch, u.w, s4.w);
    }
    float sq =
        blockSum(s4.x * s4.x + s4.y * s4.y + s4.z * s4.z + s4.w * s4.w, red);
    float sc = (sq / (1.f + sq)) / sqrtf(sq + SQ_EPS);
    v4.x = sc * s4.x; v4.y = sc * s4.y; v4.z = sc * s4.z; v4.w = sc * s4.w;
    if (it < 2) {
      float p[8];
#pragma unroll
      for (int h = 0; h < 8; h++) {
        float4 u = *(float4*)&Ur[h * 1024 + k0];
        p[h] = u.x * v4.x + u.y * v4.y + u.z * v4.z + u.w * v4.w;
      }
      __syncthreads();
#pragma unroll
      for (int h = 0; h < 8; h++) {
        float w = wredSum(p[h]);
        if ((t & 63) == 0) red8[(t >> 6) * 8 + h] = w;
      }
      __syncthreads();
#pragma unroll
      for (int h = 0; h < 8; h++)
        bh[h] += red8[h] + red8[8 + h] + red8[16 + h] + red8[24 + h];
    }
  }
  *(float4*)&vV[(long long)bq * 1024 + k0] = v4;
}

// causal row softmax: cH16[i,j] = softmax_{j<=i}(bH[i,j]) in bf16, 0 for j>i
__global__ __launch_bounds__(256) void softmax_causal_bf16_kernel(
    const float* __restrict__ bH, unsigned short* __restrict__ cH16) {
  __shared__ float red[4];
  int i = blockIdx.x;
  long long base = (long long)i * 1024;
  int t = (int)threadIdx.x, k0 = t * 4;
  float4 x = *(const float4*)&bH[base + k0];
  bool m0 = (k0 + 0) <= i, m1 = (k0 + 1) <= i, m2 = (k0 + 2) <= i,
       m3 = (k0 + 3) <= i;
  float mx = -3.0e38f;
  if (m0) mx = fmaxf(mx, x.x);
  if (m1) mx = fmaxf(mx, x.y);
  if (m2) mx = fmaxf(mx, x.z);
  if (m3) mx = fmaxf(mx, x.w);
  mx = blockMax(mx, red);
  float e0 = m0 ? expf(x.x - mx) : 0.f;
  float e1 = m1 ? expf(x.y - mx) : 0.f;
  float e2 = m2 ? expf(x.z - mx) : 0.f;
  float e3 = m3 ? expf(x.w - mx) : 0.f;
  float zz = blockSum(e0 + e1 + e2 + e3, red);
  float inv = 1.f / zz;
  unsigned int lo = (unsigned int)f2bf(e0 * inv) |
                    ((unsigned int)f2bf(e1 * inv) << 16);
  unsigned int hi = (unsigned int)f2bf(e2 * inv) |
                    ((unsigned int)f2bf(e3 * inv) << 16);
  uint2 o = {lo, hi};
  *(uint2*)&cH16[base + k0] = o;
}

// squash rows of length 8192 in place, bf16
__global__ __launch_bounds__(256) void squash16_kernel(
    unsigned short* __restrict__ Sm) {
  __shared__ float red[4];
  long long base = (long long)blockIdx.x * 8192;
  int t = (int)threadIdx.x;
  float fv[4][8];
  float sq = 0.f;
#pragma unroll
  for (int r = 0; r < 4; r++) {
    i32x4 pk = *(i32x4*)&Sm[base + (t + 256 * r) * 8];
#pragma unroll
    for (int e = 0; e < 4; e++) {
      unsigned int w = (unsigned int)pk[e];
      float f0 = bf2f(w & 0xffffu), f1 = bf2f(w >> 16);
      fv[r][e * 2 + 0] = f0;
      fv[r][e * 2 + 1] = f1;
      sq += f0 * f0 + f1 * f1;
    }
  }
  sq = blockSum(sq, red);
  float sc = (sq / (1.f + sq)) / sqrtf(sq + SQ_EPS);
#pragma unroll
  for (int r = 0; r < 4; r++) {
    i32x4 pk;
#pragma unroll
    for (int e = 0; e < 4; e++) {
      unsigned int lo = f2bf(sc * fv[r][e * 2 + 0]);
      unsigned int hi = f2bf(sc * fv[r][e * 2 + 1]);
      pk[e] = (int)(lo | (hi << 16));
    }
    *(i32x4*)&Sm[base + (t + 256 * r) * 8] = pk;
  }
}

// enhanced = U + vV + vH16; w = softmax_k(enhanced); write w into U in place.
__global__ __launch_bounds__(256) void enh_softmax_kernel(
    float* __restrict__ U, const float* __restrict__ vV,
    const unsigned short* __restrict__ vH16) {
  __shared__ float red[4];
  int idx = blockIdx.x;  // Q*H
  int h = idx & 7;
  int bq = idx >> 3;
  float* Urow = U + (long long)bq * 8192 + h * 1024;
  const float* va = vV + (long long)bq * 1024;
  const unsigned short* vb = vH16 + (long long)bq * 8192 + h * 1024;
  int t = (int)threadIdx.x, k0 = t * 4;
  float4 x = *(float4*)&Urow[k0];
  float4 a = *(const float4*)&va[k0];
  uint2 pb = *(const uint2*)&vb[k0];
  float b0 = bf2f(pb.x & 0xffffu), b1 = bf2f(pb.x >> 16);
  float b2 = bf2f(pb.y & 0xffffu), b3 = bf2f(pb.y >> 16);
  x.x += a.x + b0; x.y += a.y + b1; x.z += a.z + b2; x.w += a.w + b3;
  float mx = blockMax(fmaxf(fmaxf(x.x, x.y), fmaxf(x.z, x.w)), red);
  float e0 = expf(x.x - mx), e1 = expf(x.y - mx), e2 = expf(x.z - mx),
        e3 = expf(x.w - mx);
  float zz = blockSum(e0 + e1 + e2 + e3, red);
  float inv = 1.f / zz;
  float4 o = {e0 * inv, e1 * inv, e2 * inv, e3 * inv};
  *(float4*)&Urow[k0] = o;
}

// ---------------------------------------------------------------------------
extern "C" void kernel_launch(void* const* d_in, const int* in_sizes, int n_in,
                              void* d_out, int out_size, void* d_ws,
                              size_t ws_size, hipStream_t stream) {
  (void)in_sizes; (void)n_in; (void)out_size; (void)ws_size;
  const float* x = (const float*)d_in[0];
  const float* Wq = (const float*)d_in[1];
  const float* bq = (const float*)d_in[2];
  const float* Wk = (const float*)d_in[3];
  const float* bk = (const float*)d_in[4];
  const float* Wv = (const float*)d_in[5];
  const float* bv = (const float*)d_in[6];
  const float* Wo = (const float*)d_in[7];
  const float* bo = (const float*)d_in[8];
  float* out = (float*)d_out;
  float* ws = (float*)d_ws;

  float* U = ws;                                      //  8388608 f32
  unsigned short* sv16 = (unsigned short*)(ws + 8388608);   // 8388608 bf16
  unsigned short* uT16 = (unsigned short*)(ws + 12582912);  // 8388608 bf16
  float* Qb = ws + 16777216;                          //   524288
  float* Kb = ws + 17301504;                          //   524288
  float* Vb = ws + 17825792;                          //   524288
  float* vV = ws + 18350080;                          //  1048576
  float* bH = ws + 19398656;                          //  1048576
  unsigned short* cH16 = (unsigned short*)(ws + 20447232);  // 1048576 bf16
  float* ctx = ws + 20971520;                         //   524288
  // total 21495808 floats = 82 MiB

  for (int b = 0; b < 4; ++b) {
    const float* xb = x + (long long)b * 524288;

    // 1. QKV projections: [1024,512] x [512,512] + bias
    gemm_f32<128, 128, 8, false, 0><<<dim3(4, 8, 1), 256, 0, stream>>>(
        xb, Wq, Qb, bq, 512, 512, 512, 512, 0, 0, 0, 1.f, 0.f);
    gemm_f32<128, 128, 8, false, 0><<<dim3(4, 8, 1), 256, 0, stream>>>(
        xb, Wk, Kb, bk, 512, 512, 512, 512, 0, 0, 0, 1.f, 0.f);
    gemm_f32<128, 128, 8, false, 0><<<dim3(4, 8, 1), 256, 0, stream>>>(
        xb, Wv, Vb, bv, 512, 512, 512, 512, 0, 0, 0, 1.f, 0.f);

    // 2. scores into u-layout: U[i,(h,k)] = (1/8) Qb[i,h*64:].Kb[k,h*64:]
    gemm_f32<128, 128, 8, true, 0><<<dim3(8, 8, 8), 256, 0, stream>>>(
        Qb, Kb, U, nullptr, 64, 512, 512, 8192, 64LL, 64LL, 1024LL, 0.125f,
        0.f);

    // 3. uT16 = transpose(U) in bf16
    transpose_bf16_kernel<<<dim3(16, 128), 256, 0, stream>>>(U, uT16);

    // 4. vertical routing (3 iters fused) -> vV
    vertical_routing_kernel<<<dim3(1024), 256, 0, stream>>>(U, vV);

    // 5. horizontal routing (bf16 MFMA GEMMs)
    fill_zero_kernel<<<dim3(1024), 256, 0, stream>>>(bH);
    for (int it = 0; it < 3; ++it) {
      softmax_causal_bf16_kernel<<<dim3(1024), 256, 0, stream>>>(bH, cH16);
      gemm_s_bf16<<<dim3(64, 8), 256, 0, stream>>>(cH16, uT16, sv16);
      squash16_kernel<<<dim3(1024), 256, 0, stream>>>(sv16);
      if (it < 2) {
        gemm_b_bf16<<<dim3(16, 16), 256, 0, stream>>>(sv16, uT16, bH);
      }
    }

    // 6. enhanced + softmax -> w written into U in place
    enh_softmax_kernel<<<dim3(8192), 256, 0, stream>>>(U, vV, sv16);

    // 7. ctx[i,(h,d)] = sum_k w[i,(h,k)] * Vb[k,(h,d)]
    gemm_f32<64, 64, 16, false, 0><<<dim3(1, 16, 8), 256, 0, stream>>>(
        U, Vb, ctx, nullptr, 1024, 8192, 512, 512, 1024LL, 64LL, 64LL, 1.f,
        0.f);

    // 8. out = ctx x Wo + bo
    gemm_f32<128, 128, 8, false, 0><<<dim3(4, 8, 1), 256, 0, stream>>>(
        ctx, Wo, out + (long long)b * 524288, bo, 512, 512, 512, 512, 0, 0, 0,
        1.f, 0.f);
  }
}

// Round 4
// 1492.941 us; speedup vs baseline: 4.6466x; 2.0829x over previous
//
#include <hip/hip_runtime.h>
#include <math.h>

// ---------------------------------------------------------------------------
// CapsuleRoutingSelfAttention — bf16-centric restructure.
// B=4, S=Q=K=1024, E=512, H=8, DK=DV=64, capsule dim H*K=8192.
//
// Per-batch workspace (float units), reused across the 4 batches:
//   u16   [1024,8192] bf16  4194304  scores row-major; later w in place
//   uT16  [8192,1024] bf16  4194304  scores transposed (s-GEMM B operand)
//   sv16  [1024,8192] bf16  4194304  horizontal routing s/v
//   Qb    [1024,512]  f32    524288
//   Kb    [1024,512]  f32    524288
//   Vb    [1024,512]  f32    524288
//   VbT16 [512,1024]  bf16   262144
//   vV    [1024,1024] f32   1048576  vertical routing output
//   bH    [1024,1024] f32   1048576  horizontal routing logits
//   p1    [1024,1024] f32   1048576  split-K partial of b-update
//   cH16  [1024,1024] bf16   524288  coupling coefficients
//   ctx   [1024,512]  f32    524288
// total = 18,612,224 floats = 71 MiB (<= proven-safe 84 MiB)
// ---------------------------------------------------------------------------

#define SQ_EPS 1e-8f

typedef __attribute__((ext_vector_type(4))) int i32x4;    // 8 bf16
typedef __attribute__((ext_vector_type(4))) float f32x4;

__device__ __forceinline__ float bf2f(unsigned int u) {
  union { unsigned int i; float f; } x;
  x.i = u << 16;
  return x.f;
}
__device__ __forceinline__ unsigned short f2bf(float f) {
  union { float f; unsigned int i; } x;
  x.f = f;
  unsigned int r = x.i + 0x7fffu + ((x.i >> 16) & 1u);
  return (unsigned short)(r >> 16);
}

__device__ __forceinline__ f32x4 mfma_bf16(i32x4 a, i32x4 b, f32x4 c) {
  asm("v_mfma_f32_16x16x32_bf16 %0, %1, %2, %0" : "+v"(c) : "v"(a), "v"(b));
  return c;
}

__device__ __forceinline__ float wredSum(float v) {
#pragma unroll
  for (int off = 32; off > 0; off >>= 1) v += __shfl_xor(v, off);
  return v;
}
__device__ __forceinline__ float wredMax(float v) {
#pragma unroll
  for (int off = 32; off > 0; off >>= 1) v = fmaxf(v, __shfl_xor(v, off));
  return v;
}
__device__ __forceinline__ float blockSum(float v, volatile float* red) {
  v = wredSum(v);
  int wid = threadIdx.x >> 6;
  __syncthreads();
  if ((threadIdx.x & 63) == 0) red[wid] = v;
  __syncthreads();
  return red[0] + red[1] + red[2] + red[3];
}
__device__ __forceinline__ float blockMax(float v, volatile float* red) {
  v = wredMax(v);
  int wid = threadIdx.x >> 6;
  __syncthreads();
  if ((threadIdx.x & 63) == 0) red[wid] = v;
  __syncthreads();
  return fmaxf(fmaxf(red[0], red[1]), fmaxf(red[2], red[3]));
}

// ---------------------------------------------------------------------------
// fp32 tiled GEMM (projections / out-projection only). C = A*B + bias.
// A [M,K] row-major, B [K,N] row-major. Grid (N/BN, M/BM).
// ---------------------------------------------------------------------------
template <int BM, int BN, int BK>
__global__ __launch_bounds__(256) void gemm_f32(
    const float* __restrict__ A, const float* __restrict__ B,
    float* __restrict__ C, const float* __restrict__ bias,
    int K, int lda, int ldb, int ldc) {
  constexpr int TM = BM / 16;
  constexpr int TN = BN / 16;
  __shared__ float As[BK][BM + 4];
  __shared__ float Bs[BK][BN + 4];

  int row0 = blockIdx.y * BM;
  int col0 = blockIdx.x * BN;
  int tid = (int)threadIdx.x;
  int tx = tid & 15, ty = tid >> 4;

  constexpr int AKC = BK / 4;
  int arow = tid / AKC;
  int akc = (tid - arow * AKC) * 4;
  int brow = tid / (BN / 4);
  int bcol = (tid - brow * (BN / 4)) * 4;

  float acc[TM][TN];
#pragma unroll
  for (int i = 0; i < TM; i++)
#pragma unroll
    for (int j = 0; j < TN; j++) acc[i][j] = 0.f;

  const float* Aptr = A + (long long)(row0 + arow) * lda + akc;
  const float* Bptr = B + (long long)brow * ldb + col0 + bcol;

  for (int kb = 0; kb < K; kb += BK) {
    float4 av = *(const float4*)(Aptr + kb);
    float4 bv = *(const float4*)(Bptr + (long long)kb * ldb);
    __syncthreads();
    As[akc + 0][arow] = av.x;
    As[akc + 1][arow] = av.y;
    As[akc + 2][arow] = av.z;
    As[akc + 3][arow] = av.w;
    *(float4*)&Bs[brow][bcol] = bv;
    __syncthreads();

#pragma unroll
    for (int k = 0; k < BK; k++) {
      float a[TM], b[TN];
#pragma unroll
      for (int c = 0; c < TM / 4; c++) {
        float4 q = *(float4*)&As[k][ty * TM + c * 4];
        a[c * 4 + 0] = q.x; a[c * 4 + 1] = q.y;
        a[c * 4 + 2] = q.z; a[c * 4 + 3] = q.w;
      }
#pragma unroll
      for (int c = 0; c < TN / 4; c++) {
        float4 q = *(float4*)&Bs[k][c * 64 + tx * 4];
        b[c * 4 + 0] = q.x; b[c * 4 + 1] = q.y;
        b[c * 4 + 2] = q.z; b[c * 4 + 3] = q.w;
      }
#pragma unroll
      for (int i = 0; i < TM; i++)
#pragma unroll
        for (int j = 0; j < TN; j++) acc[i][j] = fmaf(a[i], b[j], acc[i][j]);
    }
  }

#pragma unroll
  for (int i = 0; i < TM; i++) {
    long long r = row0 + ty * TM + i;
#pragma unroll
    for (int c = 0; c < TN / 4; c++) {
      int col = col0 + c * 64 + tx * 4;
      float4 val = {acc[i][c * 4 + 0], acc[i][c * 4 + 1], acc[i][c * 4 + 2],
                    acc[i][c * 4 + 3]};
      if (bias) {
        float4 bb = *(const float4*)&bias[col];
        val.x += bb.x; val.y += bb.y; val.z += bb.z; val.w += bb.w;
      }
      *(float4*)&C[r * ldc + col] = val;
    }
  }
}

// ---------------------------------------------------------------------------
// Scores (fp32 compute, bf16 out): u16[i, h*1024+k] = (1/8) q[i,h,:].k[k,h,:]
// A = Qb+h*64 [1024,64] lda 512; B^T = Kb+h*64 [1024,64]; 128x128x8 tile.
// Grid (8, 8, 8=heads).
// ---------------------------------------------------------------------------
__global__ __launch_bounds__(256) void gemm_scores_bf16(
    const float* __restrict__ Qb, const float* __restrict__ Kb,
    unsigned short* __restrict__ u16) {
  __shared__ float As[8][132];
  __shared__ float Bs[8][132];
  int h = blockIdx.z;
  const float* A = Qb + h * 64;
  const float* B = Kb + h * 64;
  unsigned short* C16 = u16 + h * 1024;

  int row0 = blockIdx.y * 128;
  int col0 = blockIdx.x * 128;
  int tid = (int)threadIdx.x;
  int tx = tid & 15, ty = tid >> 4;
  int arow = tid >> 1;
  int akc = (tid & 1) * 4;

  float acc[8][8];
#pragma unroll
  for (int i = 0; i < 8; i++)
#pragma unroll
    for (int j = 0; j < 8; j++) acc[i][j] = 0.f;

  const float* Aptr = A + (long long)(row0 + arow) * 512 + akc;
  const float* Bptr = B + (long long)(col0 + arow) * 512 + akc;

  for (int kb = 0; kb < 64; kb += 8) {
    float4 av = *(const float4*)(Aptr + kb);
    float4 bv = *(const float4*)(Bptr + kb);
    __syncthreads();
    As[akc + 0][arow] = av.x; As[akc + 1][arow] = av.y;
    As[akc + 2][arow] = av.z; As[akc + 3][arow] = av.w;
    Bs[akc + 0][arow] = bv.x; Bs[akc + 1][arow] = bv.y;
    Bs[akc + 2][arow] = bv.z; Bs[akc + 3][arow] = bv.w;
    __syncthreads();

#pragma unroll
    for (int k = 0; k < 8; k++) {
      float a[8], b[8];
#pragma unroll
      for (int c = 0; c < 2; c++) {
        float4 q = *(float4*)&As[k][ty * 8 + c * 4];
        a[c * 4 + 0] = q.x; a[c * 4 + 1] = q.y;
        a[c * 4 + 2] = q.z; a[c * 4 + 3] = q.w;
      }
#pragma unroll
      for (int c = 0; c < 2; c++) {
        float4 q = *(float4*)&Bs[k][c * 64 + tx * 4];
        b[c * 4 + 0] = q.x; b[c * 4 + 1] = q.y;
        b[c * 4 + 2] = q.z; b[c * 4 + 3] = q.w;
      }
#pragma unroll
      for (int i = 0; i < 8; i++)
#pragma unroll
        for (int j = 0; j < 8; j++) acc[i][j] = fmaf(a[i], b[j], acc[i][j]);
    }
  }

#pragma unroll
  for (int i = 0; i < 8; i++) {
    long long r = row0 + ty * 8 + i;
#pragma unroll
    for (int c = 0; c < 2; c++) {
      int col = col0 + c * 64 + tx * 4;
      unsigned int lo = (unsigned int)f2bf(0.125f * acc[i][c * 4 + 0]) |
                        ((unsigned int)f2bf(0.125f * acc[i][c * 4 + 1]) << 16);
      unsigned int hi = (unsigned int)f2bf(0.125f * acc[i][c * 4 + 2]) |
                        ((unsigned int)f2bf(0.125f * acc[i][c * 4 + 3]) << 16);
      uint2 o = {lo, hi};
      *(uint2*)&C16[r * 8192 + col] = o;
    }
  }
}

// ---------------------------------------------------------------------------
// bf16 -> bf16 transpose, 64x64 tiles. src [R,C] ldS -> dst [C,R] ldD.
// ---------------------------------------------------------------------------
__global__ __launch_bounds__(256) void transpose16_kernel(
    const unsigned short* __restrict__ src, unsigned short* __restrict__ dst,
    int ldS, int ldD) {
  __shared__ unsigned short T[64][72];
  int i0 = blockIdx.x * 64;
  int c0 = blockIdx.y * 64;
  int t = (int)threadIdx.x;
  int r = t >> 2, cq = (t & 3) * 16;
  i32x4 v0 = *(const i32x4*)&src[(long long)(i0 + r) * ldS + c0 + cq];
  i32x4 v1 = *(const i32x4*)&src[(long long)(i0 + r) * ldS + c0 + cq + 8];
  *(i32x4*)&T[r][cq] = v0;
  *(i32x4*)&T[r][cq + 8] = v1;
  __syncthreads();
  int c = t >> 2, iq = (t & 3) * 16;
  unsigned short tmp[16];
#pragma unroll
  for (int j = 0; j < 16; j++) tmp[j] = T[iq + j][c];
  *(i32x4*)&dst[(long long)(c0 + c) * ldD + i0 + iq] = *(i32x4*)&tmp[0];
  *(i32x4*)&dst[(long long)(c0 + c) * ldD + i0 + iq + 8] = *(i32x4*)&tmp[8];
}

// f32 -> bf16 transpose, 64x64 tiles. src [R,C] ldS -> dst bf16 [C,R] ldD.
__global__ __launch_bounds__(256) void transpose_f32_bf16_kernel(
    const float* __restrict__ src, unsigned short* __restrict__ dst,
    int ldS, int ldD) {
  __shared__ unsigned short T[64][72];
  int i0 = blockIdx.x * 64;
  int c0 = blockIdx.y * 64;
  int t = (int)threadIdx.x;
  int r = t >> 2, cq = (t & 3) * 16;
#pragma unroll
  for (int j = 0; j < 4; j++) {
    float4 v = *(const float4*)&src[(long long)(i0 + r) * ldS + c0 + cq + j * 4];
    T[r][cq + j * 4 + 0] = f2bf(v.x);
    T[r][cq + j * 4 + 1] = f2bf(v.y);
    T[r][cq + j * 4 + 2] = f2bf(v.z);
    T[r][cq + j * 4 + 3] = f2bf(v.w);
  }
  __syncthreads();
  int c = t >> 2, iq = (t & 3) * 16;
  unsigned short tmp[16];
#pragma unroll
  for (int j = 0; j < 16; j++) tmp[j] = T[iq + j][c];
  *(i32x4*)&dst[(long long)(c0 + c) * ldD + i0 + iq] = *(i32x4*)&tmp[0];
  *(i32x4*)&dst[(long long)(c0 + c) * ldD + i0 + iq + 8] = *(i32x4*)&tmp[8];
}

// ---------------------------------------------------------------------------
// s-GEMM (bf16 MFMA): sv16[i,c] = sum_j cH16[i,j] * u[j,c]  (u via uT16[c,j]).
// Tile 128x128x32, 4 waves; causal K-limit Kend = row0+128. Grid (64, 8).
// ---------------------------------------------------------------------------
__global__ __launch_bounds__(256) void gemm_s_bf16(
    const unsigned short* __restrict__ Abf,   // cH16 [1024,1024]
    const unsigned short* __restrict__ BT,    // uT16 [8192,1024]
    unsigned short* __restrict__ Cout) {      // sv16 [1024,8192]
  __shared__ unsigned short Alds[128][56];
  __shared__ unsigned short Blds[128][56];
  int row0 = blockIdx.y * 128;
  int col0 = blockIdx.x * 128;
  int t = (int)threadIdx.x, lane = t & 63, wave = t >> 6;
  int wm = wave >> 1, wn = wave & 1;
  int Kend = row0 + 128;

  f32x4 acc[4][4];
#pragma unroll
  for (int i = 0; i < 4; i++)
#pragma unroll
    for (int j = 0; j < 4; j++) acc[i][j] = (f32x4){0.f, 0.f, 0.f, 0.f};

  int ar = t >> 2;
  int aq = (t & 3) * 8;

  for (int kb = 0; kb < Kend; kb += 32) {
    i32x4 a0 = *(const i32x4*)&Abf[(long long)(row0 + ar) * 1024 + kb + aq];
    i32x4 a1 = *(const i32x4*)&Abf[(long long)(row0 + ar + 64) * 1024 + kb + aq];
    i32x4 b0 = *(const i32x4*)&BT[(long long)(col0 + ar) * 1024 + kb + aq];
    i32x4 b1 = *(const i32x4*)&BT[(long long)(col0 + ar + 64) * 1024 + kb + aq];
    __syncthreads();
    *(i32x4*)&Alds[ar][aq] = a0;
    *(i32x4*)&Alds[ar + 64][aq] = a1;
    *(i32x4*)&Blds[ar][aq] = b0;
    *(i32x4*)&Blds[ar + 64][aq] = b1;
    __syncthreads();

    int rr = lane & 15, koff = (lane >> 4) * 8;
    i32x4 af[4], bfv[4];
#pragma unroll
    for (int fm = 0; fm < 4; fm++)
      af[fm] = *(i32x4*)&Alds[wm * 64 + fm * 16 + rr][koff];
#pragma unroll
    for (int fn = 0; fn < 4; fn++)
      bfv[fn] = *(i32x4*)&Blds[wn * 64 + fn * 16 + rr][koff];
#pragma unroll
    for (int fm = 0; fm < 4; fm++)
#pragma unroll
      for (int fn = 0; fn < 4; fn++)
        acc[fm][fn] = mfma_bf16(af[fm], bfv[fn], acc[fm][fn]);
  }

  int rq = lane >> 4, rr = lane & 15;
#pragma unroll
  for (int fm = 0; fm < 4; fm++) {
#pragma unroll
    for (int fn = 0; fn < 4; fn++) {
      int col = col0 + wn * 64 + fn * 16 + rr;
#pragma unroll
      for (int r = 0; r < 4; r++) {
        int row = row0 + wm * 64 + fm * 16 + rq * 4 + r;
        Cout[(long long)row * 8192 + col] = f2bf(acc[fm][fn][r]);
      }
    }
  }
}

// ---------------------------------------------------------------------------
// b-update (bf16 MFMA, split-K=2): bH[i,j] (+)= sum_c v[i,c]*u[j,c].
// A = sv16 [1024,8192]; B = u16 [1024,8192] (both [*,K] row-major: clean).
// Tile 64x64x64, 4 waves (32x32 each). ks=0 -> bH (BETA), ks=1 -> p1 (store).
// Grid (16, 16, 2); skip blocks above the diagonal.
// ---------------------------------------------------------------------------
template <int BETA>
__global__ __launch_bounds__(256) void gemm_b_bf16(
    const unsigned short* __restrict__ A, const unsigned short* __restrict__ Bm,
    float* __restrict__ bH, float* __restrict__ p1) {
  int row0 = blockIdx.y * 64;
  int col0 = blockIdx.x * 64;
  if (col0 > row0) return;
  int ks = blockIdx.z;
  __shared__ unsigned short Asl[64][68];
  __shared__ unsigned short Bsl[64][68];
  int t = (int)threadIdx.x, lane = t & 63, wave = t >> 6;
  int wm = wave >> 1, wn = wave & 1;

  f32x4 acc[2][2];
#pragma unroll
  for (int i = 0; i < 2; i++)
#pragma unroll
    for (int j = 0; j < 2; j++) acc[i][j] = (f32x4){0.f, 0.f, 0.f, 0.f};

  int r = t >> 2, kq = (t & 3) * 8;
  const unsigned short* Ap = A + (long long)(row0 + r) * 8192 + ks * 4096 + kq;
  const unsigned short* Bp = Bm + (long long)(col0 + r) * 8192 + ks * 4096 + kq;

  for (int kb = 0; kb < 4096; kb += 64) {
    i32x4 a0 = *(const i32x4*)(Ap + kb);
    i32x4 a1 = *(const i32x4*)(Ap + kb + 32);
    i32x4 b0 = *(const i32x4*)(Bp + kb);
    i32x4 b1 = *(const i32x4*)(Bp + kb + 32);
    __syncthreads();
    *(i32x4*)&Asl[r][kq] = a0;
    *(i32x4*)&Asl[r][kq + 32] = a1;
    *(i32x4*)&Bsl[r][kq] = b0;
    *(i32x4*)&Bsl[r][kq + 32] = b1;
    __syncthreads();

    int rr = lane & 15, ko = (lane >> 4) * 8;
#pragma unroll
    for (int k2 = 0; k2 < 2; k2++) {
      i32x4 af0 = *(i32x4*)&Asl[wm * 32 + rr][k2 * 32 + ko];
      i32x4 af1 = *(i32x4*)&Asl[wm * 32 + 16 + rr][k2 * 32 + ko];
      i32x4 bf0 = *(i32x4*)&Bsl[wn * 32 + rr][k2 * 32 + ko];
      i32x4 bf1 = *(i32x4*)&Bsl[wn * 32 + 16 + rr][k2 * 32 + ko];
      acc[0][0] = mfma_bf16(af0, bf0, acc[0][0]);
      acc[0][1] = mfma_bf16(af0, bf1, acc[0][1]);
      acc[1][0] = mfma_bf16(af1, bf0, acc[1][0]);
      acc[1][1] = mfma_bf16(af1, bf1, acc[1][1]);
    }
  }

  float* dst = (ks == 0) ? bH : p1;
  int rq = lane >> 4, rr = lane & 15;
#pragma unroll
  for (int fm = 0; fm < 2; fm++) {
#pragma unroll
    for (int fn = 0; fn < 2; fn++) {
      int j = col0 + wn * 32 + fn * 16 + rr;
#pragma unroll
      for (int rl = 0; rl < 4; rl++) {
        int i = row0 + wm * 32 + fm * 16 + rq * 4 + rl;
        if (BETA == 1 && ks == 0)
          dst[(long long)i * 1024 + j] += acc[fm][fn][rl];
        else
          dst[(long long)i * 1024 + j] = acc[fm][fn][rl];
      }
    }
  }
}

// ---------------------------------------------------------------------------
// ctx (bf16 MFMA): ctx[i, h*64+d] = sum_k w16[i,h*1024+k] * VbT16[h*64+d, k].
// Tile 64(M)x64(N=full head)x64(K); 4 waves split M. Grid (16, 8=heads).
// ---------------------------------------------------------------------------
__global__ __launch_bounds__(256) void gemm_ctx_bf16(
    const unsigned short* __restrict__ w16,
    const unsigned short* __restrict__ VT, float* __restrict__ ctx) {
  int row0 = blockIdx.x * 64;
  int h = blockIdx.y;
  __shared__ unsigned short Asl[64][68];
  __shared__ unsigned short Bsl[64][68];
  int t = (int)threadIdx.x, lane = t & 63, wave = t >> 6;

  f32x4 acc[4];
#pragma unroll
  for (int i = 0; i < 4; i++) acc[i] = (f32x4){0.f, 0.f, 0.f, 0.f};

  int r = t >> 2, kq = (t & 3) * 8;
  const unsigned short* Ap = w16 + (long long)(row0 + r) * 8192 + h * 1024 + kq;
  const unsigned short* Bp = VT + (long long)(h * 64 + r) * 1024 + kq;

  for (int kb = 0; kb < 1024; kb += 64) {
    i32x4 a0 = *(const i32x4*)(Ap + kb);
    i32x4 a1 = *(const i32x4*)(Ap + kb + 32);
    i32x4 b0 = *(const i32x4*)(Bp + kb);
    i32x4 b1 = *(const i32x4*)(Bp + kb + 32);
    __syncthreads();
    *(i32x4*)&Asl[r][kq] = a0;
    *(i32x4*)&Asl[r][kq + 32] = a1;
    *(i32x4*)&Bsl[r][kq] = b0;
    *(i32x4*)&Bsl[r][kq + 32] = b1;
    __syncthreads();

    int rr = lane & 15, ko = (lane >> 4) * 8;
#pragma unroll
    for (int k2 = 0; k2 < 2; k2++) {
      i32x4 af = *(i32x4*)&Asl[wave * 16 + rr][k2 * 32 + ko];
#pragma unroll
      for (int fn = 0; fn < 4; fn++) {
        i32x4 bf = *(i32x4*)&Bsl[fn * 16 + rr][k2 * 32 + ko];
        acc[fn] = mfma_bf16(af, bf, acc[fn]);
      }
    }
  }

  int rq = lane >> 4, rr = lane & 15;
#pragma unroll
  for (int fn = 0; fn < 4; fn++) {
#pragma unroll
    for (int rl = 0; rl < 4; rl++) {
      int i = row0 + wave * 16 + rq * 4 + rl;
      ctx[(long long)i * 512 + h * 64 + fn * 16 + rr] = acc[fn][rl];
    }
  }
}

// ---------------------------------------------------------------------------
// Vertical routing (reads bf16 u, fused 3 iters) -> vV f32.
// ---------------------------------------------------------------------------
__global__ __launch_bounds__(256) void vertical_routing_kernel(
    const unsigned short* __restrict__ u16, float* __restrict__ vV) {
  __shared__ float Ur[8 * 1024];
  __shared__ float red[4];
  __shared__ float red8[32];
  int bq = blockIdx.x;
  int t = (int)threadIdx.x;
  const unsigned short* Ub = u16 + (long long)bq * 8192;
#pragma unroll
  for (int r = 0; r < 8; r++) {
    uint2 p = *(const uint2*)&Ub[(t + 256 * r) * 4];
    Ur[(t + 256 * r) * 4 + 0] = bf2f(p.x & 0xffffu);
    Ur[(t + 256 * r) * 4 + 1] = bf2f(p.x >> 16);
    Ur[(t + 256 * r) * 4 + 2] = bf2f(p.y & 0xffffu);
    Ur[(t + 256 * r) * 4 + 3] = bf2f(p.y >> 16);
  }
  __syncthreads();

  float bh[8] = {0.f, 0.f, 0.f, 0.f, 0.f, 0.f, 0.f, 0.f};
  int k0 = t * 4;
  float4 v4 = {0.f, 0.f, 0.f, 0.f};
  for (int it = 0; it < 3; ++it) {
    float m = bh[0];
#pragma unroll
    for (int h = 1; h < 8; h++) m = fmaxf(m, bh[h]);
    float c[8], zz = 0.f;
#pragma unroll
    for (int h = 0; h < 8; h++) {
      c[h] = expf(bh[h] - m);
      zz += c[h];
    }
    float inv = 1.f / zz;
    float4 s4 = {0.f, 0.f, 0.f, 0.f};
#pragma unroll
    for (int h = 0; h < 8; h++) {
      float4 u = *(float4*)&Ur[h * 1024 + k0];
      float ch = c[h] * inv;
      s4.x = fmaf(ch, u.x, s4.x); s4.y = fmaf(ch, u.y, s4.y);
      s4.z = fmaf(ch, u.z, s4.z); s4.w = fmaf(ch, u.w, s4.w);
    }
    float sq =
        blockSum(s4.x * s4.x + s4.y * s4.y + s4.z * s4.z + s4.w * s4.w, red);
    float sc = (sq / (1.f + sq)) / sqrtf(sq + SQ_EPS);
    v4.x = sc * s4.x; v4.y = sc * s4.y; v4.z = sc * s4.z; v4.w = sc * s4.w;
    if (it < 2) {
      float p[8];
#pragma unroll
      for (int h = 0; h < 8; h++) {
        float4 u = *(float4*)&Ur[h * 1024 + k0];
        p[h] = u.x * v4.x + u.y * v4.y + u.z * v4.z + u.w * v4.w;
      }
      __syncthreads();
#pragma unroll
      for (int h = 0; h < 8; h++) {
        float w = wredSum(p[h]);
        if ((t & 63) == 0) red8[(t >> 6) * 8 + h] = w;
      }
      __syncthreads();
#pragma unroll
      for (int h = 0; h < 8; h++)
        bh[h] += red8[h] + red8[8 + h] + red8[16 + h] + red8[24 + h];
    }
  }
  *(float4*)&vV[(long long)bq * 1024 + k0] = v4;
}

// it=0 coupling: cH16[i,j] = 1/(i+1) for j<=i else 0 (softmax of zeros).
__global__ __launch_bounds__(256) void softmax_uniform_kernel(
    unsigned short* __restrict__ cH16) {
  int i = blockIdx.x;
  int t = (int)threadIdx.x, k0 = t * 4;
  unsigned short c = f2bf(1.f / (float)(i + 1));
  unsigned short e0 = (k0 + 0) <= i ? c : (unsigned short)0;
  unsigned short e1 = (k0 + 1) <= i ? c : (unsigned short)0;
  unsigned short e2 = (k0 + 2) <= i ? c : (unsigned short)0;
  unsigned short e3 = (k0 + 3) <= i ? c : (unsigned short)0;
  uint2 o = {(unsigned int)e0 | ((unsigned int)e1 << 16),
             (unsigned int)e2 | ((unsigned int)e3 << 16)};
  *(uint2*)&cH16[(long long)i * 1024 + k0] = o;
}

// bH += p1 (masked j<=i), then cH16 = causal softmax(bH).
__global__ __launch_bounds__(256) void add_softmax_kernel(
    float* __restrict__ bH, const float* __restrict__ p1,
    unsigned short* __restrict__ cH16) {
  __shared__ float red[4];
  int i = blockIdx.x;
  long long base = (long long)i * 1024;
  int t = (int)threadIdx.x, k0 = t * 4;
  float4 x = *(const float4*)&bH[base + k0];
  float4 p = *(const float4*)&p1[base + k0];
  bool m0 = (k0 + 0) <= i, m1 = (k0 + 1) <= i, m2 = (k0 + 2) <= i,
       m3 = (k0 + 3) <= i;
  if (m0) x.x += p.x;
  if (m1) x.y += p.y;
  if (m2) x.z += p.z;
  if (m3) x.w += p.w;
  *(float4*)&bH[base + k0] = x;
  float mx = -3.0e38f;
  if (m0) mx = fmaxf(mx, x.x);
  if (m1) mx = fmaxf(mx, x.y);
  if (m2) mx = fmaxf(mx, x.z);
  if (m3) mx = fmaxf(mx, x.w);
  mx = blockMax(mx, red);
  float e0 = m0 ? expf(x.x - mx) : 0.f;
  float e1 = m1 ? expf(x.y - mx) : 0.f;
  float e2 = m2 ? expf(x.z - mx) : 0.f;
  float e3 = m3 ? expf(x.w - mx) : 0.f;
  float zz = blockSum(e0 + e1 + e2 + e3, red);
  float inv = 1.f / zz;
  uint2 o = {(unsigned int)f2bf(e0 * inv) | ((unsigned int)f2bf(e1 * inv) << 16),
             (unsigned int)f2bf(e2 * inv) | ((unsigned int)f2bf(e3 * inv) << 16)};
  *(uint2*)&cH16[base + k0] = o;
}

// squash rows of length 8192 in place, bf16
__global__ __launch_bounds__(256) void squash16_kernel(
    unsigned short* __restrict__ Sm) {
  __shared__ float red[4];
  long long base = (long long)blockIdx.x * 8192;
  int t = (int)threadIdx.x;
  float fv[4][8];
  float sq = 0.f;
#pragma unroll
  for (int r = 0; r < 4; r++) {
    i32x4 pk = *(i32x4*)&Sm[base + (t + 256 * r) * 8];
#pragma unroll
    for (int e = 0; e < 4; e++) {
      unsigned int w = (unsigned int)pk[e];
      float f0 = bf2f(w & 0xffffu), f1 = bf2f(w >> 16);
      fv[r][e * 2 + 0] = f0;
      fv[r][e * 2 + 1] = f1;
      sq += f0 * f0 + f1 * f1;
    }
  }
  sq = blockSum(sq, red);
  float sc = (sq / (1.f + sq)) / sqrtf(sq + SQ_EPS);
#pragma unroll
  for (int r = 0; r < 4; r++) {
    i32x4 pk;
#pragma unroll
    for (int e = 0; e < 4; e++) {
      unsigned int lo = f2bf(sc * fv[r][e * 2 + 0]);
      unsigned int hi = f2bf(sc * fv[r][e * 2 + 1]);
      pk[e] = (int)(lo | (hi << 16));
    }
    *(i32x4*)&Sm[base + (t + 256 * r) * 8] = pk;
  }
}

// enhanced = u16 + vV + sv16; w = softmax_k(enhanced) -> u16 in place (bf16).
__global__ __launch_bounds__(256) void enh_softmax_kernel(
    unsigned short* __restrict__ u16, const float* __restrict__ vV,
    const unsigned short* __restrict__ vH16) {
  __shared__ float red[4];
  int idx = blockIdx.x;  // Q*H
  int h = idx & 7;
  int bq = idx >> 3;
  unsigned short* Urow = u16 + (long long)bq * 8192 + h * 1024;
  const float* va = vV + (long long)bq * 1024;
  const unsigned short* vb = vH16 + (long long)bq * 8192 + h * 1024;
  int t = (int)threadIdx.x, k0 = t * 4;
  uint2 pu = *(const uint2*)&Urow[k0];
  float4 a = *(const float4*)&va[k0];
  uint2 pb = *(const uint2*)&vb[k0];
  float x0 = bf2f(pu.x & 0xffffu) + a.x + bf2f(pb.x & 0xffffu);
  float x1 = bf2f(pu.x >> 16) + a.y + bf2f(pb.x >> 16);
  float x2 = bf2f(pu.y & 0xffffu) + a.z + bf2f(pb.y & 0xffffu);
  float x3 = bf2f(pu.y >> 16) + a.w + bf2f(pb.y >> 16);
  float mx = blockMax(fmaxf(fmaxf(x0, x1), fmaxf(x2, x3)), red);
  float e0 = expf(x0 - mx), e1 = expf(x1 - mx), e2 = expf(x2 - mx),
        e3 = expf(x3 - mx);
  float zz = blockSum(e0 + e1 + e2 + e3, red);
  float inv = 1.f / zz;
  uint2 o = {(unsigned int)f2bf(e0 * inv) | ((unsigned int)f2bf(e1 * inv) << 16),
             (unsigned int)f2bf(e2 * inv) | ((unsigned int)f2bf(e3 * inv) << 16)};
  *(uint2*)&Urow[k0] = o;
}

// ---------------------------------------------------------------------------
extern "C" void kernel_launch(void* const* d_in, const int* in_sizes, int n_in,
                              void* d_out, int out_size, void* d_ws,
                              size_t ws_size, hipStream_t stream) {
  (void)in_sizes; (void)n_in; (void)out_size; (void)ws_size;
  const float* x = (const float*)d_in[0];
  const float* Wq = (const float*)d_in[1];
  const float* bq = (const float*)d_in[2];
  const float* Wk = (const float*)d_in[3];
  const float* bk = (const float*)d_in[4];
  const float* Wv = (const float*)d_in[5];
  const float* bv = (const float*)d_in[6];
  const float* Wo = (const float*)d_in[7];
  const float* bo = (const float*)d_in[8];
  float* out = (float*)d_out;
  float* ws = (float*)d_ws;

  unsigned short* u16 = (unsigned short*)(ws);              // 4194304 fl
  unsigned short* uT16 = (unsigned short*)(ws + 4194304);   // 4194304 fl
  unsigned short* sv16 = (unsigned short*)(ws + 8388608);   // 4194304 fl
  float* Qb = ws + 12582912;                                //  524288
  float* Kb = ws + 13107200;                                //  524288
  float* Vb = ws + 13631488;                                //  524288
  unsigned short* VbT16 = (unsigned short*)(ws + 14155776); //  262144 fl
  float* vV = ws + 14417920;                                // 1048576
  float* bH = ws + 15466496;                                // 1048576
  float* p1 = ws + 16515072;                                // 1048576
  unsigned short* cH16 = (unsigned short*)(ws + 17563648);  //  524288 fl
  float* ctx = ws + 18087936;                               //  524288
  // total 18612224 floats = 71 MiB

  for (int b = 0; b < 4; ++b) {
    const float* xb = x + (long long)b * 524288;

    // 1. QKV projections: [1024,512]x[512,512]+bias, 64x64 tiles (128 blocks)
    gemm_f32<64, 64, 16><<<dim3(8, 16), 256, 0, stream>>>(
        xb, Wq, Qb, bq, 512, 512, 512, 512);
    gemm_f32<64, 64, 16><<<dim3(8, 16), 256, 0, stream>>>(
        xb, Wk, Kb, bk, 512, 512, 512, 512);
    gemm_f32<64, 64, 16><<<dim3(8, 16), 256, 0, stream>>>(
        xb, Wv, Vb, bv, 512, 512, 512, 512);

    // 2. scores -> u16 bf16 (fp32 compute)
    gemm_scores_bf16<<<dim3(8, 8, 8), 256, 0, stream>>>(Qb, Kb, u16);

    // 3. transposes: uT16 = u16^T ; VbT16 = Vb^T (bf16)
    transpose16_kernel<<<dim3(16, 128), 256, 0, stream>>>(u16, uT16, 8192,
                                                          1024);
    transpose_f32_bf16_kernel<<<dim3(16, 8), 256, 0, stream>>>(Vb, VbT16, 512,
                                                               1024);

    // 4. vertical routing -> vV
    vertical_routing_kernel<<<dim3(1024), 256, 0, stream>>>(u16, vV);

    // 5. horizontal routing
    // it 0: c uniform; bH fresh-store
    softmax_uniform_kernel<<<dim3(1024), 256, 0, stream>>>(cH16);
    gemm_s_bf16<<<dim3(64, 8), 256, 0, stream>>>(cH16, uT16, sv16);
    squash16_kernel<<<dim3(1024), 256, 0, stream>>>(sv16);
    gemm_b_bf16<0><<<dim3(16, 16, 2), 256, 0, stream>>>(sv16, u16, bH, p1);
    // it 1
    add_softmax_kernel<<<dim3(1024), 256, 0, stream>>>(bH, p1, cH16);
    gemm_s_bf16<<<dim3(64, 8), 256, 0, stream>>>(cH16, uT16, sv16);
    squash16_kernel<<<dim3(1024), 256, 0, stream>>>(sv16);
    gemm_b_bf16<1><<<dim3(16, 16, 2), 256, 0, stream>>>(sv16, u16, bH, p1);
    // it 2
    add_softmax_kernel<<<dim3(1024), 256, 0, stream>>>(bH, p1, cH16);
    gemm_s_bf16<<<dim3(64, 8), 256, 0, stream>>>(cH16, uT16, sv16);
    squash16_kernel<<<dim3(1024), 256, 0, stream>>>(sv16);

    // 6. enhanced + softmax -> w bf16 into u16 in place
    enh_softmax_kernel<<<dim3(8192), 256, 0, stream>>>(u16, vV, sv16);

    // 7. ctx = w x V (bf16 MFMA)
    gemm_ctx_bf16<<<dim3(16, 8), 256, 0, stream>>>(u16, VbT16, ctx);

    // 8. out = ctx x Wo + bo
    gemm_f32<64, 64, 16><<<dim3(8, 16), 256, 0, stream>>>(
        ctx, Wo, out + (long long)b * 524288, bo, 512, 512, 512, 512);
  }
}

// Round 5
// 1133.250 us; speedup vs baseline: 6.1214x; 1.3174x over previous
//
#include <hip/hip_runtime.h>
#include <math.h>

// ---------------------------------------------------------------------------
// CapsuleRoutingSelfAttention — round 5.
// B=4, S=Q=K=1024, E=512, H=8, DK=DV=64, capsule dim H*K=8192.
//
// Per-batch workspace (float units):
//   u16   [1024,8192] bf16  4194304   scores row-major; later w in place
//   uT16  [8192,1024] bf16  4194304
//   sv16  [1024,8192] bf16  4194304   raw s (squash scale applied downstream)
//   Qb/Kb/Vb [1024,512] f32 3x524288
//   VbT16 [512,1024]  bf16   262144
//   vV    [1024,1024] f32   1048576
//   bH    [1024,1024] f32   1048576
//   P     [4][1024,1024] f32 4194304  split-K partials of b-update
//   cH16  [1024,1024] bf16   524288
//   ctx   [1024,512]  f32    524288
//   scl   [1024]      f32      1024   squash row scales
// total = 21,758,976 floats = 83.0 MiB (<= proven-safe 84 MiB)
// ---------------------------------------------------------------------------

#define SQ_EPS 1e-8f

typedef __attribute__((ext_vector_type(4))) int i32x4;    // 8 bf16
typedef __attribute__((ext_vector_type(4))) float f32x4;

__device__ __forceinline__ float bf2f(unsigned int u) {
  union { unsigned int i; float f; } x;
  x.i = u << 16;
  return x.f;
}
__device__ __forceinline__ unsigned short f2bf(float f) {
  union { float f; unsigned int i; } x;
  x.f = f;
  unsigned int r = x.i + 0x7fffu + ((x.i >> 16) & 1u);
  return (unsigned short)(r >> 16);
}

__device__ __forceinline__ f32x4 mfma_bf16(i32x4 a, i32x4 b, f32x4 c) {
  asm("v_mfma_f32_16x16x32_bf16 %0, %1, %2, %0" : "+v"(c) : "v"(a), "v"(b));
  return c;
}

__device__ __forceinline__ float wredSum(float v) {
#pragma unroll
  for (int off = 32; off > 0; off >>= 1) v += __shfl_xor(v, off);
  return v;
}
__device__ __forceinline__ float wredMax(float v) {
#pragma unroll
  for (int off = 32; off > 0; off >>= 1) v = fmaxf(v, __shfl_xor(v, off));
  return v;
}
__device__ __forceinline__ float blockSum(float v, volatile float* red) {
  v = wredSum(v);
  int wid = threadIdx.x >> 6;
  __syncthreads();
  if ((threadIdx.x & 63) == 0) red[wid] = v;
  __syncthreads();
  return red[0] + red[1] + red[2] + red[3];
}
__device__ __forceinline__ float blockMax(float v, volatile float* red) {
  v = wredMax(v);
  int wid = threadIdx.x >> 6;
  __syncthreads();
  if ((threadIdx.x & 63) == 0) red[wid] = v;
  __syncthreads();
  return fmaxf(fmaxf(red[0], red[1]), fmaxf(red[2], red[3]));
}

// ---------------------------------------------------------------------------
// Fused QKV projection, fp32. z selects (W, bias, dst). 64x64x16 tiles.
// ---------------------------------------------------------------------------
__global__ __launch_bounds__(256) void gemm_qkv_f32(
    const float* __restrict__ x, const float* __restrict__ Wq,
    const float* __restrict__ Wk, const float* __restrict__ Wv,
    const float* __restrict__ bq, const float* __restrict__ bk,
    const float* __restrict__ bv, float* __restrict__ Q,
    float* __restrict__ K, float* __restrict__ V) {
  constexpr int BM = 64, BN = 64, BK = 16, TM = 4, TN = 4;
  __shared__ float As[BK][BM + 4];
  __shared__ float Bs[BK][BN + 4];
  int z = blockIdx.z;
  const float* B = (z == 0) ? Wq : (z == 1) ? Wk : Wv;
  const float* bias = (z == 0) ? bq : (z == 1) ? bk : bv;
  float* C = (z == 0) ? Q : (z == 1) ? K : V;

  int row0 = blockIdx.y * BM;
  int col0 = blockIdx.x * BN;
  int tid = (int)threadIdx.x;
  int tx = tid & 15, ty = tid >> 4;
  int arow = tid >> 2;
  int akc = (tid & 3) * 4;
  int brow = tid >> 4;
  int bcol = (tid & 15) * 4;

  float acc[TM][TN];
#pragma unroll
  for (int i = 0; i < TM; i++)
#pragma unroll
    for (int j = 0; j < TN; j++) acc[i][j] = 0.f;

  const float* Aptr = x + (long long)(row0 + arow) * 512 + akc;
  const float* Bptr = B + (long long)brow * 512 + col0 + bcol;

  for (int kb = 0; kb < 512; kb += BK) {
    float4 av = *(const float4*)(Aptr + kb);
    float4 bv4 = *(const float4*)(Bptr + (long long)kb * 512);
    __syncthreads();
    As[akc + 0][arow] = av.x; As[akc + 1][arow] = av.y;
    As[akc + 2][arow] = av.z; As[akc + 3][arow] = av.w;
    *(float4*)&Bs[brow][bcol] = bv4;
    __syncthreads();
#pragma unroll
    for (int k = 0; k < BK; k++) {
      float a[TM], b[TN];
      float4 qa = *(float4*)&As[k][ty * TM];
      a[0] = qa.x; a[1] = qa.y; a[2] = qa.z; a[3] = qa.w;
      float4 qb = *(float4*)&Bs[k][tx * 4];
      b[0] = qb.x; b[1] = qb.y; b[2] = qb.z; b[3] = qb.w;
#pragma unroll
      for (int i = 0; i < TM; i++)
#pragma unroll
        for (int j = 0; j < TN; j++) acc[i][j] = fmaf(a[i], b[j], acc[i][j]);
    }
  }

#pragma unroll
  for (int i = 0; i < TM; i++) {
    long long r = row0 + ty * TM + i;
    int col = col0 + tx * 4;
    float4 bb = *(const float4*)&bias[col];
    float4 val = {acc[i][0] + bb.x, acc[i][1] + bb.y, acc[i][2] + bb.z,
                  acc[i][3] + bb.w};
    *(float4*)&C[r * 512 + col] = val;
  }
}

// ---------------------------------------------------------------------------
// fp32 tiled GEMM (out-projection). C = A*B + bias. 64x64x16.
// ---------------------------------------------------------------------------
template <int BM, int BN, int BK>
__global__ __launch_bounds__(256) void gemm_f32(
    const float* __restrict__ A, const float* __restrict__ B,
    float* __restrict__ C, const float* __restrict__ bias,
    int K, int lda, int ldb, int ldc) {
  constexpr int TM = BM / 16;
  constexpr int TN = BN / 16;
  __shared__ float As[BK][BM + 4];
  __shared__ float Bs[BK][BN + 4];

  int row0 = blockIdx.y * BM;
  int col0 = blockIdx.x * BN;
  int tid = (int)threadIdx.x;
  int tx = tid & 15, ty = tid >> 4;

  constexpr int AKC = BK / 4;
  int arow = tid / AKC;
  int akc = (tid - arow * AKC) * 4;
  int brow = tid / (BN / 4);
  int bcol = (tid - brow * (BN / 4)) * 4;

  float acc[TM][TN];
#pragma unroll
  for (int i = 0; i < TM; i++)
#pragma unroll
    for (int j = 0; j < TN; j++) acc[i][j] = 0.f;

  const float* Aptr = A + (long long)(row0 + arow) * lda + akc;
  const float* Bptr = B + (long long)brow * ldb + col0 + bcol;

  for (int kb = 0; kb < K; kb += BK) {
    float4 av = *(const float4*)(Aptr + kb);
    float4 bv = *(const float4*)(Bptr + (long long)kb * ldb);
    __syncthreads();
    As[akc + 0][arow] = av.x;
    As[akc + 1][arow] = av.y;
    As[akc + 2][arow] = av.z;
    As[akc + 3][arow] = av.w;
    *(float4*)&Bs[brow][bcol] = bv;
    __syncthreads();

#pragma unroll
    for (int k = 0; k < BK; k++) {
      float a[TM], b[TN];
#pragma unroll
      for (int c = 0; c < TM / 4; c++) {
        float4 q = *(float4*)&As[k][ty * TM + c * 4];
        a[c * 4 + 0] = q.x; a[c * 4 + 1] = q.y;
        a[c * 4 + 2] = q.z; a[c * 4 + 3] = q.w;
      }
#pragma unroll
      for (int c = 0; c < TN / 4; c++) {
        float4 q = *(float4*)&Bs[k][c * 64 + tx * 4];
        b[c * 4 + 0] = q.x; b[c * 4 + 1] = q.y;
        b[c * 4 + 2] = q.z; b[c * 4 + 3] = q.w;
      }
#pragma unroll
      for (int i = 0; i < TM; i++)
#pragma unroll
        for (int j = 0; j < TN; j++) acc[i][j] = fmaf(a[i], b[j], acc[i][j]);
    }
  }

#pragma unroll
  for (int i = 0; i < TM; i++) {
    long long r = row0 + ty * TM + i;
#pragma unroll
    for (int c = 0; c < TN / 4; c++) {
      int col = col0 + c * 64 + tx * 4;
      float4 val = {acc[i][c * 4 + 0], acc[i][c * 4 + 1], acc[i][c * 4 + 2],
                    acc[i][c * 4 + 3]};
      if (bias) {
        float4 bb = *(const float4*)&bias[col];
        val.x += bb.x; val.y += bb.y; val.z += bb.z; val.w += bb.w;
      }
      *(float4*)&C[r * ldc + col] = val;
    }
  }
}

// ---------------------------------------------------------------------------
// Scores (fp32 compute, bf16 out): u16[i, h*1024+k] = (1/8) q[i,h,:].k[k,h,:]
// ---------------------------------------------------------------------------
__global__ __launch_bounds__(256) void gemm_scores_bf16(
    const float* __restrict__ Qb, const float* __restrict__ Kb,
    unsigned short* __restrict__ u16) {
  __shared__ float As[8][132];
  __shared__ float Bs[8][132];
  int h = blockIdx.z;
  const float* A = Qb + h * 64;
  const float* B = Kb + h * 64;
  unsigned short* C16 = u16 + h * 1024;

  int row0 = blockIdx.y * 128;
  int col0 = blockIdx.x * 128;
  int tid = (int)threadIdx.x;
  int tx = tid & 15, ty = tid >> 4;
  int arow = tid >> 1;
  int akc = (tid & 1) * 4;

  float acc[8][8];
#pragma unroll
  for (int i = 0; i < 8; i++)
#pragma unroll
    for (int j = 0; j < 8; j++) acc[i][j] = 0.f;

  const float* Aptr = A + (long long)(row0 + arow) * 512 + akc;
  const float* Bptr = B + (long long)(col0 + arow) * 512 + akc;

  for (int kb = 0; kb < 64; kb += 8) {
    float4 av = *(const float4*)(Aptr + kb);
    float4 bv = *(const float4*)(Bptr + kb);
    __syncthreads();
    As[akc + 0][arow] = av.x; As[akc + 1][arow] = av.y;
    As[akc + 2][arow] = av.z; As[akc + 3][arow] = av.w;
    Bs[akc + 0][arow] = bv.x; Bs[akc + 1][arow] = bv.y;
    Bs[akc + 2][arow] = bv.z; Bs[akc + 3][arow] = bv.w;
    __syncthreads();

#pragma unroll
    for (int k = 0; k < 8; k++) {
      float a[8], b[8];
#pragma unroll
      for (int c = 0; c < 2; c++) {
        float4 q = *(float4*)&As[k][ty * 8 + c * 4];
        a[c * 4 + 0] = q.x; a[c * 4 + 1] = q.y;
        a[c * 4 + 2] = q.z; a[c * 4 + 3] = q.w;
      }
#pragma unroll
      for (int c = 0; c < 2; c++) {
        float4 q = *(float4*)&Bs[k][c * 64 + tx * 4];
        b[c * 4 + 0] = q.x; b[c * 4 + 1] = q.y;
        b[c * 4 + 2] = q.z; b[c * 4 + 3] = q.w;
      }
#pragma unroll
      for (int i = 0; i < 8; i++)
#pragma unroll
        for (int j = 0; j < 8; j++) acc[i][j] = fmaf(a[i], b[j], acc[i][j]);
    }
  }

#pragma unroll
  for (int i = 0; i < 8; i++) {
    long long r = row0 + ty * 8 + i;
#pragma unroll
    for (int c = 0; c < 2; c++) {
      int col = col0 + c * 64 + tx * 4;
      unsigned int lo = (unsigned int)f2bf(0.125f * acc[i][c * 4 + 0]) |
                        ((unsigned int)f2bf(0.125f * acc[i][c * 4 + 1]) << 16);
      unsigned int hi = (unsigned int)f2bf(0.125f * acc[i][c * 4 + 2]) |
                        ((unsigned int)f2bf(0.125f * acc[i][c * 4 + 3]) << 16);
      uint2 o = {lo, hi};
      *(uint2*)&C16[r * 8192 + col] = o;
    }
  }
}

// ---------------------------------------------------------------------------
// bf16 -> bf16 transpose, 64x64 tiles.
// ---------------------------------------------------------------------------
__global__ __launch_bounds__(256) void transpose16_kernel(
    const unsigned short* __restrict__ src, unsigned short* __restrict__ dst,
    int ldS, int ldD) {
  __shared__ unsigned short T[64][72];
  int i0 = blockIdx.x * 64;
  int c0 = blockIdx.y * 64;
  int t = (int)threadIdx.x;
  int r = t >> 2, cq = (t & 3) * 16;
  i32x4 v0 = *(const i32x4*)&src[(long long)(i0 + r) * ldS + c0 + cq];
  i32x4 v1 = *(const i32x4*)&src[(long long)(i0 + r) * ldS + c0 + cq + 8];
  *(i32x4*)&T[r][cq] = v0;
  *(i32x4*)&T[r][cq + 8] = v1;
  __syncthreads();
  int c = t >> 2, iq = (t & 3) * 16;
  unsigned short tmp[16];
#pragma unroll
  for (int j = 0; j < 16; j++) tmp[j] = T[iq + j][c];
  *(i32x4*)&dst[(long long)(c0 + c) * ldD + i0 + iq] = *(i32x4*)&tmp[0];
  *(i32x4*)&dst[(long long)(c0 + c) * ldD + i0 + iq + 8] = *(i32x4*)&tmp[8];
}

// f32 -> bf16 transpose, 64x64 tiles.
__global__ __launch_bounds__(256) void transpose_f32_bf16_kernel(
    const float* __restrict__ src, unsigned short* __restrict__ dst,
    int ldS, int ldD) {
  __shared__ unsigned short T[64][72];
  int i0 = blockIdx.x * 64;
  int c0 = blockIdx.y * 64;
  int t = (int)threadIdx.x;
  int r = t >> 2, cq = (t & 3) * 16;
#pragma unroll
  for (int j = 0; j < 4; j++) {
    float4 v = *(const float4*)&src[(long long)(i0 + r) * ldS + c0 + cq + j * 4];
    T[r][cq + j * 4 + 0] = f2bf(v.x);
    T[r][cq + j * 4 + 1] = f2bf(v.y);
    T[r][cq + j * 4 + 2] = f2bf(v.z);
    T[r][cq + j * 4 + 3] = f2bf(v.w);
  }
  __syncthreads();
  int c = t >> 2, iq = (t & 3) * 16;
  unsigned short tmp[16];
#pragma unroll
  for (int j = 0; j < 16; j++) tmp[j] = T[iq + j][c];
  *(i32x4*)&dst[(long long)(c0 + c) * ldD + i0 + iq] = *(i32x4*)&tmp[0];
  *(i32x4*)&dst[(long long)(c0 + c) * ldD + i0 + iq + 8] = *(i32x4*)&tmp[8];
}

// ---------------------------------------------------------------------------
// s-GEMM (bf16 MFMA): sv16[i,c] = sum_j cH16[i,j]*u[j,c]  (u via uT16[c,j]).
// Tile 128x128x32, 4 waves; causal Kend=row0+128; descending row-blocks.
// Unpadded LDS [128][32] (uniform bank spread). Grid (64, 8).
// ---------------------------------------------------------------------------
__global__ __launch_bounds__(256) void gemm_s_bf16(
    const unsigned short* __restrict__ Abf,   // cH16 [1024,1024]
    const unsigned short* __restrict__ BT,    // uT16 [8192,1024]
    unsigned short* __restrict__ Cout) {      // sv16 [1024,8192]
  __shared__ unsigned short Alds[128][32];
  __shared__ unsigned short Blds[128][32];
  int rowblk = 7 - (int)blockIdx.y;  // big-K blocks dispatched first
  int row0 = rowblk * 128;
  int col0 = blockIdx.x * 128;
  int t = (int)threadIdx.x, lane = t & 63, wave = t >> 6;
  int wm = wave >> 1, wn = wave & 1;
  int Kend = row0 + 128;

  f32x4 acc[4][4];
#pragma unroll
  for (int i = 0; i < 4; i++)
#pragma unroll
    for (int j = 0; j < 4; j++) acc[i][j] = (f32x4){0.f, 0.f, 0.f, 0.f};

  int ar = t >> 2;
  int aq = (t & 3) * 8;

  for (int kb = 0; kb < Kend; kb += 32) {
    i32x4 a0 = *(const i32x4*)&Abf[(long long)(row0 + ar) * 1024 + kb + aq];
    i32x4 a1 = *(const i32x4*)&Abf[(long long)(row0 + ar + 64) * 1024 + kb + aq];
    i32x4 b0 = *(const i32x4*)&BT[(long long)(col0 + ar) * 1024 + kb + aq];
    i32x4 b1 = *(const i32x4*)&BT[(long long)(col0 + ar + 64) * 1024 + kb + aq];
    __syncthreads();
    *(i32x4*)&Alds[ar][aq] = a0;
    *(i32x4*)&Alds[ar + 64][aq] = a1;
    *(i32x4*)&Blds[ar][aq] = b0;
    *(i32x4*)&Blds[ar + 64][aq] = b1;
    __syncthreads();

    int rr = lane & 15, koff = (lane >> 4) * 8;
    i32x4 af[4], bfv[4];
#pragma unroll
    for (int fm = 0; fm < 4; fm++)
      af[fm] = *(i32x4*)&Alds[wm * 64 + fm * 16 + rr][koff];
#pragma unroll
    for (int fn = 0; fn < 4; fn++)
      bfv[fn] = *(i32x4*)&Blds[wn * 64 + fn * 16 + rr][koff];
#pragma unroll
    for (int fm = 0; fm < 4; fm++)
#pragma unroll
      for (int fn = 0; fn < 4; fn++)
        acc[fm][fn] = mfma_bf16(af[fm], bfv[fn], acc[fm][fn]);
  }

  int rq = lane >> 4, rr = lane & 15;
#pragma unroll
  for (int fm = 0; fm < 4; fm++) {
#pragma unroll
    for (int fn = 0; fn < 4; fn++) {
      int col = col0 + wn * 64 + fn * 16 + rr;
#pragma unroll
      for (int r = 0; r < 4; r++) {
        int row = row0 + wm * 64 + fm * 16 + rq * 4 + r;
        Cout[(long long)row * 8192 + col] = f2bf(acc[fm][fn][r]);
      }
    }
  }
}

// ---------------------------------------------------------------------------
// Row sum-of-squares of raw s -> squash scale scl[i].
// ---------------------------------------------------------------------------
__global__ __launch_bounds__(256) void rowsumsq_kernel(
    const unsigned short* __restrict__ Sm, float* __restrict__ scl) {
  __shared__ float red[4];
  long long base = (long long)blockIdx.x * 8192;
  int t = (int)threadIdx.x;
  float sq = 0.f;
#pragma unroll
  for (int r = 0; r < 4; r++) {
    i32x4 pk = *(const i32x4*)&Sm[base + (t + 256 * r) * 8];
#pragma unroll
    for (int e = 0; e < 4; e++) {
      unsigned int w = (unsigned int)pk[e];
      float f0 = bf2f(w & 0xffffu), f1 = bf2f(w >> 16);
      sq += f0 * f0 + f1 * f1;
    }
  }
  sq = blockSum(sq, red);
  if (t == 0) scl[blockIdx.x] = (sq / (1.f + sq)) / sqrtf(sq + SQ_EPS);
}

// ---------------------------------------------------------------------------
// b-update (bf16 MFMA, split-K=4, pure store): P[ks][i,j] = scl[i] *
//   sum_{c in chunk ks} s[i,c]*u[j,c].  Both operands [*,8192] row-major.
// Tile 64x64x64, 4 waves. XOR chunk swizzle on unpadded [64][64] LDS.
// Grid (16, 16, 4); skip blocks above the diagonal.
// ---------------------------------------------------------------------------
__global__ __launch_bounds__(256) void gemm_b_bf16(
    const unsigned short* __restrict__ A,     // sv16 raw s
    const unsigned short* __restrict__ Bm,    // u16
    const float* __restrict__ scl, float* __restrict__ P) {
  int row0 = blockIdx.y * 64;
  int col0 = blockIdx.x * 64;
  if (col0 > row0) return;
  int ks = blockIdx.z;
  __shared__ unsigned short Asl[64][64];
  __shared__ unsigned short Bsl[64][64];
  int t = (int)threadIdx.x, lane = t & 63, wave = t >> 6;
  int wm = wave >> 1, wn = wave & 1;

  f32x4 acc[2][2];
#pragma unroll
  for (int i = 0; i < 2; i++)
#pragma unroll
    for (int j = 0; j < 2; j++) acc[i][j] = (f32x4){0.f, 0.f, 0.f, 0.f};

  int r = t >> 2, c0 = t & 3;
  int sw0 = ((c0 ^ (r & 7))) * 8;        // swizzled chunk for global chunk c0
  int sw1 = (((c0 + 4) ^ (r & 7))) * 8;  // for global chunk c0+4
  const unsigned short* Ap = A + (long long)(row0 + r) * 8192 + ks * 2048 + c0 * 8;
  const unsigned short* Bp = Bm + (long long)(col0 + r) * 8192 + ks * 2048 + c0 * 8;

  for (int kb = 0; kb < 2048; kb += 64) {
    i32x4 a0 = *(const i32x4*)(Ap + kb);
    i32x4 a1 = *(const i32x4*)(Ap + kb + 32);
    i32x4 b0 = *(const i32x4*)(Bp + kb);
    i32x4 b1 = *(const i32x4*)(Bp + kb + 32);
    __syncthreads();
    *(i32x4*)&Asl[r][sw0] = a0;
    *(i32x4*)&Asl[r][sw1] = a1;
    *(i32x4*)&Bsl[r][sw0] = b0;
    *(i32x4*)&Bsl[r][sw1] = b1;
    __syncthreads();

    int rr = lane & 15, co = lane >> 4;
#pragma unroll
    for (int k2 = 0; k2 < 2; k2++) {
      int ch = ((k2 * 4 + co) ^ (rr & 7)) * 8;
      i32x4 af0 = *(i32x4*)&Asl[wm * 32 + rr][ch];
      i32x4 af1 = *(i32x4*)&Asl[wm * 32 + 16 + rr][ch];
      i32x4 bf0 = *(i32x4*)&Bsl[wn * 32 + rr][ch];
      i32x4 bf1 = *(i32x4*)&Bsl[wn * 32 + 16 + rr][ch];
      acc[0][0] = mfma_bf16(af0, bf0, acc[0][0]);
      acc[0][1] = mfma_bf16(af0, bf1, acc[0][1]);
      acc[1][0] = mfma_bf16(af1, bf0, acc[1][0]);
      acc[1][1] = mfma_bf16(af1, bf1, acc[1][1]);
    }
  }

  float* dst = P + (long long)ks * 1048576;
  int rq = lane >> 4, rr = lane & 15;
#pragma unroll
  for (int fm = 0; fm < 2; fm++) {
#pragma unroll
    for (int fn = 0; fn < 2; fn++) {
      int j = col0 + wn * 32 + fn * 16 + rr;
#pragma unroll
      for (int rl = 0; rl < 4; rl++) {
        int i = row0 + wm * 32 + fm * 16 + rq * 4 + rl;
        dst[(long long)i * 1024 + j] = scl[i] * acc[fm][fn][rl];
      }
    }
  }
}

// ---------------------------------------------------------------------------
// ctx (bf16 MFMA): ctx[i, h*64+d] = sum_k w16[i,h*1024+k]*VbT16[h*64+d,k].
// ---------------------------------------------------------------------------
__global__ __launch_bounds__(256) void gemm_ctx_bf16(
    const unsigned short* __restrict__ w16,
    const unsigned short* __restrict__ VT, float* __restrict__ ctx) {
  int row0 = blockIdx.x * 64;
  int h = blockIdx.y;
  __shared__ unsigned short Asl[64][68];
  __shared__ unsigned short Bsl[64][68];
  int t = (int)threadIdx.x, lane = t & 63, wave = t >> 6;

  f32x4 acc[4];
#pragma unroll
  for (int i = 0; i < 4; i++) acc[i] = (f32x4){0.f, 0.f, 0.f, 0.f};

  int r = t >> 2, kq = (t & 3) * 8;
  const unsigned short* Ap = w16 + (long long)(row0 + r) * 8192 + h * 1024 + kq;
  const unsigned short* Bp = VT + (long long)(h * 64 + r) * 1024 + kq;

  for (int kb = 0; kb < 1024; kb += 64) {
    i32x4 a0 = *(const i32x4*)(Ap + kb);
    i32x4 a1 = *(const i32x4*)(Ap + kb + 32);
    i32x4 b0 = *(const i32x4*)(Bp + kb);
    i32x4 b1 = *(const i32x4*)(Bp + kb + 32);
    __syncthreads();
    *(i32x4*)&Asl[r][kq] = a0;
    *(i32x4*)&Asl[r][kq + 32] = a1;
    *(i32x4*)&Bsl[r][kq] = b0;
    *(i32x4*)&Bsl[r][kq + 32] = b1;
    __syncthreads();

    int rr = lane & 15, ko = (lane >> 4) * 8;
#pragma unroll
    for (int k2 = 0; k2 < 2; k2++) {
      i32x4 af = *(i32x4*)&Asl[wave * 16 + rr][k2 * 32 + ko];
#pragma unroll
      for (int fn = 0; fn < 4; fn++) {
        i32x4 bf = *(i32x4*)&Bsl[fn * 16 + rr][k2 * 32 + ko];
        acc[fn] = mfma_bf16(af, bf, acc[fn]);
      }
    }
  }

  int rq = lane >> 4, rr = lane & 15;
#pragma unroll
  for (int fn = 0; fn < 4; fn++) {
#pragma unroll
    for (int rl = 0; rl < 4; rl++) {
      int i = row0 + wave * 16 + rq * 4 + rl;
      ctx[(long long)i * 512 + h * 64 + fn * 16 + rr] = acc[fn][rl];
    }
  }
}

// ---------------------------------------------------------------------------
// Vertical routing (bf16 u in, 3 fused iters) -> vV f32.
// ---------------------------------------------------------------------------
__global__ __launch_bounds__(256) void vertical_routing_kernel(
    const unsigned short* __restrict__ u16, float* __restrict__ vV) {
  __shared__ float Ur[8 * 1024];
  __shared__ float red[4];
  __shared__ float red8[32];
  int bq = blockIdx.x;
  int t = (int)threadIdx.x;
  const unsigned short* Ub = u16 + (long long)bq * 8192;
#pragma unroll
  for (int r = 0; r < 8; r++) {
    uint2 p = *(const uint2*)&Ub[(t + 256 * r) * 4];
    Ur[(t + 256 * r) * 4 + 0] = bf2f(p.x & 0xffffu);
    Ur[(t + 256 * r) * 4 + 1] = bf2f(p.x >> 16);
    Ur[(t + 256 * r) * 4 + 2] = bf2f(p.y & 0xffffu);
    Ur[(t + 256 * r) * 4 + 3] = bf2f(p.y >> 16);
  }
  __syncthreads();

  float bh[8] = {0.f, 0.f, 0.f, 0.f, 0.f, 0.f, 0.f, 0.f};
  int k0 = t * 4;
  float4 v4 = {0.f, 0.f, 0.f, 0.f};
  for (int it = 0; it < 3; ++it) {
    float m = bh[0];
#pragma unroll
    for (int h = 1; h < 8; h++) m = fmaxf(m, bh[h]);
    float c[8], zz = 0.f;
#pragma unroll
    for (int h = 0; h < 8; h++) {
      c[h] = expf(bh[h] - m);
      zz += c[h];
    }
    float inv = 1.f / zz;
    float4 s4 = {0.f, 0.f, 0.f, 0.f};
#pragma unroll
    for (int h = 0; h < 8; h++) {
      float4 u = *(float4*)&Ur[h * 1024 + k0];
      float ch = c[h] * inv;
      s4.x = fmaf(ch, u.x, s4.x); s4.y = fmaf(ch, u.y, s4.y);
      s4.z = fmaf(ch, u.z, s4.z); s4.w = fmaf(ch, u.w, s4.w);
    }
    float sq =
        blockSum(s4.x * s4.x + s4.y * s4.y + s4.z * s4.z + s4.w * s4.w, red);
    float sc = (sq / (1.f + sq)) / sqrtf(sq + SQ_EPS);
    v4.x = sc * s4.x; v4.y = sc * s4.y; v4.z = sc * s4.z; v4.w = sc * s4.w;
    if (it < 2) {
      float p[8];
#pragma unroll
      for (int h = 0; h < 8; h++) {
        float4 u = *(float4*)&Ur[h * 1024 + k0];
        p[h] = u.x * v4.x + u.y * v4.y + u.z * v4.z + u.w * v4.w;
      }
      __syncthreads();
#pragma unroll
      for (int h = 0; h < 8; h++) {
        float w = wredSum(p[h]);
        if ((t & 63) == 0) red8[(t >> 6) * 8 + h] = w;
      }
      __syncthreads();
#pragma unroll
      for (int h = 0; h < 8; h++)
        bh[h] += red8[h] + red8[8 + h] + red8[16 + h] + red8[24 + h];
    }
  }
  *(float4*)&vV[(long long)bq * 1024 + k0] = v4;
}

// it=0 coupling: cH16[i,j] = 1/(i+1) for j<=i else 0.
__global__ __launch_bounds__(256) void softmax_uniform_kernel(
    unsigned short* __restrict__ cH16) {
  int i = blockIdx.x;
  int t = (int)threadIdx.x, k0 = t * 4;
  unsigned short c = f2bf(1.f / (float)(i + 1));
  unsigned short e0 = (k0 + 0) <= i ? c : (unsigned short)0;
  unsigned short e1 = (k0 + 1) <= i ? c : (unsigned short)0;
  unsigned short e2 = (k0 + 2) <= i ? c : (unsigned short)0;
  unsigned short e3 = (k0 + 3) <= i ? c : (unsigned short)0;
  uint2 o = {(unsigned int)e0 | ((unsigned int)e1 << 16),
             (unsigned int)e2 | ((unsigned int)e3 << 16)};
  *(uint2*)&cH16[(long long)i * 1024 + k0] = o;
}

// bH (+)= sum_z P[z]; cH16 = causal softmax(bH). INIT=1: fresh store.
template <int INIT>
__global__ __launch_bounds__(256) void add_softmax_kernel(
    float* __restrict__ bH, const float* __restrict__ P,
    unsigned short* __restrict__ cH16) {
  __shared__ float red[4];
  int i = blockIdx.x;
  long long base = (long long)i * 1024;
  int t = (int)threadIdx.x, k0 = t * 4;
  float4 x;
  if (INIT) x = (float4){0.f, 0.f, 0.f, 0.f};
  else x = *(const float4*)&bH[base + k0];
#pragma unroll
  for (int z = 0; z < 4; z++) {
    float4 p = *(const float4*)&P[(long long)z * 1048576 + base + k0];
    x.x += p.x; x.y += p.y; x.z += p.z; x.w += p.w;
  }
  *(float4*)&bH[base + k0] = x;
  bool m0 = (k0 + 0) <= i, m1 = (k0 + 1) <= i, m2 = (k0 + 2) <= i,
       m3 = (k0 + 3) <= i;
  float mx = -3.0e38f;
  if (m0) mx = fmaxf(mx, x.x);
  if (m1) mx = fmaxf(mx, x.y);
  if (m2) mx = fmaxf(mx, x.z);
  if (m3) mx = fmaxf(mx, x.w);
  mx = blockMax(mx, red);
  float e0 = m0 ? expf(x.x - mx) : 0.f;
  float e1 = m1 ? expf(x.y - mx) : 0.f;
  float e2 = m2 ? expf(x.z - mx) : 0.f;
  float e3 = m3 ? expf(x.w - mx) : 0.f;
  float zz = blockSum(e0 + e1 + e2 + e3, red);
  float inv = 1.f / zz;
  uint2 o = {(unsigned int)f2bf(e0 * inv) | ((unsigned int)f2bf(e1 * inv) << 16),
             (unsigned int)f2bf(e2 * inv) | ((unsigned int)f2bf(e3 * inv) << 16)};
  *(uint2*)&cH16[base + k0] = o;
}

// enhanced = u16 + vV + scl[i]*sv16; w = softmax_k -> u16 in place (bf16).
__global__ __launch_bounds__(256) void enh_softmax_kernel(
    unsigned short* __restrict__ u16, const float* __restrict__ vV,
    const unsigned short* __restrict__ sv16, const float* __restrict__ scl) {
  __shared__ float red[4];
  int idx = blockIdx.x;  // Q*H
  int h = idx & 7;
  int bq = idx >> 3;
  unsigned short* Urow = u16 + (long long)bq * 8192 + h * 1024;
  const float* va = vV + (long long)bq * 1024;
  const unsigned short* vb = sv16 + (long long)bq * 8192 + h * 1024;
  float sc = scl[bq];
  int t = (int)threadIdx.x, k0 = t * 4;
  uint2 pu = *(const uint2*)&Urow[k0];
  float4 a = *(const float4*)&va[k0];
  uint2 pb = *(const uint2*)&vb[k0];
  float x0 = bf2f(pu.x & 0xffffu) + a.x + sc * bf2f(pb.x & 0xffffu);
  float x1 = bf2f(pu.x >> 16) + a.y + sc * bf2f(pb.x >> 16);
  float x2 = bf2f(pu.y & 0xffffu) + a.z + sc * bf2f(pb.y & 0xffffu);
  float x3 = bf2f(pu.y >> 16) + a.w + sc * bf2f(pb.y >> 16);
  float mx = blockMax(fmaxf(fmaxf(x0, x1), fmaxf(x2, x3)), red);
  float e0 = expf(x0 - mx), e1 = expf(x1 - mx), e2 = expf(x2 - mx),
        e3 = expf(x3 - mx);
  float zz = blockSum(e0 + e1 + e2 + e3, red);
  float inv = 1.f / zz;
  uint2 o = {(unsigned int)f2bf(e0 * inv) | ((unsigned int)f2bf(e1 * inv) << 16),
             (unsigned int)f2bf(e2 * inv) | ((unsigned int)f2bf(e3 * inv) << 16)};
  *(uint2*)&Urow[k0] = o;
}

// ---------------------------------------------------------------------------
extern "C" void kernel_launch(void* const* d_in, const int* in_sizes, int n_in,
                              void* d_out, int out_size, void* d_ws,
                              size_t ws_size, hipStream_t stream) {
  (void)in_sizes; (void)n_in; (void)out_size; (void)ws_size;
  const float* x = (const float*)d_in[0];
  const float* Wq = (const float*)d_in[1];
  const float* bq = (const float*)d_in[2];
  const float* Wk = (const float*)d_in[3];
  const float* bk = (const float*)d_in[4];
  const float* Wv = (const float*)d_in[5];
  const float* bv = (const float*)d_in[6];
  const float* Wo = (const float*)d_in[7];
  const float* bo = (const float*)d_in[8];
  float* out = (float*)d_out;
  float* ws = (float*)d_ws;

  unsigned short* u16 = (unsigned short*)(ws);               // 4194304 fl
  unsigned short* uT16 = (unsigned short*)(ws + 4194304);    // 4194304 fl
  unsigned short* sv16 = (unsigned short*)(ws + 8388608);    // 4194304 fl
  float* Qb = ws + 12582912;                                 //  524288
  float* Kb = ws + 13107200;                                 //  524288
  float* Vb = ws + 13631488;                                 //  524288
  unsigned short* VbT16 = (unsigned short*)(ws + 14155776);  //  262144 fl
  float* vV = ws + 14417920;                                 // 1048576
  float* bH = ws + 15466496;                                 // 1048576
  float* P = ws + 16515072;                                  // 4194304 (4x)
  unsigned short* cH16 = (unsigned short*)(ws + 20709376);   //  524288 fl
  float* ctx = ws + 21233664;                                //  524288
  float* scl = ws + 21757952;                                //    1024
  // total 21758976 floats = 83.0 MiB

  for (int b = 0; b < 4; ++b) {
    const float* xb = x + (long long)b * 524288;

    // 1. fused QKV projections (one dispatch, 384 blocks)
    gemm_qkv_f32<<<dim3(8, 16, 3), 256, 0, stream>>>(xb, Wq, Wk, Wv, bq, bk,
                                                     bv, Qb, Kb, Vb);

    // 2. scores -> u16 bf16 (fp32 compute)
    gemm_scores_bf16<<<dim3(8, 8, 8), 256, 0, stream>>>(Qb, Kb, u16);

    // 3. transposes
    transpose16_kernel<<<dim3(16, 128), 256, 0, stream>>>(u16, uT16, 8192,
                                                          1024);
    transpose_f32_bf16_kernel<<<dim3(16, 8), 256, 0, stream>>>(Vb, VbT16, 512,
                                                               1024);

    // 4. vertical routing -> vV
    vertical_routing_kernel<<<dim3(1024), 256, 0, stream>>>(u16, vV);

    // 5. horizontal routing
    softmax_uniform_kernel<<<dim3(1024), 256, 0, stream>>>(cH16);
    gemm_s_bf16<<<dim3(64, 8), 256, 0, stream>>>(cH16, uT16, sv16);
    rowsumsq_kernel<<<dim3(1024), 256, 0, stream>>>(sv16, scl);
    gemm_b_bf16<<<dim3(16, 16, 4), 256, 0, stream>>>(sv16, u16, scl, P);

    add_softmax_kernel<1><<<dim3(1024), 256, 0, stream>>>(bH, P, cH16);
    gemm_s_bf16<<<dim3(64, 8), 256, 0, stream>>>(cH16, uT16, sv16);
    rowsumsq_kernel<<<dim3(1024), 256, 0, stream>>>(sv16, scl);
    gemm_b_bf16<<<dim3(16, 16, 4), 256, 0, stream>>>(sv16, u16, scl, P);

    add_softmax_kernel<0><<<dim3(1024), 256, 0, stream>>>(bH, P, cH16);
    gemm_s_bf16<<<dim3(64, 8), 256, 0, stream>>>(cH16, uT16, sv16);
    rowsumsq_kernel<<<dim3(1024), 256, 0, stream>>>(sv16, scl);

    // 6. enhanced + softmax -> w bf16 into u16 in place
    enh_softmax_kernel<<<dim3(8192), 256, 0, stream>>>(u16, vV, sv16, scl);

    // 7. ctx = w x V (bf16 MFMA)
    gemm_ctx_bf16<<<dim3(16, 8), 256, 0, stream>>>(u16, VbT16, ctx);

    // 8. out = ctx x Wo + bo
    gemm_f32<64, 64, 16><<<dim3(8, 16), 256, 0, stream>>>(
        ctx, Wo, out + (long long)b * 524288, bo, 512, 512, 512, 512);
  }
}

// Round 7
// 965.246 us; speedup vs baseline: 7.1869x; 1.1741x over previous
//
#include <hip/hip_runtime.h>
#include <math.h>

// ---------------------------------------------------------------------------
// CapsuleRoutingSelfAttention — round 7: recovery build.
// All kernels are round-5-proven molds; QKV moved to MFMA (Q,K out in fp32 to
// keep the proven fp32 scores path), out-projection hoisted across batches.
// B=4, S=1024, E=512, H=8, DK=DV=64, capsule dim 8192.
//
// Workspace (float units), total 28,181,504 fl = 107.5 MiB (ws = 256 MiB):
//   u16   [1024,8192] bf16   per-batch scores; later w in place
//   uT16  [8192,1024] bf16
//   sv16  [1024,8192] bf16   raw s (squash scale in scl)
//   Qf/Kf [4096,512]  f32    all-batch q,k (fp32 for scores precision)
//   V16a  [4096,512]  bf16   all-batch v
//   VT16a [4][512,1024] bf16
//   WT16  [3][512,512] bf16  W^T
//   ctxa  [4096,512]  f32
//   vV [1024,1024] f32 | bH [1024,1024] f32 | P[4][1024,1024] f32
//   cH16 [1024,1024] bf16 | scl [1024] f32
// ---------------------------------------------------------------------------

#define SQ_EPS 1e-8f

typedef __attribute__((ext_vector_type(4))) int i32x4;    // 8 bf16
typedef __attribute__((ext_vector_type(4))) float f32x4;

__device__ __forceinline__ float bf2f(unsigned int u) {
  union { unsigned int i; float f; } x;
  x.i = u << 16;
  return x.f;
}
__device__ __forceinline__ unsigned short f2bf(float f) {
  union { float f; unsigned int i; } x;
  x.f = f;
  unsigned int r = x.i + 0x7fffu + ((x.i >> 16) & 1u);
  return (unsigned short)(r >> 16);
}
__device__ __forceinline__ int packbf(float a, float b) {
  return (int)((unsigned int)f2bf(a) | ((unsigned int)f2bf(b) << 16));
}

__device__ __forceinline__ f32x4 mfma_bf16(i32x4 a, i32x4 b, f32x4 c) {
  asm("v_mfma_f32_16x16x32_bf16 %0, %1, %2, %0" : "+v"(c) : "v"(a), "v"(b));
  return c;
}

__device__ __forceinline__ float wredSum(float v) {
#pragma unroll
  for (int off = 32; off > 0; off >>= 1) v += __shfl_xor(v, off);
  return v;
}
__device__ __forceinline__ float wredMax(float v) {
#pragma unroll
  for (int off = 32; off > 0; off >>= 1) v = fmaxf(v, __shfl_xor(v, off));
  return v;
}
__device__ __forceinline__ float blockSum(float v, volatile float* red) {
  v = wredSum(v);
  int wid = threadIdx.x >> 6;
  __syncthreads();
  if ((threadIdx.x & 63) == 0) red[wid] = v;
  __syncthreads();
  return red[0] + red[1] + red[2] + red[3];
}
__device__ __forceinline__ float blockMax(float v, volatile float* red) {
  v = wredMax(v);
  int wid = threadIdx.x >> 6;
  __syncthreads();
  if ((threadIdx.x & 63) == 0) red[wid] = v;
  __syncthreads();
  return fmaxf(fmaxf(red[0], red[1]), fmaxf(red[2], red[3]));
}

// ---------------------------------------------------------------------------
// W^T prep: WT16[z][n][e] = bf16(W_z[e][n]).  Grid (8, 8, 3).
// (round-5 transpose_f32_bf16 mold, ldS=ldD=512 + z-select)
// ---------------------------------------------------------------------------
__global__ __launch_bounds__(256) void wtrans_kernel(
    const float* __restrict__ Wq, const float* __restrict__ Wk,
    const float* __restrict__ Wv, unsigned short* __restrict__ WT16) {
  __shared__ unsigned short T[64][72];
  int z = blockIdx.z;
  const float* src = (z == 0) ? Wq : (z == 1) ? Wk : Wv;
  unsigned short* dst = WT16 + (long long)z * 262144;
  int i0 = blockIdx.x * 64;  // e
  int c0 = blockIdx.y * 64;  // n
  int t = (int)threadIdx.x;
  int r = t >> 2, cq = (t & 3) * 16;
#pragma unroll
  for (int j = 0; j < 4; j++) {
    float4 v = *(const float4*)&src[(long long)(i0 + r) * 512 + c0 + cq + j * 4];
    T[r][cq + j * 4 + 0] = f2bf(v.x);
    T[r][cq + j * 4 + 1] = f2bf(v.y);
    T[r][cq + j * 4 + 2] = f2bf(v.z);
    T[r][cq + j * 4 + 3] = f2bf(v.w);
  }
  __syncthreads();
  int c = t >> 2, iq = (t & 3) * 16;
  unsigned short tmp[16];
#pragma unroll
  for (int j = 0; j < 16; j++) tmp[j] = T[iq + j][c];
  *(i32x4*)&dst[(long long)(c0 + c) * 512 + i0 + iq] = *(i32x4*)&tmp[0];
  *(i32x4*)&dst[(long long)(c0 + c) * 512 + i0 + iq + 8] = *(i32x4*)&tmp[8];
}

// ---------------------------------------------------------------------------
// QKV (bf16 MFMA, all batches): acc = sum_e bf16(x[i,e]) * WT16[z][n][e].
// z=0 -> Qf f32, z=1 -> Kf f32, z=2 -> V16a bf16 (all + bias in f32).
// EXACT round-5 gemm_ctx/gemm_b staging+MFMA mold (64x64x64, 4 waves 32x32,
// r=t>>2, kq=(t&3)*8, chunks at kq and kq+32, LDS [64][68]). Grid (8,64,3).
// ---------------------------------------------------------------------------
__global__ __launch_bounds__(256) void gemm_qkv_mfma(
    const float* __restrict__ x, const unsigned short* __restrict__ WT16,
    const float* __restrict__ bq, const float* __restrict__ bk,
    const float* __restrict__ bv, float* __restrict__ Qf,
    float* __restrict__ Kf, unsigned short* __restrict__ V16) {
  __shared__ unsigned short Asl[64][68];
  __shared__ unsigned short Bsl[64][68];
  int z = blockIdx.z;
  const unsigned short* WT = WT16 + (long long)z * 262144;
  const float* bias = (z == 0) ? bq : (z == 1) ? bk : bv;

  int row0 = blockIdx.y * 64;
  int col0 = blockIdx.x * 64;
  int t = (int)threadIdx.x, lane = t & 63, wave = t >> 6;
  int wm = wave >> 1, wn = wave & 1;

  f32x4 acc[2][2];
#pragma unroll
  for (int i = 0; i < 2; i++)
#pragma unroll
    for (int j = 0; j < 2; j++) acc[i][j] = (f32x4){0.f, 0.f, 0.f, 0.f};

  int r = t >> 2, kq = (t & 3) * 8;
  const float* Ap = x + (long long)(row0 + r) * 512 + kq;
  const unsigned short* Bp = WT + (long long)(col0 + r) * 512 + kq;

  for (int kb = 0; kb < 512; kb += 64) {
    float4 a0 = *(const float4*)(Ap + kb);
    float4 a1 = *(const float4*)(Ap + kb + 4);
    float4 a2 = *(const float4*)(Ap + kb + 32);
    float4 a3 = *(const float4*)(Ap + kb + 36);
    i32x4 b0 = *(const i32x4*)(Bp + kb);
    i32x4 b1 = *(const i32x4*)(Bp + kb + 32);
    __syncthreads();
    i32x4 pa0 = {packbf(a0.x, a0.y), packbf(a0.z, a0.w), packbf(a1.x, a1.y),
                 packbf(a1.z, a1.w)};
    i32x4 pa1 = {packbf(a2.x, a2.y), packbf(a2.z, a2.w), packbf(a3.x, a3.y),
                 packbf(a3.z, a3.w)};
    *(i32x4*)&Asl[r][kq] = pa0;
    *(i32x4*)&Asl[r][kq + 32] = pa1;
    *(i32x4*)&Bsl[r][kq] = b0;
    *(i32x4*)&Bsl[r][kq + 32] = b1;
    __syncthreads();

    int rr = lane & 15, ko = (lane >> 4) * 8;
#pragma unroll
    for (int k2 = 0; k2 < 2; k2++) {
      i32x4 af0 = *(i32x4*)&Asl[wm * 32 + rr][k2 * 32 + ko];
      i32x4 af1 = *(i32x4*)&Asl[wm * 32 + 16 + rr][k2 * 32 + ko];
      i32x4 bf0 = *(i32x4*)&Bsl[wn * 32 + rr][k2 * 32 + ko];
      i32x4 bf1 = *(i32x4*)&Bsl[wn * 32 + 16 + rr][k2 * 32 + ko];
      acc[0][0] = mfma_bf16(af0, bf0, acc[0][0]);
      acc[0][1] = mfma_bf16(af0, bf1, acc[0][1]);
      acc[1][0] = mfma_bf16(af1, bf0, acc[1][0]);
      acc[1][1] = mfma_bf16(af1, bf1, acc[1][1]);
    }
  }

  int rq = lane >> 4, rr = lane & 15;
#pragma unroll
  for (int fm = 0; fm < 2; fm++) {
#pragma unroll
    for (int fn = 0; fn < 2; fn++) {
      int col = col0 + wn * 32 + fn * 16 + rr;
      float bb = bias[col];
#pragma unroll
      for (int rl = 0; rl < 4; rl++) {
        int row = row0 + wm * 32 + fm * 16 + rq * 4 + rl;
        float v = acc[fm][fn][rl] + bb;
        if (z == 2)
          V16[(long long)row * 512 + col] = f2bf(v);
        else if (z == 1)
          Kf[(long long)row * 512 + col] = v;
        else
          Qf[(long long)row * 512 + col] = v;
      }
    }
  }
}

// ---------------------------------------------------------------------------
// Scores (fp32 compute, bf16 out) — round-5 verbatim.
// u16[i, h*1024+k] = bf16( (1/8) q[i,h,:].k[k,h,:] ).  Grid (8,8,8).
// ---------------------------------------------------------------------------
__global__ __launch_bounds__(256) void gemm_scores_bf16(
    const float* __restrict__ Qb, const float* __restrict__ Kb,
    unsigned short* __restrict__ u16) {
  __shared__ float As[8][132];
  __shared__ float Bs[8][132];
  int h = blockIdx.z;
  const float* A = Qb + h * 64;
  const float* B = Kb + h * 64;
  unsigned short* C16 = u16 + h * 1024;

  int row0 = blockIdx.y * 128;
  int col0 = blockIdx.x * 128;
  int tid = (int)threadIdx.x;
  int tx = tid & 15, ty = tid >> 4;
  int arow = tid >> 1;
  int akc = (tid & 1) * 4;

  float acc[8][8];
#pragma unroll
  for (int i = 0; i < 8; i++)
#pragma unroll
    for (int j = 0; j < 8; j++) acc[i][j] = 0.f;

  const float* Aptr = A + (long long)(row0 + arow) * 512 + akc;
  const float* Bptr = B + (long long)(col0 + arow) * 512 + akc;

  for (int kb = 0; kb < 64; kb += 8) {
    float4 av = *(const float4*)(Aptr + kb);
    float4 bv = *(const float4*)(Bptr + kb);
    __syncthreads();
    As[akc + 0][arow] = av.x; As[akc + 1][arow] = av.y;
    As[akc + 2][arow] = av.z; As[akc + 3][arow] = av.w;
    Bs[akc + 0][arow] = bv.x; Bs[akc + 1][arow] = bv.y;
    Bs[akc + 2][arow] = bv.z; Bs[akc + 3][arow] = bv.w;
    __syncthreads();

#pragma unroll
    for (int k = 0; k < 8; k++) {
      float a[8], b[8];
#pragma unroll
      for (int c = 0; c < 2; c++) {
        float4 q = *(float4*)&As[k][ty * 8 + c * 4];
        a[c * 4 + 0] = q.x; a[c * 4 + 1] = q.y;
        a[c * 4 + 2] = q.z; a[c * 4 + 3] = q.w;
      }
#pragma unroll
      for (int c = 0; c < 2; c++) {
        float4 q = *(float4*)&Bs[k][c * 64 + tx * 4];
        b[c * 4 + 0] = q.x; b[c * 4 + 1] = q.y;
        b[c * 4 + 2] = q.z; b[c * 4 + 3] = q.w;
      }
#pragma unroll
      for (int i = 0; i < 8; i++)
#pragma unroll
        for (int j = 0; j < 8; j++) acc[i][j] = fmaf(a[i], b[j], acc[i][j]);
    }
  }

#pragma unroll
  for (int i = 0; i < 8; i++) {
    long long r = row0 + ty * 8 + i;
#pragma unroll
    for (int c = 0; c < 2; c++) {
      int col = col0 + c * 64 + tx * 4;
      unsigned int lo = (unsigned int)f2bf(0.125f * acc[i][c * 4 + 0]) |
                        ((unsigned int)f2bf(0.125f * acc[i][c * 4 + 1]) << 16);
      unsigned int hi = (unsigned int)f2bf(0.125f * acc[i][c * 4 + 2]) |
                        ((unsigned int)f2bf(0.125f * acc[i][c * 4 + 3]) << 16);
      uint2 o = {lo, hi};
      *(uint2*)&C16[r * 8192 + col] = o;
    }
  }
}

// ---------------------------------------------------------------------------
// fp32 tiled GEMM (out-projection) — round-5 verbatim.
// ---------------------------------------------------------------------------
template <int BM, int BN, int BK>
__global__ __launch_bounds__(256) void gemm_f32(
    const float* __restrict__ A, const float* __restrict__ B,
    float* __restrict__ C, const float* __restrict__ bias,
    int K, int lda, int ldb, int ldc) {
  constexpr int TM = BM / 16;
  constexpr int TN = BN / 16;
  __shared__ float As[BK][BM + 4];
  __shared__ float Bs[BK][BN + 4];

  int row0 = blockIdx.y * BM;
  int col0 = blockIdx.x * BN;
  int tid = (int)threadIdx.x;
  int tx = tid & 15, ty = tid >> 4;

  constexpr int AKC = BK / 4;
  int arow = tid / AKC;
  int akc = (tid - arow * AKC) * 4;
  int brow = tid / (BN / 4);
  int bcol = (tid - brow * (BN / 4)) * 4;

  float acc[TM][TN];
#pragma unroll
  for (int i = 0; i < TM; i++)
#pragma unroll
    for (int j = 0; j < TN; j++) acc[i][j] = 0.f;

  const float* Aptr = A + (long long)(row0 + arow) * lda + akc;
  const float* Bptr = B + (long long)brow * ldb + col0 + bcol;

  for (int kb = 0; kb < K; kb += BK) {
    float4 av = *(const float4*)(Aptr + kb);
    float4 bv = *(const float4*)(Bptr + (long long)kb * ldb);
    __syncthreads();
    As[akc + 0][arow] = av.x;
    As[akc + 1][arow] = av.y;
    As[akc + 2][arow] = av.z;
    As[akc + 3][arow] = av.w;
    *(float4*)&Bs[brow][bcol] = bv;
    __syncthreads();

#pragma unroll
    for (int k = 0; k < BK; k++) {
      float a[TM], b[TN];
#pragma unroll
      for (int c = 0; c < TM / 4; c++) {
        float4 q = *(float4*)&As[k][ty * TM + c * 4];
        a[c * 4 + 0] = q.x; a[c * 4 + 1] = q.y;
        a[c * 4 + 2] = q.z; a[c * 4 + 3] = q.w;
      }
#pragma unroll
      for (int c = 0; c < TN / 4; c++) {
        float4 q = *(float4*)&Bs[k][c * 64 + tx * 4];
        b[c * 4 + 0] = q.x; b[c * 4 + 1] = q.y;
        b[c * 4 + 2] = q.z; b[c * 4 + 3] = q.w;
      }
#pragma unroll
      for (int i = 0; i < TM; i++)
#pragma unroll
        for (int j = 0; j < TN; j++) acc[i][j] = fmaf(a[i], b[j], acc[i][j]);
    }
  }

#pragma unroll
  for (int i = 0; i < TM; i++) {
    long long r = row0 + ty * TM + i;
#pragma unroll
    for (int c = 0; c < TN / 4; c++) {
      int col = col0 + c * 64 + tx * 4;
      float4 val = {acc[i][c * 4 + 0], acc[i][c * 4 + 1], acc[i][c * 4 + 2],
                    acc[i][c * 4 + 3]};
      if (bias) {
        float4 bb = *(const float4*)&bias[col];
        val.x += bb.x; val.y += bb.y; val.z += bb.z; val.w += bb.w;
      }
      *(float4*)&C[r * ldc + col] = val;
    }
  }
}

// ---------------------------------------------------------------------------
// bf16 -> bf16 transpose, 64x64 tiles — round-5 verbatim.
// ---------------------------------------------------------------------------
__global__ __launch_bounds__(256) void transpose16_kernel(
    const unsigned short* __restrict__ src, unsigned short* __restrict__ dst,
    int ldS, int ldD) {
  __shared__ unsigned short T[64][72];
  int i0 = blockIdx.x * 64;
  int c0 = blockIdx.y * 64;
  int t = (int)threadIdx.x;
  int r = t >> 2, cq = (t & 3) * 16;
  i32x4 v0 = *(const i32x4*)&src[(long long)(i0 + r) * ldS + c0 + cq];
  i32x4 v1 = *(const i32x4*)&src[(long long)(i0 + r) * ldS + c0 + cq + 8];
  *(i32x4*)&T[r][cq] = v0;
  *(i32x4*)&T[r][cq + 8] = v1;
  __syncthreads();
  int c = t >> 2, iq = (t & 3) * 16;
  unsigned short tmp[16];
#pragma unroll
  for (int j = 0; j < 16; j++) tmp[j] = T[iq + j][c];
  *(i32x4*)&dst[(long long)(c0 + c) * ldD + i0 + iq] = *(i32x4*)&tmp[0];
  *(i32x4*)&dst[(long long)(c0 + c) * ldD + i0 + iq + 8] = *(i32x4*)&tmp[8];
}

// ---------------------------------------------------------------------------
// s-GEMM (bf16 MFMA) — round-5 verbatim. Tile 128x128x32, causal Kend,
// descending row-blocks, LDS [128][32]. Grid (64, 8).
// ---------------------------------------------------------------------------
__global__ __launch_bounds__(256) void gemm_s_bf16(
    const unsigned short* __restrict__ Abf,   // cH16 [1024,1024]
    const unsigned short* __restrict__ BT,    // uT16 [8192,1024]
    unsigned short* __restrict__ Cout) {      // sv16 [1024,8192]
  __shared__ unsigned short Alds[128][32];
  __shared__ unsigned short Blds[128][32];
  int rowblk = 7 - (int)blockIdx.y;  // big-K blocks dispatched first
  int row0 = rowblk * 128;
  int col0 = blockIdx.x * 128;
  int t = (int)threadIdx.x, lane = t & 63, wave = t >> 6;
  int wm = wave >> 1, wn = wave & 1;
  int Kend = row0 + 128;

  f32x4 acc[4][4];
#pragma unroll
  for (int i = 0; i < 4; i++)
#pragma unroll
    for (int j = 0; j < 4; j++) acc[i][j] = (f32x4){0.f, 0.f, 0.f, 0.f};

  int ar = t >> 2;
  int aq = (t & 3) * 8;

  for (int kb = 0; kb < Kend; kb += 32) {
    i32x4 a0 = *(const i32x4*)&Abf[(long long)(row0 + ar) * 1024 + kb + aq];
    i32x4 a1 = *(const i32x4*)&Abf[(long long)(row0 + ar + 64) * 1024 + kb + aq];
    i32x4 b0 = *(const i32x4*)&BT[(long long)(col0 + ar) * 1024 + kb + aq];
    i32x4 b1 = *(const i32x4*)&BT[(long long)(col0 + ar + 64) * 1024 + kb + aq];
    __syncthreads();
    *(i32x4*)&Alds[ar][aq] = a0;
    *(i32x4*)&Alds[ar + 64][aq] = a1;
    *(i32x4*)&Blds[ar][aq] = b0;
    *(i32x4*)&Blds[ar + 64][aq] = b1;
    __syncthreads();

    int rr = lane & 15, koff = (lane >> 4) * 8;
    i32x4 af[4], bfv[4];
#pragma unroll
    for (int fm = 0; fm < 4; fm++)
      af[fm] = *(i32x4*)&Alds[wm * 64 + fm * 16 + rr][koff];
#pragma unroll
    for (int fn = 0; fn < 4; fn++)
      bfv[fn] = *(i32x4*)&Blds[wn * 64 + fn * 16 + rr][koff];
#pragma unroll
    for (int fm = 0; fm < 4; fm++)
#pragma unroll
      for (int fn = 0; fn < 4; fn++)
        acc[fm][fn] = mfma_bf16(af[fm], bfv[fn], acc[fm][fn]);
  }

  int rq = lane >> 4, rr = lane & 15;
#pragma unroll
  for (int fm = 0; fm < 4; fm++) {
#pragma unroll
    for (int fn = 0; fn < 4; fn++) {
      int col = col0 + wn * 64 + fn * 16 + rr;
#pragma unroll
      for (int r = 0; r < 4; r++) {
        int row = row0 + wm * 64 + fm * 16 + rq * 4 + r;
        Cout[(long long)row * 8192 + col] = f2bf(acc[fm][fn][r]);
      }
    }
  }
}

// ---------------------------------------------------------------------------
// Row sum-of-squares of raw s -> squash scale scl[i] — round-5 verbatim.
// ---------------------------------------------------------------------------
__global__ __launch_bounds__(256) void rowsumsq_kernel(
    const unsigned short* __restrict__ Sm, float* __restrict__ scl) {
  __shared__ float red[4];
  long long base = (long long)blockIdx.x * 8192;
  int t = (int)threadIdx.x;
  float sq = 0.f;
#pragma unroll
  for (int r = 0; r < 4; r++) {
    i32x4 pk = *(const i32x4*)&Sm[base + (t + 256 * r) * 8];
#pragma unroll
    for (int e = 0; e < 4; e++) {
      unsigned int w = (unsigned int)pk[e];
      float f0 = bf2f(w & 0xffffu), f1 = bf2f(w >> 16);
      sq += f0 * f0 + f1 * f1;
    }
  }
  sq = blockSum(sq, red);
  if (t == 0) scl[blockIdx.x] = (sq / (1.f + sq)) / sqrtf(sq + SQ_EPS);
}

// ---------------------------------------------------------------------------
// b-update (bf16 MFMA, split-K=4, pure store) — round-5 verbatim.
// ---------------------------------------------------------------------------
__global__ __launch_bounds__(256) void gemm_b_bf16(
    const unsigned short* __restrict__ A,     // sv16 raw s
    const unsigned short* __restrict__ Bm,    // u16
    const float* __restrict__ scl, float* __restrict__ P) {
  int row0 = blockIdx.y * 64;
  int col0 = blockIdx.x * 64;
  if (col0 > row0) return;
  int ks = blockIdx.z;
  __shared__ unsigned short Asl[64][64];
  __shared__ unsigned short Bsl[64][64];
  int t = (int)threadIdx.x, lane = t & 63, wave = t >> 6;
  int wm = wave >> 1, wn = wave & 1;

  f32x4 acc[2][2];
#pragma unroll
  for (int i = 0; i < 2; i++)
#pragma unroll
    for (int j = 0; j < 2; j++) acc[i][j] = (f32x4){0.f, 0.f, 0.f, 0.f};

  int r = t >> 2, c0 = t & 3;
  int sw0 = ((c0 ^ (r & 7))) * 8;
  int sw1 = (((c0 + 4) ^ (r & 7))) * 8;
  const unsigned short* Ap = A + (long long)(row0 + r) * 8192 + ks * 2048 + c0 * 8;
  const unsigned short* Bp = Bm + (long long)(col0 + r) * 8192 + ks * 2048 + c0 * 8;

  for (int kb = 0; kb < 2048; kb += 64) {
    i32x4 a0 = *(const i32x4*)(Ap + kb);
    i32x4 a1 = *(const i32x4*)(Ap + kb + 32);
    i32x4 b0 = *(const i32x4*)(Bp + kb);
    i32x4 b1 = *(const i32x4*)(Bp + kb + 32);
    __syncthreads();
    *(i32x4*)&Asl[r][sw0] = a0;
    *(i32x4*)&Asl[r][sw1] = a1;
    *(i32x4*)&Bsl[r][sw0] = b0;
    *(i32x4*)&Bsl[r][sw1] = b1;
    __syncthreads();

    int rr = lane & 15, co = lane >> 4;
#pragma unroll
    for (int k2 = 0; k2 < 2; k2++) {
      int ch = ((k2 * 4 + co) ^ (rr & 7)) * 8;
      i32x4 af0 = *(i32x4*)&Asl[wm * 32 + rr][ch];
      i32x4 af1 = *(i32x4*)&Asl[wm * 32 + 16 + rr][ch];
      i32x4 bf0 = *(i32x4*)&Bsl[wn * 32 + rr][ch];
      i32x4 bf1 = *(i32x4*)&Bsl[wn * 32 + 16 + rr][ch];
      acc[0][0] = mfma_bf16(af0, bf0, acc[0][0]);
      acc[0][1] = mfma_bf16(af0, bf1, acc[0][1]);
      acc[1][0] = mfma_bf16(af1, bf0, acc[1][0]);
      acc[1][1] = mfma_bf16(af1, bf1, acc[1][1]);
    }
  }

  float* dst = P + (long long)ks * 1048576;
  int rq = lane >> 4, rr = lane & 15;
#pragma unroll
  for (int fm = 0; fm < 2; fm++) {
#pragma unroll
    for (int fn = 0; fn < 2; fn++) {
      int j = col0 + wn * 32 + fn * 16 + rr;
#pragma unroll
      for (int rl = 0; rl < 4; rl++) {
        int i = row0 + wm * 32 + fm * 16 + rq * 4 + rl;
        dst[(long long)i * 1024 + j] = scl[i] * acc[fm][fn][rl];
      }
    }
  }
}

// ---------------------------------------------------------------------------
// ctx (bf16 MFMA) — round-5 verbatim.
// ---------------------------------------------------------------------------
__global__ __launch_bounds__(256) void gemm_ctx_bf16(
    const unsigned short* __restrict__ w16,
    const unsigned short* __restrict__ VT, float* __restrict__ ctx) {
  int row0 = blockIdx.x * 64;
  int h = blockIdx.y;
  __shared__ unsigned short Asl[64][68];
  __shared__ unsigned short Bsl[64][68];
  int t = (int)threadIdx.x, lane = t & 63, wave = t >> 6;

  f32x4 acc[4];
#pragma unroll
  for (int i = 0; i < 4; i++) acc[i] = (f32x4){0.f, 0.f, 0.f, 0.f};

  int r = t >> 2, kq = (t & 3) * 8;
  const unsigned short* Ap = w16 + (long long)(row0 + r) * 8192 + h * 1024 + kq;
  const unsigned short* Bp = VT + (long long)(h * 64 + r) * 1024 + kq;

  for (int kb = 0; kb < 1024; kb += 64) {
    i32x4 a0 = *(const i32x4*)(Ap + kb);
    i32x4 a1 = *(const i32x4*)(Ap + kb + 32);
    i32x4 b0 = *(const i32x4*)(Bp + kb);
    i32x4 b1 = *(const i32x4*)(Bp + kb + 32);
    __syncthreads();
    *(i32x4*)&Asl[r][kq] = a0;
    *(i32x4*)&Asl[r][kq + 32] = a1;
    *(i32x4*)&Bsl[r][kq] = b0;
    *(i32x4*)&Bsl[r][kq + 32] = b1;
    __syncthreads();

    int rr = lane & 15, ko = (lane >> 4) * 8;
#pragma unroll
    for (int k2 = 0; k2 < 2; k2++) {
      i32x4 af = *(i32x4*)&Asl[wave * 16 + rr][k2 * 32 + ko];
#pragma unroll
      for (int fn = 0; fn < 4; fn++) {
        i32x4 bf = *(i32x4*)&Bsl[fn * 16 + rr][k2 * 32 + ko];
        acc[fn] = mfma_bf16(af, bf, acc[fn]);
      }
    }
  }

  int rq = lane >> 4, rr = lane & 15;
#pragma unroll
  for (int fn = 0; fn < 4; fn++) {
#pragma unroll
    for (int rl = 0; rl < 4; rl++) {
      int i = row0 + wave * 16 + rq * 4 + rl;
      ctx[(long long)i * 512 + h * 64 + fn * 16 + rr] = acc[fn][rl];
    }
  }
}

// ---------------------------------------------------------------------------
// Vertical routing (bf16 u in, 3 fused iters) -> vV f32 — round-5 verbatim.
// ---------------------------------------------------------------------------
__global__ __launch_bounds__(256) void vertical_routing_kernel(
    const unsigned short* __restrict__ u16, float* __restrict__ vV) {
  __shared__ float Ur[8 * 1024];
  __shared__ float red[4];
  __shared__ float red8[32];
  int bq = blockIdx.x;
  int t = (int)threadIdx.x;
  const unsigned short* Ub = u16 + (long long)bq * 8192;
#pragma unroll
  for (int r = 0; r < 8; r++) {
    uint2 p = *(const uint2*)&Ub[(t + 256 * r) * 4];
    Ur[(t + 256 * r) * 4 + 0] = bf2f(p.x & 0xffffu);
    Ur[(t + 256 * r) * 4 + 1] = bf2f(p.x >> 16);
    Ur[(t + 256 * r) * 4 + 2] = bf2f(p.y & 0xffffu);
    Ur[(t + 256 * r) * 4 + 3] = bf2f(p.y >> 16);
  }
  __syncthreads();

  float bh[8] = {0.f, 0.f, 0.f, 0.f, 0.f, 0.f, 0.f, 0.f};
  int k0 = t * 4;
  float4 v4 = {0.f, 0.f, 0.f, 0.f};
  for (int it = 0; it < 3; ++it) {
    float m = bh[0];
#pragma unroll
    for (int h = 1; h < 8; h++) m = fmaxf(m, bh[h]);
    float c[8], zz = 0.f;
#pragma unroll
    for (int h = 0; h < 8; h++) {
      c[h] = expf(bh[h] - m);
      zz += c[h];
    }
    float inv = 1.f / zz;
    float4 s4 = {0.f, 0.f, 0.f, 0.f};
#pragma unroll
    for (int h = 0; h < 8; h++) {
      float4 u = *(float4*)&Ur[h * 1024 + k0];
      float ch = c[h] * inv;
      s4.x = fmaf(ch, u.x, s4.x); s4.y = fmaf(ch, u.y, s4.y);
      s4.z = fmaf(ch, u.z, s4.z); s4.w = fmaf(ch, u.w, s4.w);
    }
    float sq =
        blockSum(s4.x * s4.x + s4.y * s4.y + s4.z * s4.z + s4.w * s4.w, red);
    float sc = (sq / (1.f + sq)) / sqrtf(sq + SQ_EPS);
    v4.x = sc * s4.x; v4.y = sc * s4.y; v4.z = sc * s4.z; v4.w = sc * s4.w;
    if (it < 2) {
      float p[8];
#pragma unroll
      for (int h = 0; h < 8; h++) {
        float4 u = *(float4*)&Ur[h * 1024 + k0];
        p[h] = u.x * v4.x + u.y * v4.y + u.z * v4.z + u.w * v4.w;
      }
      __syncthreads();
#pragma unroll
      for (int h = 0; h < 8; h++) {
        float w = wredSum(p[h]);
        if ((t & 63) == 0) red8[(t >> 6) * 8 + h] = w;
      }
      __syncthreads();
#pragma unroll
      for (int h = 0; h < 8; h++)
        bh[h] += red8[h] + red8[8 + h] + red8[16 + h] + red8[24 + h];
    }
  }
  *(float4*)&vV[(long long)bq * 1024 + k0] = v4;
}

// it=0 coupling — round-5 verbatim.
__global__ __launch_bounds__(256) void softmax_uniform_kernel(
    unsigned short* __restrict__ cH16) {
  int i = blockIdx.x;
  int t = (int)threadIdx.x, k0 = t * 4;
  unsigned short c = f2bf(1.f / (float)(i + 1));
  unsigned short e0 = (k0 + 0) <= i ? c : (unsigned short)0;
  unsigned short e1 = (k0 + 1) <= i ? c : (unsigned short)0;
  unsigned short e2 = (k0 + 2) <= i ? c : (unsigned short)0;
  unsigned short e3 = (k0 + 3) <= i ? c : (unsigned short)0;
  uint2 o = {(unsigned int)e0 | ((unsigned int)e1 << 16),
             (unsigned int)e2 | ((unsigned int)e3 << 16)};
  *(uint2*)&cH16[(long long)i * 1024 + k0] = o;
}

// bH (+)= sum_z P[z]; cH16 = causal softmax(bH) — round-5 verbatim.
template <int INIT>
__global__ __launch_bounds__(256) void add_softmax_kernel(
    float* __restrict__ bH, const float* __restrict__ P,
    unsigned short* __restrict__ cH16) {
  __shared__ float red[4];
  int i = blockIdx.x;
  long long base = (long long)i * 1024;
  int t = (int)threadIdx.x, k0 = t * 4;
  float4 x;
  if (INIT) x = (float4){0.f, 0.f, 0.f, 0.f};
  else x = *(const float4*)&bH[base + k0];
#pragma unroll
  for (int z = 0; z < 4; z++) {
    float4 p = *(const float4*)&P[(long long)z * 1048576 + base + k0];
    x.x += p.x; x.y += p.y; x.z += p.z; x.w += p.w;
  }
  *(float4*)&bH[base + k0] = x;
  bool m0 = (k0 + 0) <= i, m1 = (k0 + 1) <= i, m2 = (k0 + 2) <= i,
       m3 = (k0 + 3) <= i;
  float mx = -3.0e38f;
  if (m0) mx = fmaxf(mx, x.x);
  if (m1) mx = fmaxf(mx, x.y);
  if (m2) mx = fmaxf(mx, x.z);
  if (m3) mx = fmaxf(mx, x.w);
  mx = blockMax(mx, red);
  float e0 = m0 ? expf(x.x - mx) : 0.f;
  float e1 = m1 ? expf(x.y - mx) : 0.f;
  float e2 = m2 ? expf(x.z - mx) : 0.f;
  float e3 = m3 ? expf(x.w - mx) : 0.f;
  float zz = blockSum(e0 + e1 + e2 + e3, red);
  float inv = 1.f / zz;
  uint2 o = {(unsigned int)f2bf(e0 * inv) | ((unsigned int)f2bf(e1 * inv) << 16),
             (unsigned int)f2bf(e2 * inv) | ((unsigned int)f2bf(e3 * inv) << 16)};
  *(uint2*)&cH16[base + k0] = o;
}

// enhanced softmax -> w into u16 — round-5 verbatim.
__global__ __launch_bounds__(256) void enh_softmax_kernel(
    unsigned short* __restrict__ u16, const float* __restrict__ vV,
    const unsigned short* __restrict__ sv16, const float* __restrict__ scl) {
  __shared__ float red[4];
  int idx = blockIdx.x;  // Q*H
  int h = idx & 7;
  int bq = idx >> 3;
  unsigned short* Urow = u16 + (long long)bq * 8192 + h * 1024;
  const float* va = vV + (long long)bq * 1024;
  const unsigned short* vb = sv16 + (long long)bq * 8192 + h * 1024;
  float sc = scl[bq];
  int t = (int)threadIdx.x, k0 = t * 4;
  uint2 pu = *(const uint2*)&Urow[k0];
  float4 a = *(const float4*)&va[k0];
  uint2 pb = *(const uint2*)&vb[k0];
  float x0 = bf2f(pu.x & 0xffffu) + a.x + sc * bf2f(pb.x & 0xffffu);
  float x1 = bf2f(pu.x >> 16) + a.y + sc * bf2f(pb.x >> 16);
  float x2 = bf2f(pu.y & 0xffffu) + a.z + sc * bf2f(pb.y & 0xffffu);
  float x3 = bf2f(pu.y >> 16) + a.w + sc * bf2f(pb.y >> 16);
  float mx = blockMax(fmaxf(fmaxf(x0, x1), fmaxf(x2, x3)), red);
  float e0 = expf(x0 - mx), e1 = expf(x1 - mx), e2 = expf(x2 - mx),
        e3 = expf(x3 - mx);
  float zz = blockSum(e0 + e1 + e2 + e3, red);
  float inv = 1.f / zz;
  uint2 o = {(unsigned int)f2bf(e0 * inv) | ((unsigned int)f2bf(e1 * inv) << 16),
             (unsigned int)f2bf(e2 * inv) | ((unsigned int)f2bf(e3 * inv) << 16)};
  *(uint2*)&Urow[k0] = o;
}

// ---------------------------------------------------------------------------
extern "C" void kernel_launch(void* const* d_in, const int* in_sizes, int n_in,
                              void* d_out, int out_size, void* d_ws,
                              size_t ws_size, hipStream_t stream) {
  (void)in_sizes; (void)n_in; (void)out_size; (void)ws_size;
  const float* x = (const float*)d_in[0];
  const float* Wq = (const float*)d_in[1];
  const float* bq = (const float*)d_in[2];
  const float* Wk = (const float*)d_in[3];
  const float* bk = (const float*)d_in[4];
  const float* Wv = (const float*)d_in[5];
  const float* bv = (const float*)d_in[6];
  const float* Wo = (const float*)d_in[7];
  const float* bo = (const float*)d_in[8];
  float* out = (float*)d_out;
  float* ws = (float*)d_ws;

  unsigned short* u16 = (unsigned short*)(ws);               // 4,194,304 fl
  unsigned short* uT16 = (unsigned short*)(ws + 4194304);    // 4,194,304 fl
  unsigned short* sv16 = (unsigned short*)(ws + 8388608);    // 4,194,304 fl
  float* Qf = ws + 12582912;                                 // 2,097,152
  float* Kf = ws + 14680064;                                 // 2,097,152
  unsigned short* V16a = (unsigned short*)(ws + 16777216);   // 1,048,576 fl
  unsigned short* VT16a = (unsigned short*)(ws + 17825792);  // 1,048,576 fl
  unsigned short* WT16 = (unsigned short*)(ws + 18874368);   //   393,216 fl
  float* ctxa = ws + 19267584;                               // 2,097,152
  float* vV = ws + 21364736;                                 // 1,048,576
  float* bH = ws + 22413312;                                 // 1,048,576
  float* P = ws + 23461888;                                  // 4,194,304
  unsigned short* cH16 = (unsigned short*)(ws + 27656192);   //   524,288 fl
  float* scl = ws + 28180480;                                //     1,024
  // total 28,181,504 floats = 107.5 MiB

  // ---- prologue (all batches) ----
  wtrans_kernel<<<dim3(8, 8, 3), 256, 0, stream>>>(Wq, Wk, Wv, WT16);
  gemm_qkv_mfma<<<dim3(8, 64, 3), 256, 0, stream>>>(x, WT16, bq, bk, bv, Qf,
                                                    Kf, V16a);
  for (int b = 0; b < 4; ++b)
    transpose16_kernel<<<dim3(16, 8), 256, 0, stream>>>(
        V16a + (long long)b * 524288, VT16a + (long long)b * 524288, 512, 1024);

  // ---- per-batch routing ----
  for (int b = 0; b < 4; ++b) {
    const float* qf = Qf + (long long)b * 524288;
    const float* kf = Kf + (long long)b * 524288;

    gemm_scores_bf16<<<dim3(8, 8, 8), 256, 0, stream>>>(qf, kf, u16);
    transpose16_kernel<<<dim3(16, 128), 256, 0, stream>>>(u16, uT16, 8192,
                                                          1024);
    vertical_routing_kernel<<<dim3(1024), 256, 0, stream>>>(u16, vV);

    softmax_uniform_kernel<<<dim3(1024), 256, 0, stream>>>(cH16);
    gemm_s_bf16<<<dim3(64, 8), 256, 0, stream>>>(cH16, uT16, sv16);
    rowsumsq_kernel<<<dim3(1024), 256, 0, stream>>>(sv16, scl);
    gemm_b_bf16<<<dim3(16, 16, 4), 256, 0, stream>>>(sv16, u16, scl, P);

    add_softmax_kernel<1><<<dim3(1024), 256, 0, stream>>>(bH, P, cH16);
    gemm_s_bf16<<<dim3(64, 8), 256, 0, stream>>>(cH16, uT16, sv16);
    rowsumsq_kernel<<<dim3(1024), 256, 0, stream>>>(sv16, scl);
    gemm_b_bf16<<<dim3(16, 16, 4), 256, 0, stream>>>(sv16, u16, scl, P);

    add_softmax_kernel<0><<<dim3(1024), 256, 0, stream>>>(bH, P, cH16);
    gemm_s_bf16<<<dim3(64, 8), 256, 0, stream>>>(cH16, uT16, sv16);
    rowsumsq_kernel<<<dim3(1024), 256, 0, stream>>>(sv16, scl);

    enh_softmax_kernel<<<dim3(8192), 256, 0, stream>>>(u16, vV, sv16, scl);
    gemm_ctx_bf16<<<dim3(16, 8), 256, 0, stream>>>(
        u16, VT16a + (long long)b * 524288, ctxa + (long long)b * 524288);
  }

  // ---- epilogue: out = ctx x Wo + bo (all batches) ----
  gemm_f32<64, 64, 16><<<dim3(8, 64), 256, 0, stream>>>(ctxa, Wo, out, bo, 512,
                                                        512, 512, 512);
}

// Round 8
// 798.385 us; speedup vs baseline: 8.6889x; 1.2090x over previous
//
#include <hip/hip_runtime.h>
#include <math.h>

// ---------------------------------------------------------------------------
// CapsuleRoutingSelfAttention — round 8: Gram-matrix reformulation of
// horizontal routing.  b += v·u^T == scl·(C·G) with G = u·u^T computed once;
// ||s||^2 == rowdot(C, C·G).  s materialized only once (final iteration).
// All kernels are proven molds (round 5/7) or strict instantiations thereof.
//
// Workspace (float units), total 29,754,368 fl = 113.5 MiB (ws = 256 MiB).
// ---------------------------------------------------------------------------

#define SQ_EPS 1e-8f

typedef __attribute__((ext_vector_type(4))) int i32x4;    // 8 bf16
typedef __attribute__((ext_vector_type(4))) float f32x4;

__device__ __forceinline__ float bf2f(unsigned int u) {
  union { unsigned int i; float f; } x;
  x.i = u << 16;
  return x.f;
}
__device__ __forceinline__ unsigned short f2bf(float f) {
  union { float f; unsigned int i; } x;
  x.f = f;
  unsigned int r = x.i + 0x7fffu + ((x.i >> 16) & 1u);
  return (unsigned short)(r >> 16);
}
__device__ __forceinline__ int packbf(float a, float b) {
  return (int)((unsigned int)f2bf(a) | ((unsigned int)f2bf(b) << 16));
}

__device__ __forceinline__ f32x4 mfma_bf16(i32x4 a, i32x4 b, f32x4 c) {
  asm("v_mfma_f32_16x16x32_bf16 %0, %1, %2, %0" : "+v"(c) : "v"(a), "v"(b));
  return c;
}

__device__ __forceinline__ float wredSum(float v) {
#pragma unroll
  for (int off = 32; off > 0; off >>= 1) v += __shfl_xor(v, off);
  return v;
}
__device__ __forceinline__ float wredMax(float v) {
#pragma unroll
  for (int off = 32; off > 0; off >>= 1) v = fmaxf(v, __shfl_xor(v, off));
  return v;
}
__device__ __forceinline__ float blockSum(float v, volatile float* red) {
  v = wredSum(v);
  int wid = threadIdx.x >> 6;
  __syncthreads();
  if ((threadIdx.x & 63) == 0) red[wid] = v;
  __syncthreads();
  return red[0] + red[1] + red[2] + red[3];
}
__device__ __forceinline__ float blockMax(float v, volatile float* red) {
  v = wredMax(v);
  int wid = threadIdx.x >> 6;
  __syncthreads();
  if ((threadIdx.x & 63) == 0) red[wid] = v;
  __syncthreads();
  return fmaxf(fmaxf(red[0], red[1]), fmaxf(red[2], red[3]));
}

// ---------------------------------------------------------------------------
// W^T prep — round-7 verbatim.
// ---------------------------------------------------------------------------
__global__ __launch_bounds__(256) void wtrans_kernel(
    const float* __restrict__ Wq, const float* __restrict__ Wk,
    const float* __restrict__ Wv, unsigned short* __restrict__ WT16) {
  __shared__ unsigned short T[64][72];
  int z = blockIdx.z;
  const float* src = (z == 0) ? Wq : (z == 1) ? Wk : Wv;
  unsigned short* dst = WT16 + (long long)z * 262144;
  int i0 = blockIdx.x * 64;
  int c0 = blockIdx.y * 64;
  int t = (int)threadIdx.x;
  int r = t >> 2, cq = (t & 3) * 16;
#pragma unroll
  for (int j = 0; j < 4; j++) {
    float4 v = *(const float4*)&src[(long long)(i0 + r) * 512 + c0 + cq + j * 4];
    T[r][cq + j * 4 + 0] = f2bf(v.x);
    T[r][cq + j * 4 + 1] = f2bf(v.y);
    T[r][cq + j * 4 + 2] = f2bf(v.z);
    T[r][cq + j * 4 + 3] = f2bf(v.w);
  }
  __syncthreads();
  int c = t >> 2, iq = (t & 3) * 16;
  unsigned short tmp[16];
#pragma unroll
  for (int j = 0; j < 16; j++) tmp[j] = T[iq + j][c];
  *(i32x4*)&dst[(long long)(c0 + c) * 512 + i0 + iq] = *(i32x4*)&tmp[0];
  *(i32x4*)&dst[(long long)(c0 + c) * 512 + i0 + iq + 8] = *(i32x4*)&tmp[8];
}

// ---------------------------------------------------------------------------
// QKV (bf16 MFMA, all batches) — round-7 verbatim.
// ---------------------------------------------------------------------------
__global__ __launch_bounds__(256) void gemm_qkv_mfma(
    const float* __restrict__ x, const unsigned short* __restrict__ WT16,
    const float* __restrict__ bq, const float* __restrict__ bk,
    const float* __restrict__ bv, float* __restrict__ Qf,
    float* __restrict__ Kf, unsigned short* __restrict__ V16) {
  __shared__ unsigned short Asl[64][68];
  __shared__ unsigned short Bsl[64][68];
  int z = blockIdx.z;
  const unsigned short* WT = WT16 + (long long)z * 262144;
  const float* bias = (z == 0) ? bq : (z == 1) ? bk : bv;

  int row0 = blockIdx.y * 64;
  int col0 = blockIdx.x * 64;
  int t = (int)threadIdx.x, lane = t & 63, wave = t >> 6;
  int wm = wave >> 1, wn = wave & 1;

  f32x4 acc[2][2];
#pragma unroll
  for (int i = 0; i < 2; i++)
#pragma unroll
    for (int j = 0; j < 2; j++) acc[i][j] = (f32x4){0.f, 0.f, 0.f, 0.f};

  int r = t >> 2, kq = (t & 3) * 8;
  const float* Ap = x + (long long)(row0 + r) * 512 + kq;
  const unsigned short* Bp = WT + (long long)(col0 + r) * 512 + kq;

  for (int kb = 0; kb < 512; kb += 64) {
    float4 a0 = *(const float4*)(Ap + kb);
    float4 a1 = *(const float4*)(Ap + kb + 4);
    float4 a2 = *(const float4*)(Ap + kb + 32);
    float4 a3 = *(const float4*)(Ap + kb + 36);
    i32x4 b0 = *(const i32x4*)(Bp + kb);
    i32x4 b1 = *(const i32x4*)(Bp + kb + 32);
    __syncthreads();
    i32x4 pa0 = {packbf(a0.x, a0.y), packbf(a0.z, a0.w), packbf(a1.x, a1.y),
                 packbf(a1.z, a1.w)};
    i32x4 pa1 = {packbf(a2.x, a2.y), packbf(a2.z, a2.w), packbf(a3.x, a3.y),
                 packbf(a3.z, a3.w)};
    *(i32x4*)&Asl[r][kq] = pa0;
    *(i32x4*)&Asl[r][kq + 32] = pa1;
    *(i32x4*)&Bsl[r][kq] = b0;
    *(i32x4*)&Bsl[r][kq + 32] = b1;
    __syncthreads();

    int rr = lane & 15, ko = (lane >> 4) * 8;
#pragma unroll
    for (int k2 = 0; k2 < 2; k2++) {
      i32x4 af0 = *(i32x4*)&Asl[wm * 32 + rr][k2 * 32 + ko];
      i32x4 af1 = *(i32x4*)&Asl[wm * 32 + 16 + rr][k2 * 32 + ko];
      i32x4 bf0 = *(i32x4*)&Bsl[wn * 32 + rr][k2 * 32 + ko];
      i32x4 bf1 = *(i32x4*)&Bsl[wn * 32 + 16 + rr][k2 * 32 + ko];
      acc[0][0] = mfma_bf16(af0, bf0, acc[0][0]);
      acc[0][1] = mfma_bf16(af0, bf1, acc[0][1]);
      acc[1][0] = mfma_bf16(af1, bf0, acc[1][0]);
      acc[1][1] = mfma_bf16(af1, bf1, acc[1][1]);
    }
  }

  int rq = lane >> 4, rr = lane & 15;
#pragma unroll
  for (int fm = 0; fm < 2; fm++) {
#pragma unroll
    for (int fn = 0; fn < 2; fn++) {
      int col = col0 + wn * 32 + fn * 16 + rr;
      float bb = bias[col];
#pragma unroll
      for (int rl = 0; rl < 4; rl++) {
        int row = row0 + wm * 32 + fm * 16 + rq * 4 + rl;
        float v = acc[fm][fn][rl] + bb;
        if (z == 2)
          V16[(long long)row * 512 + col] = f2bf(v);
        else if (z == 1)
          Kf[(long long)row * 512 + col] = v;
        else
          Qf[(long long)row * 512 + col] = v;
      }
    }
  }
}

// ---------------------------------------------------------------------------
// Scores (fp32 compute, bf16 out) — round-7 verbatim.
// ---------------------------------------------------------------------------
__global__ __launch_bounds__(256) void gemm_scores_bf16(
    const float* __restrict__ Qb, const float* __restrict__ Kb,
    unsigned short* __restrict__ u16) {
  __shared__ float As[8][132];
  __shared__ float Bs[8][132];
  int h = blockIdx.z;
  const float* A = Qb + h * 64;
  const float* B = Kb + h * 64;
  unsigned short* C16 = u16 + h * 1024;

  int row0 = blockIdx.y * 128;
  int col0 = blockIdx.x * 128;
  int tid = (int)threadIdx.x;
  int tx = tid & 15, ty = tid >> 4;
  int arow = tid >> 1;
  int akc = (tid & 1) * 4;

  float acc[8][8];
#pragma unroll
  for (int i = 0; i < 8; i++)
#pragma unroll
    for (int j = 0; j < 8; j++) acc[i][j] = 0.f;

  const float* Aptr = A + (long long)(row0 + arow) * 512 + akc;
  const float* Bptr = B + (long long)(col0 + arow) * 512 + akc;

  for (int kb = 0; kb < 64; kb += 8) {
    float4 av = *(const float4*)(Aptr + kb);
    float4 bv = *(const float4*)(Bptr + kb);
    __syncthreads();
    As[akc + 0][arow] = av.x; As[akc + 1][arow] = av.y;
    As[akc + 2][arow] = av.z; As[akc + 3][arow] = av.w;
    Bs[akc + 0][arow] = bv.x; Bs[akc + 1][arow] = bv.y;
    Bs[akc + 2][arow] = bv.z; Bs[akc + 3][arow] = bv.w;
    __syncthreads();

#pragma unroll
    for (int k = 0; k < 8; k++) {
      float a[8], b[8];
#pragma unroll
      for (int c = 0; c < 2; c++) {
        float4 q = *(float4*)&As[k][ty * 8 + c * 4];
        a[c * 4 + 0] = q.x; a[c * 4 + 1] = q.y;
        a[c * 4 + 2] = q.z; a[c * 4 + 3] = q.w;
      }
#pragma unroll
      for (int c = 0; c < 2; c++) {
        float4 q = *(float4*)&Bs[k][c * 64 + tx * 4];
        b[c * 4 + 0] = q.x; b[c * 4 + 1] = q.y;
        b[c * 4 + 2] = q.z; b[c * 4 + 3] = q.w;
      }
#pragma unroll
      for (int i = 0; i < 8; i++)
#pragma unroll
        for (int j = 0; j < 8; j++) acc[i][j] = fmaf(a[i], b[j], acc[i][j]);
    }
  }

#pragma unroll
  for (int i = 0; i < 8; i++) {
    long long r = row0 + ty * 8 + i;
#pragma unroll
    for (int c = 0; c < 2; c++) {
      int col = col0 + c * 64 + tx * 4;
      unsigned int lo = (unsigned int)f2bf(0.125f * acc[i][c * 4 + 0]) |
                        ((unsigned int)f2bf(0.125f * acc[i][c * 4 + 1]) << 16);
      unsigned int hi = (unsigned int)f2bf(0.125f * acc[i][c * 4 + 2]) |
                        ((unsigned int)f2bf(0.125f * acc[i][c * 4 + 3]) << 16);
      uint2 o = {lo, hi};
      *(uint2*)&C16[r * 8192 + col] = o;
    }
  }
}

// ---------------------------------------------------------------------------
// fp32 tiled GEMM (out-projection) — round-7 verbatim.
// ---------------------------------------------------------------------------
template <int BM, int BN, int BK>
__global__ __launch_bounds__(256) void gemm_f32(
    const float* __restrict__ A, const float* __restrict__ B,
    float* __restrict__ C, const float* __restrict__ bias,
    int K, int lda, int ldb, int ldc) {
  constexpr int TM = BM / 16;
  constexpr int TN = BN / 16;
  __shared__ float As[BK][BM + 4];
  __shared__ float Bs[BK][BN + 4];

  int row0 = blockIdx.y * BM;
  int col0 = blockIdx.x * BN;
  int tid = (int)threadIdx.x;
  int tx = tid & 15, ty = tid >> 4;

  constexpr int AKC = BK / 4;
  int arow = tid / AKC;
  int akc = (tid - arow * AKC) * 4;
  int brow = tid / (BN / 4);
  int bcol = (tid - brow * (BN / 4)) * 4;

  float acc[TM][TN];
#pragma unroll
  for (int i = 0; i < TM; i++)
#pragma unroll
    for (int j = 0; j < TN; j++) acc[i][j] = 0.f;

  const float* Aptr = A + (long long)(row0 + arow) * lda + akc;
  const float* Bptr = B + (long long)brow * ldb + col0 + bcol;

  for (int kb = 0; kb < K; kb += BK) {
    float4 av = *(const float4*)(Aptr + kb);
    float4 bv = *(const float4*)(Bptr + (long long)kb * ldb);
    __syncthreads();
    As[akc + 0][arow] = av.x;
    As[akc + 1][arow] = av.y;
    As[akc + 2][arow] = av.z;
    As[akc + 3][arow] = av.w;
    *(float4*)&Bs[brow][bcol] = bv;
    __syncthreads();

#pragma unroll
    for (int k = 0; k < BK; k++) {
      float a[TM], b[TN];
#pragma unroll
      for (int c = 0; c < TM / 4; c++) {
        float4 q = *(float4*)&As[k][ty * TM + c * 4];
        a[c * 4 + 0] = q.x; a[c * 4 + 1] = q.y;
        a[c * 4 + 2] = q.z; a[c * 4 + 3] = q.w;
      }
#pragma unroll
      for (int c = 0; c < TN / 4; c++) {
        float4 q = *(float4*)&Bs[k][c * 64 + tx * 4];
        b[c * 4 + 0] = q.x; b[c * 4 + 1] = q.y;
        b[c * 4 + 2] = q.z; b[c * 4 + 3] = q.w;
      }
#pragma unroll
      for (int i = 0; i < TM; i++)
#pragma unroll
        for (int j = 0; j < TN; j++) acc[i][j] = fmaf(a[i], b[j], acc[i][j]);
    }
  }

#pragma unroll
  for (int i = 0; i < TM; i++) {
    long long r = row0 + ty * TM + i;
#pragma unroll
    for (int c = 0; c < TN / 4; c++) {
      int col = col0 + c * 64 + tx * 4;
      float4 val = {acc[i][c * 4 + 0], acc[i][c * 4 + 1], acc[i][c * 4 + 2],
                    acc[i][c * 4 + 3]};
      if (bias) {
        float4 bb = *(const float4*)&bias[col];
        val.x += bb.x; val.y += bb.y; val.z += bb.z; val.w += bb.w;
      }
      *(float4*)&C[r * ldc + col] = val;
    }
  }
}

// ---------------------------------------------------------------------------
// bf16 -> bf16 transpose, 64x64 tiles — round-7 verbatim.
// ---------------------------------------------------------------------------
__global__ __launch_bounds__(256) void transpose16_kernel(
    const unsigned short* __restrict__ src, unsigned short* __restrict__ dst,
    int ldS, int ldD) {
  __shared__ unsigned short T[64][72];
  int i0 = blockIdx.x * 64;
  int c0 = blockIdx.y * 64;
  int t = (int)threadIdx.x;
  int r = t >> 2, cq = (t & 3) * 16;
  i32x4 v0 = *(const i32x4*)&src[(long long)(i0 + r) * ldS + c0 + cq];
  i32x4 v1 = *(const i32x4*)&src[(long long)(i0 + r) * ldS + c0 + cq + 8];
  *(i32x4*)&T[r][cq] = v0;
  *(i32x4*)&T[r][cq + 8] = v1;
  __syncthreads();
  int c = t >> 2, iq = (t & 3) * 16;
  unsigned short tmp[16];
#pragma unroll
  for (int j = 0; j < 16; j++) tmp[j] = T[iq + j][c];
  *(i32x4*)&dst[(long long)(c0 + c) * ldD + i0 + iq] = *(i32x4*)&tmp[0];
  *(i32x4*)&dst[(long long)(c0 + c) * ldD + i0 + iq + 8] = *(i32x4*)&tmp[8];
}

// ---------------------------------------------------------------------------
// G = u·u^T (bf16 MFMA, split-K=4, full square): P[ks][i,j] =
//   sum_{c in chunk ks} u[i,c]·u[j,c].  gemm_b mold, A=B=u16, no scl.
// Grid (16, 16, 4).
// ---------------------------------------------------------------------------
__global__ __launch_bounds__(256) void gemm_G_bf16(
    const unsigned short* __restrict__ U, float* __restrict__ P) {
  int row0 = blockIdx.y * 64;
  int col0 = blockIdx.x * 64;
  int ks = blockIdx.z;
  __shared__ unsigned short Asl[64][64];
  __shared__ unsigned short Bsl[64][64];
  int t = (int)threadIdx.x, lane = t & 63, wave = t >> 6;
  int wm = wave >> 1, wn = wave & 1;

  f32x4 acc[2][2];
#pragma unroll
  for (int i = 0; i < 2; i++)
#pragma unroll
    for (int j = 0; j < 2; j++) acc[i][j] = (f32x4){0.f, 0.f, 0.f, 0.f};

  int r = t >> 2, c0 = t & 3;
  int sw0 = ((c0 ^ (r & 7))) * 8;
  int sw1 = (((c0 + 4) ^ (r & 7))) * 8;
  const unsigned short* Ap = U + (long long)(row0 + r) * 8192 + ks * 2048 + c0 * 8;
  const unsigned short* Bp = U + (long long)(col0 + r) * 8192 + ks * 2048 + c0 * 8;

  for (int kb = 0; kb < 2048; kb += 64) {
    i32x4 a0 = *(const i32x4*)(Ap + kb);
    i32x4 a1 = *(const i32x4*)(Ap + kb + 32);
    i32x4 b0 = *(const i32x4*)(Bp + kb);
    i32x4 b1 = *(const i32x4*)(Bp + kb + 32);
    __syncthreads();
    *(i32x4*)&Asl[r][sw0] = a0;
    *(i32x4*)&Asl[r][sw1] = a1;
    *(i32x4*)&Bsl[r][sw0] = b0;
    *(i32x4*)&Bsl[r][sw1] = b1;
    __syncthreads();

    int rr = lane & 15, co = lane >> 4;
#pragma unroll
    for (int k2 = 0; k2 < 2; k2++) {
      int ch = ((k2 * 4 + co) ^ (rr & 7)) * 8;
      i32x4 af0 = *(i32x4*)&Asl[wm * 32 + rr][ch];
      i32x4 af1 = *(i32x4*)&Asl[wm * 32 + 16 + rr][ch];
      i32x4 bf0 = *(i32x4*)&Bsl[wn * 32 + rr][ch];
      i32x4 bf1 = *(i32x4*)&Bsl[wn * 32 + 16 + rr][ch];
      acc[0][0] = mfma_bf16(af0, bf0, acc[0][0]);
      acc[0][1] = mfma_bf16(af0, bf1, acc[0][1]);
      acc[1][0] = mfma_bf16(af1, bf0, acc[1][0]);
      acc[1][1] = mfma_bf16(af1, bf1, acc[1][1]);
    }
  }

  float* dst = P + (long long)ks * 1048576;
  int rq = lane >> 4, rr = lane & 15;
#pragma unroll
  for (int fm = 0; fm < 2; fm++) {
#pragma unroll
    for (int fn = 0; fn < 2; fn++) {
      int j = col0 + wn * 32 + fn * 16 + rr;
#pragma unroll
      for (int rl = 0; rl < 4; rl++) {
        int i = row0 + wm * 32 + fm * 16 + rq * 4 + rl;
        dst[(long long)i * 1024 + j] = acc[fm][fn][rl];
      }
    }
  }
}

// G16 = bf16(sum_z P[z]).  Grid 1024.
__global__ __launch_bounds__(256) void merge_G_kernel(
    const float* __restrict__ P, unsigned short* __restrict__ G16) {
  int i = blockIdx.x;
  int t = (int)threadIdx.x, j0 = t * 4;
  long long base = (long long)i * 1024;
  float4 s = {0.f, 0.f, 0.f, 0.f};
#pragma unroll
  for (int z = 0; z < 4; z++) {
    float4 p = *(const float4*)&P[(long long)z * 1048576 + base + j0];
    s.x += p.x; s.y += p.y; s.z += p.z; s.w += p.w;
  }
  uint2 o = {(unsigned int)f2bf(s.x) | ((unsigned int)f2bf(s.y) << 16),
             (unsigned int)f2bf(s.z) | ((unsigned int)f2bf(s.w) << 16)};
  *(uint2*)&G16[base + j0] = o;
}

// ---------------------------------------------------------------------------
// M = C·G (bf16 MFMA): M[i,j] = sum_{k<=i} c[i,k]·G[j,k]   (G symmetric).
// gemm_b mold with lda=ldb=1024, Kend=row0+64, single-z, fp32 store.
// Skip blocks above the diagonal (M needed for j<=i only). Grid (16,16).
// ---------------------------------------------------------------------------
__global__ __launch_bounds__(256) void gemm_M_bf16(
    const unsigned short* __restrict__ C,     // cH16
    const unsigned short* __restrict__ G,     // G16
    float* __restrict__ M) {
  int row0 = blockIdx.y * 64;
  int col0 = blockIdx.x * 64;
  if (col0 > row0) return;
  int Kend = row0 + 64;
  __shared__ unsigned short Asl[64][64];
  __shared__ unsigned short Bsl[64][64];
  int t = (int)threadIdx.x, lane = t & 63, wave = t >> 6;
  int wm = wave >> 1, wn = wave & 1;

  f32x4 acc[2][2];
#pragma unroll
  for (int i = 0; i < 2; i++)
#pragma unroll
    for (int j = 0; j < 2; j++) acc[i][j] = (f32x4){0.f, 0.f, 0.f, 0.f};

  int r = t >> 2, c0 = t & 3;
  int sw0 = ((c0 ^ (r & 7))) * 8;
  int sw1 = (((c0 + 4) ^ (r & 7))) * 8;
  const unsigned short* Ap = C + (long long)(row0 + r) * 1024 + c0 * 8;
  const unsigned short* Bp = G + (long long)(col0 + r) * 1024 + c0 * 8;

  for (int kb = 0; kb < Kend; kb += 64) {
    i32x4 a0 = *(const i32x4*)(Ap + kb);
    i32x4 a1 = *(const i32x4*)(Ap + kb + 32);
    i32x4 b0 = *(const i32x4*)(Bp + kb);
    i32x4 b1 = *(const i32x4*)(Bp + kb + 32);
    __syncthreads();
    *(i32x4*)&Asl[r][sw0] = a0;
    *(i32x4*)&Asl[r][sw1] = a1;
    *(i32x4*)&Bsl[r][sw0] = b0;
    *(i32x4*)&Bsl[r][sw1] = b1;
    __syncthreads();

    int rr = lane & 15, co = lane >> 4;
#pragma unroll
    for (int k2 = 0; k2 < 2; k2++) {
      int ch = ((k2 * 4 + co) ^ (rr & 7)) * 8;
      i32x4 af0 = *(i32x4*)&Asl[wm * 32 + rr][ch];
      i32x4 af1 = *(i32x4*)&Asl[wm * 32 + 16 + rr][ch];
      i32x4 bf0 = *(i32x4*)&Bsl[wn * 32 + rr][ch];
      i32x4 bf1 = *(i32x4*)&Bsl[wn * 32 + 16 + rr][ch];
      acc[0][0] = mfma_bf16(af0, bf0, acc[0][0]);
      acc[0][1] = mfma_bf16(af0, bf1, acc[0][1]);
      acc[1][0] = mfma_bf16(af1, bf0, acc[1][0]);
      acc[1][1] = mfma_bf16(af1, bf1, acc[1][1]);
    }
  }

  int rq = lane >> 4, rr = lane & 15;
#pragma unroll
  for (int fm = 0; fm < 2; fm++) {
#pragma unroll
    for (int fn = 0; fn < 2; fn++) {
      int j = col0 + wn * 32 + fn * 16 + rr;
#pragma unroll
      for (int rl = 0; rl < 4; rl++) {
        int i = row0 + wm * 32 + fm * 16 + rq * 4 + rl;
        M[(long long)i * 1024 + j] = acc[fm][fn][rl];
      }
    }
  }
}

// ||s_i||^2 = sum_{j<=i} c[i,j]·M[i,j]  ->  scl[i].  Grid 1024.
__global__ __launch_bounds__(256) void scldot_kernel(
    const float* __restrict__ M, const unsigned short* __restrict__ C,
    float* __restrict__ scl) {
  __shared__ float red[4];
  int i = blockIdx.x;
  int t = (int)threadIdx.x, j0 = t * 4;
  long long base = (long long)i * 1024;
  float4 m = *(const float4*)&M[base + j0];
  uint2 pc = *(const uint2*)&C[base + j0];
  float c0 = bf2f(pc.x & 0xffffu), c1 = bf2f(pc.x >> 16);
  float c2 = bf2f(pc.y & 0xffffu), c3 = bf2f(pc.y >> 16);
  float acc = 0.f;
  if (j0 + 0 <= i) acc += c0 * m.x;
  if (j0 + 1 <= i) acc += c1 * m.y;
  if (j0 + 2 <= i) acc += c2 * m.z;
  if (j0 + 3 <= i) acc += c3 * m.w;
  float ssq = blockSum(acc, red);
  if (t == 0) scl[i] = (ssq / (1.f + ssq)) / sqrtf(ssq + SQ_EPS);
}

// it=0 coupling — round-7 verbatim.
__global__ __launch_bounds__(256) void softmax_uniform_kernel(
    unsigned short* __restrict__ cH16) {
  int i = blockIdx.x;
  int t = (int)threadIdx.x, k0 = t * 4;
  unsigned short c = f2bf(1.f / (float)(i + 1));
  unsigned short e0 = (k0 + 0) <= i ? c : (unsigned short)0;
  unsigned short e1 = (k0 + 1) <= i ? c : (unsigned short)0;
  unsigned short e2 = (k0 + 2) <= i ? c : (unsigned short)0;
  unsigned short e3 = (k0 + 3) <= i ? c : (unsigned short)0;
  uint2 o = {(unsigned int)e0 | ((unsigned int)e1 << 16),
             (unsigned int)e2 | ((unsigned int)e3 << 16)};
  *(uint2*)&cH16[(long long)i * 1024 + k0] = o;
}

// bH (+)= scl[i]·M[i,j] (masked j<=i); cH16 = causal softmax(bH).
// add_softmax mold with the P-sum replaced by scl·M.  Grid 1024.
template <int INIT>
__global__ __launch_bounds__(256) void bupd_softmax_kernel(
    float* __restrict__ bH, const float* __restrict__ M,
    const float* __restrict__ scl, unsigned short* __restrict__ cH16) {
  __shared__ float red[4];
  int i = blockIdx.x;
  long long base = (long long)i * 1024;
  int t = (int)threadIdx.x, k0 = t * 4;
  float sc = scl[i];
  float4 x;
  if (INIT) x = (float4){0.f, 0.f, 0.f, 0.f};
  else x = *(const float4*)&bH[base + k0];
  float4 m = *(const float4*)&M[base + k0];
  bool m0 = (k0 + 0) <= i, m1 = (k0 + 1) <= i, m2 = (k0 + 2) <= i,
       m3 = (k0 + 3) <= i;
  if (m0) x.x += sc * m.x;
  if (m1) x.y += sc * m.y;
  if (m2) x.z += sc * m.z;
  if (m3) x.w += sc * m.w;
  *(float4*)&bH[base + k0] = x;
  float mx = -3.0e38f;
  if (m0) mx = fmaxf(mx, x.x);
  if (m1) mx = fmaxf(mx, x.y);
  if (m2) mx = fmaxf(mx, x.z);
  if (m3) mx = fmaxf(mx, x.w);
  mx = blockMax(mx, red);
  float e0 = m0 ? expf(x.x - mx) : 0.f;
  float e1 = m1 ? expf(x.y - mx) : 0.f;
  float e2 = m2 ? expf(x.z - mx) : 0.f;
  float e3 = m3 ? expf(x.w - mx) : 0.f;
  float zz = blockSum(e0 + e1 + e2 + e3, red);
  float inv = 1.f / zz;
  uint2 o = {(unsigned int)f2bf(e0 * inv) | ((unsigned int)f2bf(e1 * inv) << 16),
             (unsigned int)f2bf(e2 * inv) | ((unsigned int)f2bf(e3 * inv) << 16)};
  *(uint2*)&cH16[base + k0] = o;
}

// ---------------------------------------------------------------------------
// Final v: sv16[i,c] = scl[i] · sum_j c[i,j]·u[j,c] — gemm_s mold + scl
// epilogue.  Grid (64, 8).
// ---------------------------------------------------------------------------
__global__ __launch_bounds__(256) void gemm_s_scl(
    const unsigned short* __restrict__ Abf,   // cH16
    const unsigned short* __restrict__ BT,    // uT16
    const float* __restrict__ scl, unsigned short* __restrict__ Cout) {
  __shared__ unsigned short Alds[128][32];
  __shared__ unsigned short Blds[128][32];
  int rowblk = 7 - (int)blockIdx.y;
  int row0 = rowblk * 128;
  int col0 = blockIdx.x * 128;
  int t = (int)threadIdx.x, lane = t & 63, wave = t >> 6;
  int wm = wave >> 1, wn = wave & 1;
  int Kend = row0 + 128;

  f32x4 acc[4][4];
#pragma unroll
  for (int i = 0; i < 4; i++)
#pragma unroll
    for (int j = 0; j < 4; j++) acc[i][j] = (f32x4){0.f, 0.f, 0.f, 0.f};

  int ar = t >> 2;
  int aq = (t & 3) * 8;

  for (int kb = 0; kb < Kend; kb += 32) {
    i32x4 a0 = *(const i32x4*)&Abf[(long long)(row0 + ar) * 1024 + kb + aq];
    i32x4 a1 = *(const i32x4*)&Abf[(long long)(row0 + ar + 64) * 1024 + kb + aq];
    i32x4 b0 = *(const i32x4*)&BT[(long long)(col0 + ar) * 1024 + kb + aq];
    i32x4 b1 = *(const i32x4*)&BT[(long long)(col0 + ar + 64) * 1024 + kb + aq];
    __syncthreads();
    *(i32x4*)&Alds[ar][aq] = a0;
    *(i32x4*)&Alds[ar + 64][aq] = a1;
    *(i32x4*)&Blds[ar][aq] = b0;
    *(i32x4*)&Blds[ar + 64][aq] = b1;
    __syncthreads();

    int rr = lane & 15, koff = (lane >> 4) * 8;
    i32x4 af[4], bfv[4];
#pragma unroll
    for (int fm = 0; fm < 4; fm++)
      af[fm] = *(i32x4*)&Alds[wm * 64 + fm * 16 + rr][koff];
#pragma unroll
    for (int fn = 0; fn < 4; fn++)
      bfv[fn] = *(i32x4*)&Blds[wn * 64 + fn * 16 + rr][koff];
#pragma unroll
    for (int fm = 0; fm < 4; fm++)
#pragma unroll
      for (int fn = 0; fn < 4; fn++)
        acc[fm][fn] = mfma_bf16(af[fm], bfv[fn], acc[fm][fn]);
  }

  int rq = lane >> 4, rr = lane & 15;
#pragma unroll
  for (int fm = 0; fm < 4; fm++) {
#pragma unroll
    for (int fn = 0; fn < 4; fn++) {
      int col = col0 + wn * 64 + fn * 16 + rr;
#pragma unroll
      for (int r = 0; r < 4; r++) {
        int row = row0 + wm * 64 + fm * 16 + rq * 4 + r;
        Cout[(long long)row * 8192 + col] = f2bf(scl[row] * acc[fm][fn][r]);
      }
    }
  }
}

// ---------------------------------------------------------------------------
// ctx (bf16 MFMA) — round-7 verbatim.
// ---------------------------------------------------------------------------
__global__ __launch_bounds__(256) void gemm_ctx_bf16(
    const unsigned short* __restrict__ w16,
    const unsigned short* __restrict__ VT, float* __restrict__ ctx) {
  int row0 = blockIdx.x * 64;
  int h = blockIdx.y;
  __shared__ unsigned short Asl[64][68];
  __shared__ unsigned short Bsl[64][68];
  int t = (int)threadIdx.x, lane = t & 63, wave = t >> 6;

  f32x4 acc[4];
#pragma unroll
  for (int i = 0; i < 4; i++) acc[i] = (f32x4){0.f, 0.f, 0.f, 0.f};

  int r = t >> 2, kq = (t & 3) * 8;
  const unsigned short* Ap = w16 + (long long)(row0 + r) * 8192 + h * 1024 + kq;
  const unsigned short* Bp = VT + (long long)(h * 64 + r) * 1024 + kq;

  for (int kb = 0; kb < 1024; kb += 64) {
    i32x4 a0 = *(const i32x4*)(Ap + kb);
    i32x4 a1 = *(const i32x4*)(Ap + kb + 32);
    i32x4 b0 = *(const i32x4*)(Bp + kb);
    i32x4 b1 = *(const i32x4*)(Bp + kb + 32);
    __syncthreads();
    *(i32x4*)&Asl[r][kq] = a0;
    *(i32x4*)&Asl[r][kq + 32] = a1;
    *(i32x4*)&Bsl[r][kq] = b0;
    *(i32x4*)&Bsl[r][kq + 32] = b1;
    __syncthreads();

    int rr = lane & 15, ko = (lane >> 4) * 8;
#pragma unroll
    for (int k2 = 0; k2 < 2; k2++) {
      i32x4 af = *(i32x4*)&Asl[wave * 16 + rr][k2 * 32 + ko];
#pragma unroll
      for (int fn = 0; fn < 4; fn++) {
        i32x4 bf = *(i32x4*)&Bsl[fn * 16 + rr][k2 * 32 + ko];
        acc[fn] = mfma_bf16(af, bf, acc[fn]);
      }
    }
  }

  int rq = lane >> 4, rr = lane & 15;
#pragma unroll
  for (int fn = 0; fn < 4; fn++) {
#pragma unroll
    for (int rl = 0; rl < 4; rl++) {
      int i = row0 + wave * 16 + rq * 4 + rl;
      ctx[(long long)i * 512 + h * 64 + fn * 16 + rr] = acc[fn][rl];
    }
  }
}

// ---------------------------------------------------------------------------
// Vertical routing — round-7 verbatim.
// ---------------------------------------------------------------------------
__global__ __launch_bounds__(256) void vertical_routing_kernel(
    const unsigned short* __restrict__ u16, float* __restrict__ vV) {
  __shared__ float Ur[8 * 1024];
  __shared__ float red[4];
  __shared__ float red8[32];
  int bq = blockIdx.x;
  int t = (int)threadIdx.x;
  const unsigned short* Ub = u16 + (long long)bq * 8192;
#pragma unroll
  for (int r = 0; r < 8; r++) {
    uint2 p = *(const uint2*)&Ub[(t + 256 * r) * 4];
    Ur[(t + 256 * r) * 4 + 0] = bf2f(p.x & 0xffffu);
    Ur[(t + 256 * r) * 4 + 1] = bf2f(p.x >> 16);
    Ur[(t + 256 * r) * 4 + 2] = bf2f(p.y & 0xffffu);
    Ur[(t + 256 * r) * 4 + 3] = bf2f(p.y >> 16);
  }
  __syncthreads();

  float bh[8] = {0.f, 0.f, 0.f, 0.f, 0.f, 0.f, 0.f, 0.f};
  int k0 = t * 4;
  float4 v4 = {0.f, 0.f, 0.f, 0.f};
  for (int it = 0; it < 3; ++it) {
    float m = bh[0];
#pragma unroll
    for (int h = 1; h < 8; h++) m = fmaxf(m, bh[h]);
    float c[8], zz = 0.f;
#pragma unroll
    for (int h = 0; h < 8; h++) {
      c[h] = expf(bh[h] - m);
      zz += c[h];
    }
    float inv = 1.f / zz;
    float4 s4 = {0.f, 0.f, 0.f, 0.f};
#pragma unroll
    for (int h = 0; h < 8; h++) {
      float4 u = *(float4*)&Ur[h * 1024 + k0];
      float ch = c[h] * inv;
      s4.x = fmaf(ch, u.x, s4.x); s4.y = fmaf(ch, u.y, s4.y);
      s4.z = fmaf(ch, u.z, s4.z); s4.w = fmaf(ch, u.w, s4.w);
    }
    float sq =
        blockSum(s4.x * s4.x + s4.y * s4.y + s4.z * s4.z + s4.w * s4.w, red);
    float sc = (sq / (1.f + sq)) / sqrtf(sq + SQ_EPS);
    v4.x = sc * s4.x; v4.y = sc * s4.y; v4.z = sc * s4.z; v4.w = sc * s4.w;
    if (it < 2) {
      float p[8];
#pragma unroll
      for (int h = 0; h < 8; h++) {
        float4 u = *(float4*)&Ur[h * 1024 + k0];
        p[h] = u.x * v4.x + u.y * v4.y + u.z * v4.z + u.w * v4.w;
      }
      __syncthreads();
#pragma unroll
      for (int h = 0; h < 8; h++) {
        float w = wredSum(p[h]);
        if ((t & 63) == 0) red8[(t >> 6) * 8 + h] = w;
      }
      __syncthreads();
#pragma unroll
      for (int h = 0; h < 8; h++)
        bh[h] += red8[h] + red8[8 + h] + red8[16 + h] + red8[24 + h];
    }
  }
  *(float4*)&vV[(long long)bq * 1024 + k0] = v4;
}

// enhanced = u16 + vV + v16 (pre-scaled); w = softmax_k -> u16 in place.
__global__ __launch_bounds__(256) void enh_softmax_kernel(
    unsigned short* __restrict__ u16, const float* __restrict__ vV,
    const unsigned short* __restrict__ v16) {
  __shared__ float red[4];
  int idx = blockIdx.x;  // Q*H
  int h = idx & 7;
  int bq = idx >> 3;
  unsigned short* Urow = u16 + (long long)bq * 8192 + h * 1024;
  const float* va = vV + (long long)bq * 1024;
  const unsigned short* vb = v16 + (long long)bq * 8192 + h * 1024;
  int t = (int)threadIdx.x, k0 = t * 4;
  uint2 pu = *(const uint2*)&Urow[k0];
  float4 a = *(const float4*)&va[k0];
  uint2 pb = *(const uint2*)&vb[k0];
  float x0 = bf2f(pu.x & 0xffffu) + a.x + bf2f(pb.x & 0xffffu);
  float x1 = bf2f(pu.x >> 16) + a.y + bf2f(pb.x >> 16);
  float x2 = bf2f(pu.y & 0xffffu) + a.z + bf2f(pb.y & 0xffffu);
  float x3 = bf2f(pu.y >> 16) + a.w + bf2f(pb.y >> 16);
  float mx = blockMax(fmaxf(fmaxf(x0, x1), fmaxf(x2, x3)), red);
  float e0 = expf(x0 - mx), e1 = expf(x1 - mx), e2 = expf(x2 - mx),
        e3 = expf(x3 - mx);
  float zz = blockSum(e0 + e1 + e2 + e3, red);
  float inv = 1.f / zz;
  uint2 o = {(unsigned int)f2bf(e0 * inv) | ((unsigned int)f2bf(e1 * inv) << 16),
             (unsigned int)f2bf(e2 * inv) | ((unsigned int)f2bf(e3 * inv) << 16)};
  *(uint2*)&Urow[k0] = o;
}

// ---------------------------------------------------------------------------
extern "C" void kernel_launch(void* const* d_in, const int* in_sizes, int n_in,
                              void* d_out, int out_size, void* d_ws,
                              size_t ws_size, hipStream_t stream) {
  (void)in_sizes; (void)n_in; (void)out_size; (void)ws_size;
  const float* x = (const float*)d_in[0];
  const float* Wq = (const float*)d_in[1];
  const float* bq = (const float*)d_in[2];
  const float* Wk = (const float*)d_in[3];
  const float* bk = (const float*)d_in[4];
  const float* Wv = (const float*)d_in[5];
  const float* bv = (const float*)d_in[6];
  const float* Wo = (const float*)d_in[7];
  const float* bo = (const float*)d_in[8];
  float* out = (float*)d_out;
  float* ws = (float*)d_ws;

  unsigned short* u16 = (unsigned short*)(ws);               // 4,194,304 fl
  unsigned short* uT16 = (unsigned short*)(ws + 4194304);    // 4,194,304 fl
  unsigned short* sv16 = (unsigned short*)(ws + 8388608);    // 4,194,304 fl
  float* Qf = ws + 12582912;                                 // 2,097,152
  float* Kf = ws + 14680064;                                 // 2,097,152
  unsigned short* V16a = (unsigned short*)(ws + 16777216);   // 1,048,576 fl
  unsigned short* VT16a = (unsigned short*)(ws + 17825792);  // 1,048,576 fl
  unsigned short* WT16 = (unsigned short*)(ws + 18874368);   //   393,216 fl
  float* ctxa = ws + 19267584;                               // 2,097,152
  float* vV = ws + 21364736;                                 // 1,048,576
  float* bH = ws + 22413312;                                 // 1,048,576
  float* P = ws + 23461888;                                  // 4,194,304
  unsigned short* cH16 = (unsigned short*)(ws + 27656192);   //   524,288 fl
  float* Mbuf = ws + 28180480;                               // 1,048,576
  unsigned short* G16 = (unsigned short*)(ws + 29229056);    //   524,288 fl
  float* scl = ws + 29753344;                                //     1,024
  // total 29,754,368 floats = 113.5 MiB

  // ---- prologue (all batches) ----
  wtrans_kernel<<<dim3(8, 8, 3), 256, 0, stream>>>(Wq, Wk, Wv, WT16);
  gemm_qkv_mfma<<<dim3(8, 64, 3), 256, 0, stream>>>(x, WT16, bq, bk, bv, Qf,
                                                    Kf, V16a);
  for (int b = 0; b < 4; ++b)
    transpose16_kernel<<<dim3(16, 8), 256, 0, stream>>>(
        V16a + (long long)b * 524288, VT16a + (long long)b * 524288, 512, 1024);

  // ---- per-batch routing ----
  for (int b = 0; b < 4; ++b) {
    const float* qf = Qf + (long long)b * 524288;
    const float* kf = Kf + (long long)b * 524288;

    gemm_scores_bf16<<<dim3(8, 8, 8), 256, 0, stream>>>(qf, kf, u16);
    transpose16_kernel<<<dim3(16, 128), 256, 0, stream>>>(u16, uT16, 8192,
                                                          1024);
    vertical_routing_kernel<<<dim3(1024), 256, 0, stream>>>(u16, vV);

    // Gram matrix G = u·u^T (once per batch)
    gemm_G_bf16<<<dim3(16, 16, 4), 256, 0, stream>>>(u16, P);
    merge_G_kernel<<<dim3(1024), 256, 0, stream>>>(P, G16);

    // it 0: c0 uniform; M0 = C0·G; scl0; bH = scl0·M0; c1
    softmax_uniform_kernel<<<dim3(1024), 256, 0, stream>>>(cH16);
    gemm_M_bf16<<<dim3(16, 16), 256, 0, stream>>>(cH16, G16, Mbuf);
    scldot_kernel<<<dim3(1024), 256, 0, stream>>>(Mbuf, cH16, scl);
    bupd_softmax_kernel<1><<<dim3(1024), 256, 0, stream>>>(bH, Mbuf, scl,
                                                           cH16);
    // it 1: M1 = C1·G; scl1; bH += scl1·M1; c2
    gemm_M_bf16<<<dim3(16, 16), 256, 0, stream>>>(cH16, G16, Mbuf);
    scldot_kernel<<<dim3(1024), 256, 0, stream>>>(Mbuf, cH16, scl);
    bupd_softmax_kernel<0><<<dim3(1024), 256, 0, stream>>>(bH, Mbuf, scl,
                                                           cH16);
    // it 2: M2 = C2·G; scl2; final v = scl2·(C2·u)
    gemm_M_bf16<<<dim3(16, 16), 256, 0, stream>>>(cH16, G16, Mbuf);
    scldot_kernel<<<dim3(1024), 256, 0, stream>>>(Mbuf, cH16, scl);
    gemm_s_scl<<<dim3(64, 8), 256, 0, stream>>>(cH16, uT16, scl, sv16);

    enh_softmax_kernel<<<dim3(8192), 256, 0, stream>>>(u16, vV, sv16);
    gemm_ctx_bf16<<<dim3(16, 8), 256, 0, stream>>>(
        u16, VT16a + (long long)b * 524288, ctxa + (long long)b * 524288);
  }

  // ---- epilogue: out = ctx x Wo + bo (all batches) ----
  gemm_f32<64, 64, 16><<<dim3(8, 64), 256, 0, stream>>>(ctxa, Wo, out, bo, 512,
                                                        512, 512, 512);
}

// Round 9
// 530.738 us; speedup vs baseline: 13.0706x; 1.5043x over previous
//
#include <hip/hip_runtime.h>
#include <math.h>

// ---------------------------------------------------------------------------
// CapsuleRoutingSelfAttention — round 9: cross-batch batching (75 -> 19
// dispatches), symmetric-G triangular compute + mirror, transpose-free uT
// (scores dual-writes u and u^T).  All kernel bodies are proven molds; only
// z/y-grid batch decomposition and pointer offsets added.
//
// Workspace (float units), 65,409,024 fl = 249.5 MiB (ws = 256 MiB):
//   u16a  [4][1024][8192] bf16  @ 0          scores; later w in place
//   uT16a [4][8192][1024] bf16  @ 16777216
//   OVR   [16,777,216 fl]       @ 33554432   time-multiplexed:
//       Qf [4096,512] f32 @33554432 | Kf @35651584 (die after scores)
//       Pa [8][1024^2] f32 @37748736        (G split-K partials; die at merge)
//       Mbufa [4][1024^2] f32 @46137344     (dies after it2 scldot)
//       sv16a [4][1024][8192] bf16 @33554432 (written by s_scl after all die)
//   vVa  [4][1024,1024] f32 @ 50331648
//   bHa  [4][1024^2] f32 @ 54525952  ; ctxa [4096,512] f32 overlays (bH dead)
//   cH16a [4][1024^2] bf16 @ 58720256
//   G16a  [4][1024^2] bf16 @ 60817408
//   V16a [4096,512] bf16 @ 62914560 | VT16a [4][512,1024] bf16 @ 63963136
//   WT16 [3][512,512] bf16 @ 65011712 | scl [4][1024] f32 @ 65404928
// ---------------------------------------------------------------------------

#define SQ_EPS 1e-8f

typedef __attribute__((ext_vector_type(4))) int i32x4;    // 8 bf16
typedef __attribute__((ext_vector_type(4))) float f32x4;

__device__ __forceinline__ float bf2f(unsigned int u) {
  union { unsigned int i; float f; } x;
  x.i = u << 16;
  return x.f;
}
__device__ __forceinline__ unsigned short f2bf(float f) {
  union { float f; unsigned int i; } x;
  x.f = f;
  unsigned int r = x.i + 0x7fffu + ((x.i >> 16) & 1u);
  return (unsigned short)(r >> 16);
}
__device__ __forceinline__ int packbf(float a, float b) {
  return (int)((unsigned int)f2bf(a) | ((unsigned int)f2bf(b) << 16));
}

__device__ __forceinline__ f32x4 mfma_bf16(i32x4 a, i32x4 b, f32x4 c) {
  asm("v_mfma_f32_16x16x32_bf16 %0, %1, %2, %0" : "+v"(c) : "v"(a), "v"(b));
  return c;
}

__device__ __forceinline__ float wredSum(float v) {
#pragma unroll
  for (int off = 32; off > 0; off >>= 1) v += __shfl_xor(v, off);
  return v;
}
__device__ __forceinline__ float wredMax(float v) {
#pragma unroll
  for (int off = 32; off > 0; off >>= 1) v = fmaxf(v, __shfl_xor(v, off));
  return v;
}
__device__ __forceinline__ float blockSum(float v, volatile float* red) {
  v = wredSum(v);
  int wid = threadIdx.x >> 6;
  __syncthreads();
  if ((threadIdx.x & 63) == 0) red[wid] = v;
  __syncthreads();
  return red[0] + red[1] + red[2] + red[3];
}
__device__ __forceinline__ float blockMax(float v, volatile float* red) {
  v = wredMax(v);
  int wid = threadIdx.x >> 6;
  __syncthreads();
  if ((threadIdx.x & 63) == 0) red[wid] = v;
  __syncthreads();
  return fmaxf(fmaxf(red[0], red[1]), fmaxf(red[2], red[3]));
}

// ---------------------------------------------------------------------------
// W^T prep — round-8 verbatim.
// ---------------------------------------------------------------------------
__global__ __launch_bounds__(256) void wtrans_kernel(
    const float* __restrict__ Wq, const float* __restrict__ Wk,
    const float* __restrict__ Wv, unsigned short* __restrict__ WT16) {
  __shared__ unsigned short T[64][72];
  int z = blockIdx.z;
  const float* src = (z == 0) ? Wq : (z == 1) ? Wk : Wv;
  unsigned short* dst = WT16 + (long long)z * 262144;
  int i0 = blockIdx.x * 64;
  int c0 = blockIdx.y * 64;
  int t = (int)threadIdx.x;
  int r = t >> 2, cq = (t & 3) * 16;
#pragma unroll
  for (int j = 0; j < 4; j++) {
    float4 v = *(const float4*)&src[(long long)(i0 + r) * 512 + c0 + cq + j * 4];
    T[r][cq + j * 4 + 0] = f2bf(v.x);
    T[r][cq + j * 4 + 1] = f2bf(v.y);
    T[r][cq + j * 4 + 2] = f2bf(v.z);
    T[r][cq + j * 4 + 3] = f2bf(v.w);
  }
  __syncthreads();
  int c = t >> 2, iq = (t & 3) * 16;
  unsigned short tmp[16];
#pragma unroll
  for (int j = 0; j < 16; j++) tmp[j] = T[iq + j][c];
  *(i32x4*)&dst[(long long)(c0 + c) * 512 + i0 + iq] = *(i32x4*)&tmp[0];
  *(i32x4*)&dst[(long long)(c0 + c) * 512 + i0 + iq + 8] = *(i32x4*)&tmp[8];
}

// ---------------------------------------------------------------------------
// QKV (bf16 MFMA, all batches) — round-8 verbatim.
// ---------------------------------------------------------------------------
__global__ __launch_bounds__(256) void gemm_qkv_mfma(
    const float* __restrict__ x, const unsigned short* __restrict__ WT16,
    const float* __restrict__ bq, const float* __restrict__ bk,
    const float* __restrict__ bv, float* __restrict__ Qf,
    float* __restrict__ Kf, unsigned short* __restrict__ V16) {
  __shared__ unsigned short Asl[64][68];
  __shared__ unsigned short Bsl[64][68];
  int z = blockIdx.z;
  const unsigned short* WT = WT16 + (long long)z * 262144;
  const float* bias = (z == 0) ? bq : (z == 1) ? bk : bv;

  int row0 = blockIdx.y * 64;
  int col0 = blockIdx.x * 64;
  int t = (int)threadIdx.x, lane = t & 63, wave = t >> 6;
  int wm = wave >> 1, wn = wave & 1;

  f32x4 acc[2][2];
#pragma unroll
  for (int i = 0; i < 2; i++)
#pragma unroll
    for (int j = 0; j < 2; j++) acc[i][j] = (f32x4){0.f, 0.f, 0.f, 0.f};

  int r = t >> 2, kq = (t & 3) * 8;
  const float* Ap = x + (long long)(row0 + r) * 512 + kq;
  const unsigned short* Bp = WT + (long long)(col0 + r) * 512 + kq;

  for (int kb = 0; kb < 512; kb += 64) {
    float4 a0 = *(const float4*)(Ap + kb);
    float4 a1 = *(const float4*)(Ap + kb + 4);
    float4 a2 = *(const float4*)(Ap + kb + 32);
    float4 a3 = *(const float4*)(Ap + kb + 36);
    i32x4 b0 = *(const i32x4*)(Bp + kb);
    i32x4 b1 = *(const i32x4*)(Bp + kb + 32);
    __syncthreads();
    i32x4 pa0 = {packbf(a0.x, a0.y), packbf(a0.z, a0.w), packbf(a1.x, a1.y),
                 packbf(a1.z, a1.w)};
    i32x4 pa1 = {packbf(a2.x, a2.y), packbf(a2.z, a2.w), packbf(a3.x, a3.y),
                 packbf(a3.z, a3.w)};
    *(i32x4*)&Asl[r][kq] = pa0;
    *(i32x4*)&Asl[r][kq + 32] = pa1;
    *(i32x4*)&Bsl[r][kq] = b0;
    *(i32x4*)&Bsl[r][kq + 32] = b1;
    __syncthreads();

    int rr = lane & 15, ko = (lane >> 4) * 8;
#pragma unroll
    for (int k2 = 0; k2 < 2; k2++) {
      i32x4 af0 = *(i32x4*)&Asl[wm * 32 + rr][k2 * 32 + ko];
      i32x4 af1 = *(i32x4*)&Asl[wm * 32 + 16 + rr][k2 * 32 + ko];
      i32x4 bf0 = *(i32x4*)&Bsl[wn * 32 + rr][k2 * 32 + ko];
      i32x4 bf1 = *(i32x4*)&Bsl[wn * 32 + 16 + rr][k2 * 32 + ko];
      acc[0][0] = mfma_bf16(af0, bf0, acc[0][0]);
      acc[0][1] = mfma_bf16(af0, bf1, acc[0][1]);
      acc[1][0] = mfma_bf16(af1, bf0, acc[1][0]);
      acc[1][1] = mfma_bf16(af1, bf1, acc[1][1]);
    }
  }

  int rq = lane >> 4, rr = lane & 15;
#pragma unroll
  for (int fm = 0; fm < 2; fm++) {
#pragma unroll
    for (int fn = 0; fn < 2; fn++) {
      int col = col0 + wn * 32 + fn * 16 + rr;
      float bb = bias[col];
#pragma unroll
      for (int rl = 0; rl < 4; rl++) {
        int row = row0 + wm * 32 + fm * 16 + rq * 4 + rl;
        float v = acc[fm][fn][rl] + bb;
        if (z == 2)
          V16[(long long)row * 512 + col] = f2bf(v);
        else if (z == 1)
          Kf[(long long)row * 512 + col] = v;
        else
          Qf[(long long)row * 512 + col] = v;
      }
    }
  }
}

// ---------------------------------------------------------------------------
// Scores (fp32 compute, bf16 out) — round-8 mold + z-batch + dual uT write.
// Grid (8, 8, 32): z = b*8 + h.
// ---------------------------------------------------------------------------
__global__ __launch_bounds__(256) void gemm_scores_bf16(
    const float* __restrict__ Qf, const float* __restrict__ Kf,
    unsigned short* __restrict__ u16a, unsigned short* __restrict__ uT16a) {
  __shared__ float As[8][132];
  __shared__ float Bs[8][132];
  int z = blockIdx.z;
  int b = z >> 3, h = z & 7;
  const float* A = Qf + (long long)b * 524288 + h * 64;
  const float* B = Kf + (long long)b * 524288 + h * 64;
  unsigned short* C16 = u16a + (long long)b * 8388608 + h * 1024;
  unsigned short* uTb = uT16a + (long long)b * 8388608;

  int row0 = blockIdx.y * 128;
  int col0 = blockIdx.x * 128;
  int tid = (int)threadIdx.x;
  int tx = tid & 15, ty = tid >> 4;
  int arow = tid >> 1;
  int akc = (tid & 1) * 4;

  float acc[8][8];
#pragma unroll
  for (int i = 0; i < 8; i++)
#pragma unroll
    for (int j = 0; j < 8; j++) acc[i][j] = 0.f;

  const float* Aptr = A + (long long)(row0 + arow) * 512 + akc;
  const float* Bptr = B + (long long)(col0 + arow) * 512 + akc;

  for (int kb = 0; kb < 64; kb += 8) {
    float4 av = *(const float4*)(Aptr + kb);
    float4 bv = *(const float4*)(Bptr + kb);
    __syncthreads();
    As[akc + 0][arow] = av.x; As[akc + 1][arow] = av.y;
    As[akc + 2][arow] = av.z; As[akc + 3][arow] = av.w;
    Bs[akc + 0][arow] = bv.x; Bs[akc + 1][arow] = bv.y;
    Bs[akc + 2][arow] = bv.z; Bs[akc + 3][arow] = bv.w;
    __syncthreads();

#pragma unroll
    for (int k = 0; k < 8; k++) {
      float a[8], b2[8];
#pragma unroll
      for (int c = 0; c < 2; c++) {
        float4 q = *(float4*)&As[k][ty * 8 + c * 4];
        a[c * 4 + 0] = q.x; a[c * 4 + 1] = q.y;
        a[c * 4 + 2] = q.z; a[c * 4 + 3] = q.w;
      }
#pragma unroll
      for (int c = 0; c < 2; c++) {
        float4 q = *(float4*)&Bs[k][c * 64 + tx * 4];
        b2[c * 4 + 0] = q.x; b2[c * 4 + 1] = q.y;
        b2[c * 4 + 2] = q.z; b2[c * 4 + 3] = q.w;
      }
#pragma unroll
      for (int i = 0; i < 8; i++)
#pragma unroll
        for (int j = 0; j < 8; j++) acc[i][j] = fmaf(a[i], b2[j], acc[i][j]);
    }
  }

  // u16 write (row-major) — round-8 verbatim
#pragma unroll
  for (int i = 0; i < 8; i++) {
    long long r = row0 + ty * 8 + i;
#pragma unroll
    for (int c = 0; c < 2; c++) {
      int col = col0 + c * 64 + tx * 4;
      unsigned int lo = (unsigned int)f2bf(0.125f * acc[i][c * 4 + 0]) |
                        ((unsigned int)f2bf(0.125f * acc[i][c * 4 + 1]) << 16);
      unsigned int hi = (unsigned int)f2bf(0.125f * acc[i][c * 4 + 2]) |
                        ((unsigned int)f2bf(0.125f * acc[i][c * 4 + 3]) << 16);
      uint2 o = {lo, hi};
      *(uint2*)&C16[r * 8192 + col] = o;
    }
  }
  // uT dual write: for each owned column, pack the 8 owned rows (16B store).
  // uT[h*1024+colg][r] = u[r][h*1024+colg]; rows row0+ty*8 .. +7 contiguous.
#pragma unroll
  for (int c = 0; c < 2; c++) {
#pragma unroll
    for (int cc = 0; cc < 4; cc++) {
      int colg = col0 + c * 64 + tx * 4 + cc;
      i32x4 pk;
      pk[0] = packbf(0.125f * acc[0][c * 4 + cc], 0.125f * acc[1][c * 4 + cc]);
      pk[1] = packbf(0.125f * acc[2][c * 4 + cc], 0.125f * acc[3][c * 4 + cc]);
      pk[2] = packbf(0.125f * acc[4][c * 4 + cc], 0.125f * acc[5][c * 4 + cc]);
      pk[3] = packbf(0.125f * acc[6][c * 4 + cc], 0.125f * acc[7][c * 4 + cc]);
      *(i32x4*)&uTb[(long long)(h * 1024 + colg) * 1024 + row0 + ty * 8] = pk;
    }
  }
}

// ---------------------------------------------------------------------------
// fp32 tiled GEMM (out-projection) — round-8 verbatim.
// ---------------------------------------------------------------------------
template <int BM, int BN, int BK>
__global__ __launch_bounds__(256) void gemm_f32(
    const float* __restrict__ A, const float* __restrict__ B,
    float* __restrict__ C, const float* __restrict__ bias,
    int K, int lda, int ldb, int ldc) {
  constexpr int TM = BM / 16;
  constexpr int TN = BN / 16;
  __shared__ float As[BK][BM + 4];
  __shared__ float Bs[BK][BN + 4];

  int row0 = blockIdx.y * BM;
  int col0 = blockIdx.x * BN;
  int tid = (int)threadIdx.x;
  int tx = tid & 15, ty = tid >> 4;

  constexpr int AKC = BK / 4;
  int arow = tid / AKC;
  int akc = (tid - arow * AKC) * 4;
  int brow = tid / (BN / 4);
  int bcol = (tid - brow * (BN / 4)) * 4;

  float acc[TM][TN];
#pragma unroll
  for (int i = 0; i < TM; i++)
#pragma unroll
    for (int j = 0; j < TN; j++) acc[i][j] = 0.f;

  const float* Aptr = A + (long long)(row0 + arow) * lda + akc;
  const float* Bptr = B + (long long)brow * ldb + col0 + bcol;

  for (int kb = 0; kb < K; kb += BK) {
    float4 av = *(const float4*)(Aptr + kb);
    float4 bv = *(const float4*)(Bptr + (long long)kb * ldb);
    __syncthreads();
    As[akc + 0][arow] = av.x;
    As[akc + 1][arow] = av.y;
    As[akc + 2][arow] = av.z;
    As[akc + 3][arow] = av.w;
    *(float4*)&Bs[brow][bcol] = bv;
    __syncthreads();

#pragma unroll
    for (int k = 0; k < BK; k++) {
      float a[TM], b[TN];
#pragma unroll
      for (int c = 0; c < TM / 4; c++) {
        float4 q = *(float4*)&As[k][ty * TM + c * 4];
        a[c * 4 + 0] = q.x; a[c * 4 + 1] = q.y;
        a[c * 4 + 2] = q.z; a[c * 4 + 3] = q.w;
      }
#pragma unroll
      for (int c = 0; c < TN / 4; c++) {
        float4 q = *(float4*)&Bs[k][c * 64 + tx * 4];
        b[c * 4 + 0] = q.x; b[c * 4 + 1] = q.y;
        b[c * 4 + 2] = q.z; b[c * 4 + 3] = q.w;
      }
#pragma unroll
      for (int i = 0; i < TM; i++)
#pragma unroll
        for (int j = 0; j < TN; j++) acc[i][j] = fmaf(a[i], b[j], acc[i][j]);
    }
  }

#pragma unroll
  for (int i = 0; i < TM; i++) {
    long long r = row0 + ty * TM + i;
#pragma unroll
    for (int c = 0; c < TN / 4; c++) {
      int col = col0 + c * 64 + tx * 4;
      float4 val = {acc[i][c * 4 + 0], acc[i][c * 4 + 1], acc[i][c * 4 + 2],
                    acc[i][c * 4 + 3]};
      if (bias) {
        float4 bb = *(const float4*)&bias[col];
        val.x += bb.x; val.y += bb.y; val.z += bb.z; val.w += bb.w;
      }
      *(float4*)&C[r * ldc + col] = val;
    }
  }
}

// ---------------------------------------------------------------------------
// bf16 transpose (V only now), z-batched.  Grid (16, 8, 4).
// ---------------------------------------------------------------------------
__global__ __launch_bounds__(256) void transpose16_kernel(
    const unsigned short* __restrict__ src, unsigned short* __restrict__ dst,
    int ldS, int ldD, long long zsS, long long zsD) {
  __shared__ unsigned short T[64][72];
  src += (long long)blockIdx.z * zsS;
  dst += (long long)blockIdx.z * zsD;
  int i0 = blockIdx.x * 64;
  int c0 = blockIdx.y * 64;
  int t = (int)threadIdx.x;
  int r = t >> 2, cq = (t & 3) * 16;
  i32x4 v0 = *(const i32x4*)&src[(long long)(i0 + r) * ldS + c0 + cq];
  i32x4 v1 = *(const i32x4*)&src[(long long)(i0 + r) * ldS + c0 + cq + 8];
  *(i32x4*)&T[r][cq] = v0;
  *(i32x4*)&T[r][cq + 8] = v1;
  __syncthreads();
  int c = t >> 2, iq = (t & 3) * 16;
  unsigned short tmp[16];
#pragma unroll
  for (int j = 0; j < 16; j++) tmp[j] = T[iq + j][c];
  *(i32x4*)&dst[(long long)(c0 + c) * ldD + i0 + iq] = *(i32x4*)&tmp[0];
  *(i32x4*)&dst[(long long)(c0 + c) * ldD + i0 + iq + 8] = *(i32x4*)&tmp[8];
}

// ---------------------------------------------------------------------------
// G = u·u^T lower triangle (bf16 MFMA, split-K=2, z-batched).
// Grid (16, 16, 8): z = b*2 + ks.  Skip col0 > row0 (G symmetric).
// ---------------------------------------------------------------------------
__global__ __launch_bounds__(256) void gemm_G_bf16(
    const unsigned short* __restrict__ U16a, float* __restrict__ P) {
  int row0 = blockIdx.y * 64;
  int col0 = blockIdx.x * 64;
  if (col0 > row0) return;
  int z = blockIdx.z;
  int b = z >> 1, ks = z & 1;
  const unsigned short* U = U16a + (long long)b * 8388608;
  __shared__ unsigned short Asl[64][64];
  __shared__ unsigned short Bsl[64][64];
  int t = (int)threadIdx.x, lane = t & 63, wave = t >> 6;
  int wm = wave >> 1, wn = wave & 1;

  f32x4 acc[2][2];
#pragma unroll
  for (int i = 0; i < 2; i++)
#pragma unroll
    for (int j = 0; j < 2; j++) acc[i][j] = (f32x4){0.f, 0.f, 0.f, 0.f};

  int r = t >> 2, c0 = t & 3;
  int sw0 = ((c0 ^ (r & 7))) * 8;
  int sw1 = (((c0 + 4) ^ (r & 7))) * 8;
  const unsigned short* Ap = U + (long long)(row0 + r) * 8192 + ks * 4096 + c0 * 8;
  const unsigned short* Bp = U + (long long)(col0 + r) * 8192 + ks * 4096 + c0 * 8;

  for (int kb = 0; kb < 4096; kb += 64) {
    i32x4 a0 = *(const i32x4*)(Ap + kb);
    i32x4 a1 = *(const i32x4*)(Ap + kb + 32);
    i32x4 b0 = *(const i32x4*)(Bp + kb);
    i32x4 b1 = *(const i32x4*)(Bp + kb + 32);
    __syncthreads();
    *(i32x4*)&Asl[r][sw0] = a0;
    *(i32x4*)&Asl[r][sw1] = a1;
    *(i32x4*)&Bsl[r][sw0] = b0;
    *(i32x4*)&Bsl[r][sw1] = b1;
    __syncthreads();

    int rr = lane & 15, co = lane >> 4;
#pragma unroll
    for (int k2 = 0; k2 < 2; k2++) {
      int ch = ((k2 * 4 + co) ^ (rr & 7)) * 8;
      i32x4 af0 = *(i32x4*)&Asl[wm * 32 + rr][ch];
      i32x4 af1 = *(i32x4*)&Asl[wm * 32 + 16 + rr][ch];
      i32x4 bf0 = *(i32x4*)&Bsl[wn * 32 + rr][ch];
      i32x4 bf1 = *(i32x4*)&Bsl[wn * 32 + 16 + rr][ch];
      acc[0][0] = mfma_bf16(af0, bf0, acc[0][0]);
      acc[0][1] = mfma_bf16(af0, bf1, acc[0][1]);
      acc[1][0] = mfma_bf16(af1, bf0, acc[1][0]);
      acc[1][1] = mfma_bf16(af1, bf1, acc[1][1]);
    }
  }

  float* dst = P + (long long)z * 1048576;
  int rq = lane >> 4, rr = lane & 15;
#pragma unroll
  for (int fm = 0; fm < 2; fm++) {
#pragma unroll
    for (int fn = 0; fn < 2; fn++) {
      int j = col0 + wn * 32 + fn * 16 + rr;
#pragma unroll
      for (int rl = 0; rl < 4; rl++) {
        int i = row0 + wm * 32 + fm * 16 + rq * 4 + rl;
        dst[(long long)i * 1024 + j] = acc[fm][fn][rl];
      }
    }
  }
}

// G16 = bf16(P0+P1), mirrored to the upper triangle.  Grid (1024, 4).
__global__ __launch_bounds__(256) void merge_mirror_G_kernel(
    const float* __restrict__ P, unsigned short* __restrict__ G16a) {
  int i = blockIdx.x;
  int b = blockIdx.y;
  int t = (int)threadIdx.x, j0 = t * 4;
  if (j0 > i) return;  // lane covers only j <= i
  const float* P0 = P + (long long)(b * 2) * 1048576 + (long long)i * 1024;
  const float* P1 = P0 + 1048576;
  unsigned short* Gb = G16a + (long long)b * 1048576;
  float4 a = *(const float4*)&P0[j0];
  float4 c = *(const float4*)&P1[j0];
  float v[4] = {a.x + c.x, a.y + c.y, a.z + c.z, a.w + c.w};
#pragma unroll
  for (int e = 0; e < 4; e++) {
    int j = j0 + e;
    if (j > i) break;
    unsigned short g = f2bf(v[e]);
    Gb[(long long)i * 1024 + j] = g;
    if (j < i) Gb[(long long)j * 1024 + i] = g;
  }
}

// ---------------------------------------------------------------------------
// M = C·G (bf16 MFMA, z-batched).  Grid (16, 16, 4); skip col0 > row0.
// ---------------------------------------------------------------------------
__global__ __launch_bounds__(256) void gemm_M_bf16(
    const unsigned short* __restrict__ Ca, const unsigned short* __restrict__ Ga,
    float* __restrict__ Ma) {
  int row0 = blockIdx.y * 64;
  int col0 = blockIdx.x * 64;
  if (col0 > row0) return;
  int b = blockIdx.z;
  const unsigned short* C = Ca + (long long)b * 1048576;
  const unsigned short* G = Ga + (long long)b * 1048576;
  float* M = Ma + (long long)b * 1048576;
  int Kend = row0 + 64;
  __shared__ unsigned short Asl[64][64];
  __shared__ unsigned short Bsl[64][64];
  int t = (int)threadIdx.x, lane = t & 63, wave = t >> 6;
  int wm = wave >> 1, wn = wave & 1;

  f32x4 acc[2][2];
#pragma unroll
  for (int i = 0; i < 2; i++)
#pragma unroll
    for (int j = 0; j < 2; j++) acc[i][j] = (f32x4){0.f, 0.f, 0.f, 0.f};

  int r = t >> 2, c0 = t & 3;
  int sw0 = ((c0 ^ (r & 7))) * 8;
  int sw1 = (((c0 + 4) ^ (r & 7))) * 8;
  const unsigned short* Ap = C + (long long)(row0 + r) * 1024 + c0 * 8;
  const unsigned short* Bp = G + (long long)(col0 + r) * 1024 + c0 * 8;

  for (int kb = 0; kb < Kend; kb += 64) {
    i32x4 a0 = *(const i32x4*)(Ap + kb);
    i32x4 a1 = *(const i32x4*)(Ap + kb + 32);
    i32x4 b0 = *(const i32x4*)(Bp + kb);
    i32x4 b1 = *(const i32x4*)(Bp + kb + 32);
    __syncthreads();
    *(i32x4*)&Asl[r][sw0] = a0;
    *(i32x4*)&Asl[r][sw1] = a1;
    *(i32x4*)&Bsl[r][sw0] = b0;
    *(i32x4*)&Bsl[r][sw1] = b1;
    __syncthreads();

    int rr = lane & 15, co = lane >> 4;
#pragma unroll
    for (int k2 = 0; k2 < 2; k2++) {
      int ch = ((k2 * 4 + co) ^ (rr & 7)) * 8;
      i32x4 af0 = *(i32x4*)&Asl[wm * 32 + rr][ch];
      i32x4 af1 = *(i32x4*)&Asl[wm * 32 + 16 + rr][ch];
      i32x4 bf0 = *(i32x4*)&Bsl[wn * 32 + rr][ch];
      i32x4 bf1 = *(i32x4*)&Bsl[wn * 32 + 16 + rr][ch];
      acc[0][0] = mfma_bf16(af0, bf0, acc[0][0]);
      acc[0][1] = mfma_bf16(af0, bf1, acc[0][1]);
      acc[1][0] = mfma_bf16(af1, bf0, acc[1][0]);
      acc[1][1] = mfma_bf16(af1, bf1, acc[1][1]);
    }
  }

  int rq = lane >> 4, rr = lane & 15;
#pragma unroll
  for (int fm = 0; fm < 2; fm++) {
#pragma unroll
    for (int fn = 0; fn < 2; fn++) {
      int j = col0 + wn * 32 + fn * 16 + rr;
#pragma unroll
      for (int rl = 0; rl < 4; rl++) {
        int i = row0 + wm * 32 + fm * 16 + rq * 4 + rl;
        M[(long long)i * 1024 + j] = acc[fm][fn][rl];
      }
    }
  }
}

// ||s_i||^2 = sum_{j<=i} c[i,j]·M[i,j] -> scl.  Grid (1024, 4).
__global__ __launch_bounds__(256) void scldot_kernel(
    const float* __restrict__ Ma, const unsigned short* __restrict__ Ca,
    float* __restrict__ scl) {
  __shared__ float red[4];
  int i = blockIdx.x;
  int b = blockIdx.y;
  const float* M = Ma + (long long)b * 1048576;
  const unsigned short* C = Ca + (long long)b * 1048576;
  int t = (int)threadIdx.x, j0 = t * 4;
  long long base = (long long)i * 1024;
  float4 m = *(const float4*)&M[base + j0];
  uint2 pc = *(const uint2*)&C[base + j0];
  float c0 = bf2f(pc.x & 0xffffu), c1 = bf2f(pc.x >> 16);
  float c2 = bf2f(pc.y & 0xffffu), c3 = bf2f(pc.y >> 16);
  float acc = 0.f;
  if (j0 + 0 <= i) acc += c0 * m.x;
  if (j0 + 1 <= i) acc += c1 * m.y;
  if (j0 + 2 <= i) acc += c2 * m.z;
  if (j0 + 3 <= i) acc += c3 * m.w;
  float ssq = blockSum(acc, red);
  if (t == 0) scl[b * 1024 + i] = (ssq / (1.f + ssq)) / sqrtf(ssq + SQ_EPS);
}

// it=0 coupling.  Grid (1024, 4).
__global__ __launch_bounds__(256) void softmax_uniform_kernel(
    unsigned short* __restrict__ cH16a) {
  int i = blockIdx.x;
  int b = blockIdx.y;
  unsigned short* cH16 = cH16a + (long long)b * 1048576;
  int t = (int)threadIdx.x, k0 = t * 4;
  unsigned short c = f2bf(1.f / (float)(i + 1));
  unsigned short e0 = (k0 + 0) <= i ? c : (unsigned short)0;
  unsigned short e1 = (k0 + 1) <= i ? c : (unsigned short)0;
  unsigned short e2 = (k0 + 2) <= i ? c : (unsigned short)0;
  unsigned short e3 = (k0 + 3) <= i ? c : (unsigned short)0;
  uint2 o = {(unsigned int)e0 | ((unsigned int)e1 << 16),
             (unsigned int)e2 | ((unsigned int)e3 << 16)};
  *(uint2*)&cH16[(long long)i * 1024 + k0] = o;
}

// bH (+)= scl[i]·M[i,j] (j<=i); cH16 = causal softmax(bH).  Grid (1024, 4).
template <int INIT>
__global__ __launch_bounds__(256) void bupd_softmax_kernel(
    float* __restrict__ bHa, const float* __restrict__ Ma,
    const float* __restrict__ scl, unsigned short* __restrict__ cH16a) {
  __shared__ float red[4];
  int i = blockIdx.x;
  int b = blockIdx.y;
  float* bH = bHa + (long long)b * 1048576;
  const float* M = Ma + (long long)b * 1048576;
  unsigned short* cH16 = cH16a + (long long)b * 1048576;
  long long base = (long long)i * 1024;
  int t = (int)threadIdx.x, k0 = t * 4;
  float sc = scl[b * 1024 + i];
  float4 x;
  if (INIT) x = (float4){0.f, 0.f, 0.f, 0.f};
  else x = *(const float4*)&bH[base + k0];
  float4 m = *(const float4*)&M[base + k0];
  bool m0 = (k0 + 0) <= i, m1 = (k0 + 1) <= i, m2 = (k0 + 2) <= i,
       m3 = (k0 + 3) <= i;
  if (m0) x.x += sc * m.x;
  if (m1) x.y += sc * m.y;
  if (m2) x.z += sc * m.z;
  if (m3) x.w += sc * m.w;
  *(float4*)&bH[base + k0] = x;
  float mx = -3.0e38f;
  if (m0) mx = fmaxf(mx, x.x);
  if (m1) mx = fmaxf(mx, x.y);
  if (m2) mx = fmaxf(mx, x.z);
  if (m3) mx = fmaxf(mx, x.w);
  mx = blockMax(mx, red);
  float e0 = m0 ? expf(x.x - mx) : 0.f;
  float e1 = m1 ? expf(x.y - mx) : 0.f;
  float e2 = m2 ? expf(x.z - mx) : 0.f;
  float e3 = m3 ? expf(x.w - mx) : 0.f;
  float zz = blockSum(e0 + e1 + e2 + e3, red);
  float inv = 1.f / zz;
  uint2 o = {(unsigned int)f2bf(e0 * inv) | ((unsigned int)f2bf(e1 * inv) << 16),
             (unsigned int)f2bf(e2 * inv) | ((unsigned int)f2bf(e3 * inv) << 16)};
  *(uint2*)&cH16[base + k0] = o;
}

// ---------------------------------------------------------------------------
// Final v (z-batched): sv16[i,c] = scl[i]·sum_j c[i,j]·u[j,c].  Grid (64,8,4).
// ---------------------------------------------------------------------------
__global__ __launch_bounds__(256) void gemm_s_scl(
    const unsigned short* __restrict__ Ca, const unsigned short* __restrict__ BTa,
    const float* __restrict__ scla, unsigned short* __restrict__ Ca_out) {
  __shared__ unsigned short Alds[128][32];
  __shared__ unsigned short Blds[128][32];
  int b = blockIdx.z;
  const unsigned short* Abf = Ca + (long long)b * 1048576;
  const unsigned short* BT = BTa + (long long)b * 8388608;
  const float* scl = scla + b * 1024;
  unsigned short* Cout = Ca_out + (long long)b * 8388608;
  int rowblk = 7 - (int)blockIdx.y;
  int row0 = rowblk * 128;
  int col0 = blockIdx.x * 128;
  int t = (int)threadIdx.x, lane = t & 63, wave = t >> 6;
  int wm = wave >> 1, wn = wave & 1;
  int Kend = row0 + 128;

  f32x4 acc[4][4];
#pragma unroll
  for (int i = 0; i < 4; i++)
#pragma unroll
    for (int j = 0; j < 4; j++) acc[i][j] = (f32x4){0.f, 0.f, 0.f, 0.f};

  int ar = t >> 2;
  int aq = (t & 3) * 8;

  for (int kb = 0; kb < Kend; kb += 32) {
    i32x4 a0 = *(const i32x4*)&Abf[(long long)(row0 + ar) * 1024 + kb + aq];
    i32x4 a1 = *(const i32x4*)&Abf[(long long)(row0 + ar + 64) * 1024 + kb + aq];
    i32x4 b0 = *(const i32x4*)&BT[(long long)(col0 + ar) * 1024 + kb + aq];
    i32x4 b1 = *(const i32x4*)&BT[(long long)(col0 + ar + 64) * 1024 + kb + aq];
    __syncthreads();
    *(i32x4*)&Alds[ar][aq] = a0;
    *(i32x4*)&Alds[ar + 64][aq] = a1;
    *(i32x4*)&Blds[ar][aq] = b0;
    *(i32x4*)&Blds[ar + 64][aq] = b1;
    __syncthreads();

    int rr = lane & 15, koff = (lane >> 4) * 8;
    i32x4 af[4], bfv[4];
#pragma unroll
    for (int fm = 0; fm < 4; fm++)
      af[fm] = *(i32x4*)&Alds[wm * 64 + fm * 16 + rr][koff];
#pragma unroll
    for (int fn = 0; fn < 4; fn++)
      bfv[fn] = *(i32x4*)&Blds[wn * 64 + fn * 16 + rr][koff];
#pragma unroll
    for (int fm = 0; fm < 4; fm++)
#pragma unroll
      for (int fn = 0; fn < 4; fn++)
        acc[fm][fn] = mfma_bf16(af[fm], bfv[fn], acc[fm][fn]);
  }

  int rq = lane >> 4, rr = lane & 15;
#pragma unroll
  for (int fm = 0; fm < 4; fm++) {
#pragma unroll
    for (int fn = 0; fn < 4; fn++) {
      int col = col0 + wn * 64 + fn * 16 + rr;
#pragma unroll
      for (int r = 0; r < 4; r++) {
        int row = row0 + wm * 64 + fm * 16 + rq * 4 + r;
        Cout[(long long)row * 8192 + col] = f2bf(scl[row] * acc[fm][fn][r]);
      }
    }
  }
}

// ---------------------------------------------------------------------------
// ctx (bf16 MFMA), batch from global row.  Grid (64, 8).
// ---------------------------------------------------------------------------
__global__ __launch_bounds__(256) void gemm_ctx_bf16(
    const unsigned short* __restrict__ w16,
    const unsigned short* __restrict__ VTa, float* __restrict__ ctx) {
  int row0 = blockIdx.x * 64;             // global row in [0, 4096)
  int b = blockIdx.x >> 4;
  int h = blockIdx.y;
  const unsigned short* VT = VTa + (long long)b * 524288;
  __shared__ unsigned short Asl[64][68];
  __shared__ unsigned short Bsl[64][68];
  int t = (int)threadIdx.x, lane = t & 63, wave = t >> 6;

  f32x4 acc[4];
#pragma unroll
  for (int i = 0; i < 4; i++) acc[i] = (f32x4){0.f, 0.f, 0.f, 0.f};

  int r = t >> 2, kq = (t & 3) * 8;
  const unsigned short* Ap = w16 + (long long)(row0 + r) * 8192 + h * 1024 + kq;
  const unsigned short* Bp = VT + (long long)(h * 64 + r) * 1024 + kq;

  for (int kb = 0; kb < 1024; kb += 64) {
    i32x4 a0 = *(const i32x4*)(Ap + kb);
    i32x4 a1 = *(const i32x4*)(Ap + kb + 32);
    i32x4 b0 = *(const i32x4*)(Bp + kb);
    i32x4 b1 = *(const i32x4*)(Bp + kb + 32);
    __syncthreads();
    *(i32x4*)&Asl[r][kq] = a0;
    *(i32x4*)&Asl[r][kq + 32] = a1;
    *(i32x4*)&Bsl[r][kq] = b0;
    *(i32x4*)&Bsl[r][kq + 32] = b1;
    __syncthreads();

    int rr = lane & 15, ko = (lane >> 4) * 8;
#pragma unroll
    for (int k2 = 0; k2 < 2; k2++) {
      i32x4 af = *(i32x4*)&Asl[wave * 16 + rr][k2 * 32 + ko];
#pragma unroll
      for (int fn = 0; fn < 4; fn++) {
        i32x4 bf = *(i32x4*)&Bsl[fn * 16 + rr][k2 * 32 + ko];
        acc[fn] = mfma_bf16(af, bf, acc[fn]);
      }
    }
  }

  int rq = lane >> 4, rr = lane & 15;
#pragma unroll
  for (int fn = 0; fn < 4; fn++) {
#pragma unroll
    for (int rl = 0; rl < 4; rl++) {
      int i = row0 + wave * 16 + rq * 4 + rl;
      ctx[(long long)i * 512 + h * 64 + fn * 16 + rr] = acc[fn][rl];
    }
  }
}

// ---------------------------------------------------------------------------
// Vertical routing — round-8 verbatim (grid 4096; buffers batch-contiguous).
// ---------------------------------------------------------------------------
__global__ __launch_bounds__(256) void vertical_routing_kernel(
    const unsigned short* __restrict__ u16, float* __restrict__ vV) {
  __shared__ float Ur[8 * 1024];
  __shared__ float red[4];
  __shared__ float red8[32];
  int bq = blockIdx.x;
  int t = (int)threadIdx.x;
  const unsigned short* Ub = u16 + (long long)bq * 8192;
#pragma unroll
  for (int r = 0; r < 8; r++) {
    uint2 p = *(const uint2*)&Ub[(t + 256 * r) * 4];
    Ur[(t + 256 * r) * 4 + 0] = bf2f(p.x & 0xffffu);
    Ur[(t + 256 * r) * 4 + 1] = bf2f(p.x >> 16);
    Ur[(t + 256 * r) * 4 + 2] = bf2f(p.y & 0xffffu);
    Ur[(t + 256 * r) * 4 + 3] = bf2f(p.y >> 16);
  }
  __syncthreads();

  float bh[8] = {0.f, 0.f, 0.f, 0.f, 0.f, 0.f, 0.f, 0.f};
  int k0 = t * 4;
  float4 v4 = {0.f, 0.f, 0.f, 0.f};
  for (int it = 0; it < 3; ++it) {
    float m = bh[0];
#pragma unroll
    for (int h = 1; h < 8; h++) m = fmaxf(m, bh[h]);
    float c[8], zz = 0.f;
#pragma unroll
    for (int h = 0; h < 8; h++) {
      c[h] = expf(bh[h] - m);
      zz += c[h];
    }
    float inv = 1.f / zz;
    float4 s4 = {0.f, 0.f, 0.f, 0.f};
#pragma unroll
    for (int h = 0; h < 8; h++) {
      float4 u = *(float4*)&Ur[h * 1024 + k0];
      float ch = c[h] * inv;
      s4.x = fmaf(ch, u.x, s4.x); s4.y = fmaf(ch, u.y, s4.y);
      s4.z = fmaf(ch, u.z, s4.z); s4.w = fmaf(ch, u.w, s4.w);
    }
    float sq =
        blockSum(s4.x * s4.x + s4.y * s4.y + s4.z * s4.z + s4.w * s4.w, red);
    float sc = (sq / (1.f + sq)) / sqrtf(sq + SQ_EPS);
    v4.x = sc * s4.x; v4.y = sc * s4.y; v4.z = sc * s4.z; v4.w = sc * s4.w;
    if (it < 2) {
      float p[8];
#pragma unroll
      for (int h = 0; h < 8; h++) {
        float4 u = *(float4*)&Ur[h * 1024 + k0];
        p[h] = u.x * v4.x + u.y * v4.y + u.z * v4.z + u.w * v4.w;
      }
      __syncthreads();
#pragma unroll
      for (int h = 0; h < 8; h++) {
        float w = wredSum(p[h]);
        if ((t & 63) == 0) red8[(t >> 6) * 8 + h] = w;
      }
      __syncthreads();
#pragma unroll
      for (int h = 0; h < 8; h++)
        bh[h] += red8[h] + red8[8 + h] + red8[16 + h] + red8[24 + h];
    }
  }
  *(float4*)&vV[(long long)bq * 1024 + k0] = v4;
}

// enhanced softmax — round-8 verbatim (grid 32768; buffers batch-contiguous).
__global__ __launch_bounds__(256) void enh_softmax_kernel(
    unsigned short* __restrict__ u16, const float* __restrict__ vV,
    const unsigned short* __restrict__ v16) {
  __shared__ float red[4];
  int idx = blockIdx.x;  // B*Q*H
  int h = idx & 7;
  int bq = idx >> 3;
  unsigned short* Urow = u16 + (long long)bq * 8192 + h * 1024;
  const float* va = vV + (long long)bq * 1024;
  const unsigned short* vb = v16 + (long long)bq * 8192 + h * 1024;
  int t = (int)threadIdx.x, k0 = t * 4;
  uint2 pu = *(const uint2*)&Urow[k0];
  float4 a = *(const float4*)&va[k0];
  uint2 pb = *(const uint2*)&vb[k0];
  float x0 = bf2f(pu.x & 0xffffu) + a.x + bf2f(pb.x & 0xffffu);
  float x1 = bf2f(pu.x >> 16) + a.y + bf2f(pb.x >> 16);
  float x2 = bf2f(pu.y & 0xffffu) + a.z + bf2f(pb.y & 0xffffu);
  float x3 = bf2f(pu.y >> 16) + a.w + bf2f(pb.y >> 16);
  float mx = blockMax(fmaxf(fmaxf(x0, x1), fmaxf(x2, x3)), red);
  float e0 = expf(x0 - mx), e1 = expf(x1 - mx), e2 = expf(x2 - mx),
        e3 = expf(x3 - mx);
  float zz = blockSum(e0 + e1 + e2 + e3, red);
  float inv = 1.f / zz;
  uint2 o = {(unsigned int)f2bf(e0 * inv) | ((unsigned int)f2bf(e1 * inv) << 16),
             (unsigned int)f2bf(e2 * inv) | ((unsigned int)f2bf(e3 * inv) << 16)};
  *(uint2*)&Urow[k0] = o;
}

// ---------------------------------------------------------------------------
extern "C" void kernel_launch(void* const* d_in, const int* in_sizes, int n_in,
                              void* d_out, int out_size, void* d_ws,
                              size_t ws_size, hipStream_t stream) {
  (void)in_sizes; (void)n_in; (void)out_size; (void)ws_size;
  const float* x = (const float*)d_in[0];
  const float* Wq = (const float*)d_in[1];
  const float* bq = (const float*)d_in[2];
  const float* Wk = (const float*)d_in[3];
  const float* bk = (const float*)d_in[4];
  const float* Wv = (const float*)d_in[5];
  const float* bv = (const float*)d_in[6];
  const float* Wo = (const float*)d_in[7];
  const float* bo = (const float*)d_in[8];
  float* out = (float*)d_out;
  float* ws = (float*)d_ws;

  unsigned short* u16a = (unsigned short*)(ws);              // 16,777,216 fl
  unsigned short* uT16a = (unsigned short*)(ws + 16777216);  // 16,777,216 fl
  // OVR region (16,777,216 fl @ 33554432):
  float* Qf = ws + 33554432;                                 //  2,097,152
  float* Kf = ws + 35651584;                                 //  2,097,152
  float* Pa = ws + 37748736;                                 //  8,388,608
  float* Mbufa = ws + 46137344;                              //  4,194,304
  unsigned short* sv16a = (unsigned short*)(ws + 33554432);  // overlays OVR
  float* vVa = ws + 50331648;                                //  4,194,304
  float* bHa = ws + 54525952;                                //  4,194,304
  float* ctxa = ws + 54525952;                               // overlays bHa
  unsigned short* cH16a = (unsigned short*)(ws + 58720256);  //  2,097,152 fl
  unsigned short* G16a = (unsigned short*)(ws + 60817408);   //  2,097,152 fl
  unsigned short* V16a = (unsigned short*)(ws + 62914560);   //  1,048,576 fl
  unsigned short* VT16a = (unsigned short*)(ws + 63963136);  //  1,048,576 fl
  unsigned short* WT16 = (unsigned short*)(ws + 65011712);   //    393,216 fl
  float* scl = ws + 65404928;                                //      4,096
  // total 65,409,024 fl = 249.5 MiB

  // 1-3. prologue
  wtrans_kernel<<<dim3(8, 8, 3), 256, 0, stream>>>(Wq, Wk, Wv, WT16);
  gemm_qkv_mfma<<<dim3(8, 64, 3), 256, 0, stream>>>(x, WT16, bq, bk, bv, Qf,
                                                    Kf, V16a);
  transpose16_kernel<<<dim3(16, 8, 4), 256, 0, stream>>>(V16a, VT16a, 512,
                                                         1024, 524288, 524288);

  // 4. scores (dual-writes u and u^T), all batches
  gemm_scores_bf16<<<dim3(8, 8, 32), 256, 0, stream>>>(Qf, Kf, u16a, uT16a);

  // 5. vertical routing, all batches
  vertical_routing_kernel<<<dim3(4096), 256, 0, stream>>>(u16a, vVa);

  // 6. G = u·u^T (lower triangle, split-K=2), all batches; merge + mirror
  gemm_G_bf16<<<dim3(16, 16, 8), 256, 0, stream>>>(u16a, Pa);
  merge_mirror_G_kernel<<<dim3(1024, 4), 256, 0, stream>>>(Pa, G16a);

  // 7. horizontal routing iterations (all batches per stage)
  softmax_uniform_kernel<<<dim3(1024, 4), 256, 0, stream>>>(cH16a);
  gemm_M_bf16<<<dim3(16, 16, 4), 256, 0, stream>>>(cH16a, G16a, Mbufa);
  scldot_kernel<<<dim3(1024, 4), 256, 0, stream>>>(Mbufa, cH16a, scl);
  bupd_softmax_kernel<1><<<dim3(1024, 4), 256, 0, stream>>>(bHa, Mbufa, scl,
                                                            cH16a);
  gemm_M_bf16<<<dim3(16, 16, 4), 256, 0, stream>>>(cH16a, G16a, Mbufa);
  scldot_kernel<<<dim3(1024, 4), 256, 0, stream>>>(Mbufa, cH16a, scl);
  bupd_softmax_kernel<0><<<dim3(1024, 4), 256, 0, stream>>>(bHa, Mbufa, scl,
                                                            cH16a);
  gemm_M_bf16<<<dim3(16, 16, 4), 256, 0, stream>>>(cH16a, G16a, Mbufa);
  scldot_kernel<<<dim3(1024, 4), 256, 0, stream>>>(Mbufa, cH16a, scl);

  // 8. final v = scl·(C·u)  (writes sv16a over dead Qf/Kf/Pa/Mbufa)
  gemm_s_scl<<<dim3(64, 8, 4), 256, 0, stream>>>(cH16a, uT16a, scl, sv16a);

  // 9. enhanced + softmax -> w into u16a
  enh_softmax_kernel<<<dim3(32768), 256, 0, stream>>>(u16a, vVa, sv16a);

  // 10. ctx = w x V  (writes ctxa over dead bHa)
  gemm_ctx_bf16<<<dim3(64, 8), 256, 0, stream>>>(u16a, VT16a, ctxa);

  // 11. out = ctx x Wo + bo
  gemm_f32<64, 64, 16><<<dim3(8, 64), 256, 0, stream>>>(ctxa, Wo, out, bo, 512,
                                                        512, 512, 512);
}

// Round 10
// 492.302 us; speedup vs baseline: 14.0911x; 1.0781x over previous
//
#include <hip/hip_runtime.h>
#include <math.h>

// ---------------------------------------------------------------------------
// CapsuleRoutingSelfAttention — round 10.
//   * gemm_G on 128x128 tiles (gemm_s mold), split-K=4, triangular skip
//   * out-projection on bf16 MFMA (ctx stored bf16, Wo^T via wtrans z=4)
//   * scldot+bupd fused for it0/it1
//
// Workspace (float units), 66,064,384 fl = 252.0 MiB (ws = 256 MiB):
//   u16a  [4][1024][8192] bf16 @ 0
//   uT16a [4][8192][1024] bf16 @ 16777216
//   OVR @ 33554432 (16,777,216 fl), time-multiplexed:
//     Qf @33554432 (2M) | Kf @35651584 (2M)      [die after scores]
//     Pa @33554432 (16 x 1M fl, G partials)      [after scores; die at merge]
//     Mbufa @33554432 (4M)                       [after merge; dies after it2]
//     sv16a bf16 @33554432 (16M fl)              [written by s_scl at the end]
//   vVa @ 50331648 (4M) | bHa @ 54525952 (4M); ctx16 bf16 overlays bHa (1M fl)
//   cH16a @ 58720256 (2M fl) | G16a @ 60817408 (2M fl)
//   V16a @ 62914560 (1M fl) | VT16a @ 63963136 (1M fl)
//   WT16 @ 65011712 (4 x 262144 = 1M fl, incl Wo^T) | scl @ 66060288 (4096)
// ---------------------------------------------------------------------------

#define SQ_EPS 1e-8f

typedef __attribute__((ext_vector_type(4))) int i32x4;    // 8 bf16
typedef __attribute__((ext_vector_type(4))) float f32x4;

__device__ __forceinline__ float bf2f(unsigned int u) {
  union { unsigned int i; float f; } x;
  x.i = u << 16;
  return x.f;
}
__device__ __forceinline__ unsigned short f2bf(float f) {
  union { float f; unsigned int i; } x;
  x.f = f;
  unsigned int r = x.i + 0x7fffu + ((x.i >> 16) & 1u);
  return (unsigned short)(r >> 16);
}
__device__ __forceinline__ int packbf(float a, float b) {
  return (int)((unsigned int)f2bf(a) | ((unsigned int)f2bf(b) << 16));
}

__device__ __forceinline__ f32x4 mfma_bf16(i32x4 a, i32x4 b, f32x4 c) {
  asm("v_mfma_f32_16x16x32_bf16 %0, %1, %2, %0" : "+v"(c) : "v"(a), "v"(b));
  return c;
}

__device__ __forceinline__ float wredSum(float v) {
#pragma unroll
  for (int off = 32; off > 0; off >>= 1) v += __shfl_xor(v, off);
  return v;
}
__device__ __forceinline__ float wredMax(float v) {
#pragma unroll
  for (int off = 32; off > 0; off >>= 1) v = fmaxf(v, __shfl_xor(v, off));
  return v;
}
__device__ __forceinline__ float blockSum(float v, volatile float* red) {
  v = wredSum(v);
  int wid = threadIdx.x >> 6;
  __syncthreads();
  if ((threadIdx.x & 63) == 0) red[wid] = v;
  __syncthreads();
  return red[0] + red[1] + red[2] + red[3];
}
__device__ __forceinline__ float blockMax(float v, volatile float* red) {
  v = wredMax(v);
  int wid = threadIdx.x >> 6;
  __syncthreads();
  if ((threadIdx.x & 63) == 0) red[wid] = v;
  __syncthreads();
  return fmaxf(fmaxf(red[0], red[1]), fmaxf(red[2], red[3]));
}

// ---------------------------------------------------------------------------
// W^T prep (now includes Wo at z=3).  Grid (8, 8, 4).
// ---------------------------------------------------------------------------
__global__ __launch_bounds__(256) void wtrans_kernel(
    const float* __restrict__ Wq, const float* __restrict__ Wk,
    const float* __restrict__ Wv, const float* __restrict__ Wo,
    unsigned short* __restrict__ WT16) {
  __shared__ unsigned short T[64][72];
  int z = blockIdx.z;
  const float* src = (z == 0) ? Wq : (z == 1) ? Wk : (z == 2) ? Wv : Wo;
  unsigned short* dst = WT16 + (long long)z * 262144;
  int i0 = blockIdx.x * 64;
  int c0 = blockIdx.y * 64;
  int t = (int)threadIdx.x;
  int r = t >> 2, cq = (t & 3) * 16;
#pragma unroll
  for (int j = 0; j < 4; j++) {
    float4 v = *(const float4*)&src[(long long)(i0 + r) * 512 + c0 + cq + j * 4];
    T[r][cq + j * 4 + 0] = f2bf(v.x);
    T[r][cq + j * 4 + 1] = f2bf(v.y);
    T[r][cq + j * 4 + 2] = f2bf(v.z);
    T[r][cq + j * 4 + 3] = f2bf(v.w);
  }
  __syncthreads();
  int c = t >> 2, iq = (t & 3) * 16;
  unsigned short tmp[16];
#pragma unroll
  for (int j = 0; j < 16; j++) tmp[j] = T[iq + j][c];
  *(i32x4*)&dst[(long long)(c0 + c) * 512 + i0 + iq] = *(i32x4*)&tmp[0];
  *(i32x4*)&dst[(long long)(c0 + c) * 512 + i0 + iq + 8] = *(i32x4*)&tmp[8];
}

// ---------------------------------------------------------------------------
// QKV (bf16 MFMA, all batches) — round-9 verbatim.
// ---------------------------------------------------------------------------
__global__ __launch_bounds__(256) void gemm_qkv_mfma(
    const float* __restrict__ x, const unsigned short* __restrict__ WT16,
    const float* __restrict__ bq, const float* __restrict__ bk,
    const float* __restrict__ bv, float* __restrict__ Qf,
    float* __restrict__ Kf, unsigned short* __restrict__ V16) {
  __shared__ unsigned short Asl[64][68];
  __shared__ unsigned short Bsl[64][68];
  int z = blockIdx.z;
  const unsigned short* WT = WT16 + (long long)z * 262144;
  const float* bias = (z == 0) ? bq : (z == 1) ? bk : bv;

  int row0 = blockIdx.y * 64;
  int col0 = blockIdx.x * 64;
  int t = (int)threadIdx.x, lane = t & 63, wave = t >> 6;
  int wm = wave >> 1, wn = wave & 1;

  f32x4 acc[2][2];
#pragma unroll
  for (int i = 0; i < 2; i++)
#pragma unroll
    for (int j = 0; j < 2; j++) acc[i][j] = (f32x4){0.f, 0.f, 0.f, 0.f};

  int r = t >> 2, kq = (t & 3) * 8;
  const float* Ap = x + (long long)(row0 + r) * 512 + kq;
  const unsigned short* Bp = WT + (long long)(col0 + r) * 512 + kq;

  for (int kb = 0; kb < 512; kb += 64) {
    float4 a0 = *(const float4*)(Ap + kb);
    float4 a1 = *(const float4*)(Ap + kb + 4);
    float4 a2 = *(const float4*)(Ap + kb + 32);
    float4 a3 = *(const float4*)(Ap + kb + 36);
    i32x4 b0 = *(const i32x4*)(Bp + kb);
    i32x4 b1 = *(const i32x4*)(Bp + kb + 32);
    __syncthreads();
    i32x4 pa0 = {packbf(a0.x, a0.y), packbf(a0.z, a0.w), packbf(a1.x, a1.y),
                 packbf(a1.z, a1.w)};
    i32x4 pa1 = {packbf(a2.x, a2.y), packbf(a2.z, a2.w), packbf(a3.x, a3.y),
                 packbf(a3.z, a3.w)};
    *(i32x4*)&Asl[r][kq] = pa0;
    *(i32x4*)&Asl[r][kq + 32] = pa1;
    *(i32x4*)&Bsl[r][kq] = b0;
    *(i32x4*)&Bsl[r][kq + 32] = b1;
    __syncthreads();

    int rr = lane & 15, ko = (lane >> 4) * 8;
#pragma unroll
    for (int k2 = 0; k2 < 2; k2++) {
      i32x4 af0 = *(i32x4*)&Asl[wm * 32 + rr][k2 * 32 + ko];
      i32x4 af1 = *(i32x4*)&Asl[wm * 32 + 16 + rr][k2 * 32 + ko];
      i32x4 bf0 = *(i32x4*)&Bsl[wn * 32 + rr][k2 * 32 + ko];
      i32x4 bf1 = *(i32x4*)&Bsl[wn * 32 + 16 + rr][k2 * 32 + ko];
      acc[0][0] = mfma_bf16(af0, bf0, acc[0][0]);
      acc[0][1] = mfma_bf16(af0, bf1, acc[0][1]);
      acc[1][0] = mfma_bf16(af1, bf0, acc[1][0]);
      acc[1][1] = mfma_bf16(af1, bf1, acc[1][1]);
    }
  }

  int rq = lane >> 4, rr = lane & 15;
#pragma unroll
  for (int fm = 0; fm < 2; fm++) {
#pragma unroll
    for (int fn = 0; fn < 2; fn++) {
      int col = col0 + wn * 32 + fn * 16 + rr;
      float bb = bias[col];
#pragma unroll
      for (int rl = 0; rl < 4; rl++) {
        int row = row0 + wm * 32 + fm * 16 + rq * 4 + rl;
        float v = acc[fm][fn][rl] + bb;
        if (z == 2)
          V16[(long long)row * 512 + col] = f2bf(v);
        else if (z == 1)
          Kf[(long long)row * 512 + col] = v;
        else
          Qf[(long long)row * 512 + col] = v;
      }
    }
  }
}

// ---------------------------------------------------------------------------
// Out-projection (bf16 MFMA): out = ctx16 x Wo + bo.  qkv mold, A already
// bf16 (no packing).  Grid (8, 64).
// ---------------------------------------------------------------------------
__global__ __launch_bounds__(256) void gemm_out_mfma(
    const unsigned short* __restrict__ A16,   // ctx16 [4096,512]
    const unsigned short* __restrict__ WoT,   // [512,512] bf16 (n,k)
    const float* __restrict__ bo, float* __restrict__ out) {
  __shared__ unsigned short Asl[64][68];
  __shared__ unsigned short Bsl[64][68];
  int row0 = blockIdx.y * 64;
  int col0 = blockIdx.x * 64;
  int t = (int)threadIdx.x, lane = t & 63, wave = t >> 6;
  int wm = wave >> 1, wn = wave & 1;

  f32x4 acc[2][2];
#pragma unroll
  for (int i = 0; i < 2; i++)
#pragma unroll
    for (int j = 0; j < 2; j++) acc[i][j] = (f32x4){0.f, 0.f, 0.f, 0.f};

  int r = t >> 2, kq = (t & 3) * 8;
  const unsigned short* Ap = A16 + (long long)(row0 + r) * 512 + kq;
  const unsigned short* Bp = WoT + (long long)(col0 + r) * 512 + kq;

  for (int kb = 0; kb < 512; kb += 64) {
    i32x4 a0 = *(const i32x4*)(Ap + kb);
    i32x4 a1 = *(const i32x4*)(Ap + kb + 32);
    i32x4 b0 = *(const i32x4*)(Bp + kb);
    i32x4 b1 = *(const i32x4*)(Bp + kb + 32);
    __syncthreads();
    *(i32x4*)&Asl[r][kq] = a0;
    *(i32x4*)&Asl[r][kq + 32] = a1;
    *(i32x4*)&Bsl[r][kq] = b0;
    *(i32x4*)&Bsl[r][kq + 32] = b1;
    __syncthreads();

    int rr = lane & 15, ko = (lane >> 4) * 8;
#pragma unroll
    for (int k2 = 0; k2 < 2; k2++) {
      i32x4 af0 = *(i32x4*)&Asl[wm * 32 + rr][k2 * 32 + ko];
      i32x4 af1 = *(i32x4*)&Asl[wm * 32 + 16 + rr][k2 * 32 + ko];
      i32x4 bf0 = *(i32x4*)&Bsl[wn * 32 + rr][k2 * 32 + ko];
      i32x4 bf1 = *(i32x4*)&Bsl[wn * 32 + 16 + rr][k2 * 32 + ko];
      acc[0][0] = mfma_bf16(af0, bf0, acc[0][0]);
      acc[0][1] = mfma_bf16(af0, bf1, acc[0][1]);
      acc[1][0] = mfma_bf16(af1, bf0, acc[1][0]);
      acc[1][1] = mfma_bf16(af1, bf1, acc[1][1]);
    }
  }

  int rq = lane >> 4, rr = lane & 15;
#pragma unroll
  for (int fm = 0; fm < 2; fm++) {
#pragma unroll
    for (int fn = 0; fn < 2; fn++) {
      int col = col0 + wn * 32 + fn * 16 + rr;
      float bb = bo[col];
#pragma unroll
      for (int rl = 0; rl < 4; rl++) {
        int row = row0 + wm * 32 + fm * 16 + rq * 4 + rl;
        out[(long long)row * 512 + col] = acc[fm][fn][rl] + bb;
      }
    }
  }
}

// ---------------------------------------------------------------------------
// Scores (fp32 compute, bf16 out, dual u/u^T write) — round-9 verbatim.
// ---------------------------------------------------------------------------
__global__ __launch_bounds__(256) void gemm_scores_bf16(
    const float* __restrict__ Qf, const float* __restrict__ Kf,
    unsigned short* __restrict__ u16a, unsigned short* __restrict__ uT16a) {
  __shared__ float As[8][132];
  __shared__ float Bs[8][132];
  int z = blockIdx.z;
  int b = z >> 3, h = z & 7;
  const float* A = Qf + (long long)b * 524288 + h * 64;
  const float* B = Kf + (long long)b * 524288 + h * 64;
  unsigned short* C16 = u16a + (long long)b * 8388608 + h * 1024;
  unsigned short* uTb = uT16a + (long long)b * 8388608;

  int row0 = blockIdx.y * 128;
  int col0 = blockIdx.x * 128;
  int tid = (int)threadIdx.x;
  int tx = tid & 15, ty = tid >> 4;
  int arow = tid >> 1;
  int akc = (tid & 1) * 4;

  float acc[8][8];
#pragma unroll
  for (int i = 0; i < 8; i++)
#pragma unroll
    for (int j = 0; j < 8; j++) acc[i][j] = 0.f;

  const float* Aptr = A + (long long)(row0 + arow) * 512 + akc;
  const float* Bptr = B + (long long)(col0 + arow) * 512 + akc;

  for (int kb = 0; kb < 64; kb += 8) {
    float4 av = *(const float4*)(Aptr + kb);
    float4 bv = *(const float4*)(Bptr + kb);
    __syncthreads();
    As[akc + 0][arow] = av.x; As[akc + 1][arow] = av.y;
    As[akc + 2][arow] = av.z; As[akc + 3][arow] = av.w;
    Bs[akc + 0][arow] = bv.x; Bs[akc + 1][arow] = bv.y;
    Bs[akc + 2][arow] = bv.z; Bs[akc + 3][arow] = bv.w;
    __syncthreads();

#pragma unroll
    for (int k = 0; k < 8; k++) {
      float a[8], b2[8];
#pragma unroll
      for (int c = 0; c < 2; c++) {
        float4 q = *(float4*)&As[k][ty * 8 + c * 4];
        a[c * 4 + 0] = q.x; a[c * 4 + 1] = q.y;
        a[c * 4 + 2] = q.z; a[c * 4 + 3] = q.w;
      }
#pragma unroll
      for (int c = 0; c < 2; c++) {
        float4 q = *(float4*)&Bs[k][c * 64 + tx * 4];
        b2[c * 4 + 0] = q.x; b2[c * 4 + 1] = q.y;
        b2[c * 4 + 2] = q.z; b2[c * 4 + 3] = q.w;
      }
#pragma unroll
      for (int i = 0; i < 8; i++)
#pragma unroll
        for (int j = 0; j < 8; j++) acc[i][j] = fmaf(a[i], b2[j], acc[i][j]);
    }
  }

#pragma unroll
  for (int i = 0; i < 8; i++) {
    long long r = row0 + ty * 8 + i;
#pragma unroll
    for (int c = 0; c < 2; c++) {
      int col = col0 + c * 64 + tx * 4;
      unsigned int lo = (unsigned int)f2bf(0.125f * acc[i][c * 4 + 0]) |
                        ((unsigned int)f2bf(0.125f * acc[i][c * 4 + 1]) << 16);
      unsigned int hi = (unsigned int)f2bf(0.125f * acc[i][c * 4 + 2]) |
                        ((unsigned int)f2bf(0.125f * acc[i][c * 4 + 3]) << 16);
      uint2 o = {lo, hi};
      *(uint2*)&C16[r * 8192 + col] = o;
    }
  }
#pragma unroll
  for (int c = 0; c < 2; c++) {
#pragma unroll
    for (int cc = 0; cc < 4; cc++) {
      int colg = col0 + c * 64 + tx * 4 + cc;
      i32x4 pk;
      pk[0] = packbf(0.125f * acc[0][c * 4 + cc], 0.125f * acc[1][c * 4 + cc]);
      pk[1] = packbf(0.125f * acc[2][c * 4 + cc], 0.125f * acc[3][c * 4 + cc]);
      pk[2] = packbf(0.125f * acc[4][c * 4 + cc], 0.125f * acc[5][c * 4 + cc]);
      pk[3] = packbf(0.125f * acc[6][c * 4 + cc], 0.125f * acc[7][c * 4 + cc]);
      *(i32x4*)&uTb[(long long)(h * 1024 + colg) * 1024 + row0 + ty * 8] = pk;
    }
  }
}

// ---------------------------------------------------------------------------
// bf16 transpose (V), z-batched — round-9 verbatim.
// ---------------------------------------------------------------------------
__global__ __launch_bounds__(256) void transpose16_kernel(
    const unsigned short* __restrict__ src, unsigned short* __restrict__ dst,
    int ldS, int ldD, long long zsS, long long zsD) {
  __shared__ unsigned short T[64][72];
  src += (long long)blockIdx.z * zsS;
  dst += (long long)blockIdx.z * zsD;
  int i0 = blockIdx.x * 64;
  int c0 = blockIdx.y * 64;
  int t = (int)threadIdx.x;
  int r = t >> 2, cq = (t & 3) * 16;
  i32x4 v0 = *(const i32x4*)&src[(long long)(i0 + r) * ldS + c0 + cq];
  i32x4 v1 = *(const i32x4*)&src[(long long)(i0 + r) * ldS + c0 + cq + 8];
  *(i32x4*)&T[r][cq] = v0;
  *(i32x4*)&T[r][cq + 8] = v1;
  __syncthreads();
  int c = t >> 2, iq = (t & 3) * 16;
  unsigned short tmp[16];
#pragma unroll
  for (int j = 0; j < 16; j++) tmp[j] = T[iq + j][c];
  *(i32x4*)&dst[(long long)(c0 + c) * ldD + i0 + iq] = *(i32x4*)&tmp[0];
  *(i32x4*)&dst[(long long)(c0 + c) * ldD + i0 + iq + 8] = *(i32x4*)&tmp[8];
}

// ---------------------------------------------------------------------------
// G = u·u^T lower triangle (bf16 MFMA, 128x128 tile, split-K=4).
// gemm_s mold: LDS [128][32], acc[4][4], BK=32.  Grid (8, 8, 16): z=b*4+ks.
// P[z][i,j] = sum_{c in chunk ks} u[i,c]·u[j,c].
// ---------------------------------------------------------------------------
__global__ __launch_bounds__(256) void gemm_G128_bf16(
    const unsigned short* __restrict__ U16a, float* __restrict__ P) {
  __shared__ unsigned short Alds[128][32];
  __shared__ unsigned short Blds[128][32];
  int row0 = blockIdx.y * 128;
  int col0 = blockIdx.x * 128;
  if (col0 > row0) return;
  int z = blockIdx.z;
  int b = z >> 2, ks = z & 3;
  const unsigned short* U = U16a + (long long)b * 8388608;
  int t = (int)threadIdx.x, lane = t & 63, wave = t >> 6;
  int wm = wave >> 1, wn = wave & 1;

  f32x4 acc[4][4];
#pragma unroll
  for (int i = 0; i < 4; i++)
#pragma unroll
    for (int j = 0; j < 4; j++) acc[i][j] = (f32x4){0.f, 0.f, 0.f, 0.f};

  int ar = t >> 2;
  int aq = (t & 3) * 8;
  const unsigned short* Ap = U + (long long)(row0 + ar) * 8192 + ks * 2048 + aq;
  const unsigned short* Ap2 = Ap + 64LL * 8192;
  const unsigned short* Bp = U + (long long)(col0 + ar) * 8192 + ks * 2048 + aq;
  const unsigned short* Bp2 = Bp + 64LL * 8192;

  for (int kb = 0; kb < 2048; kb += 32) {
    i32x4 a0 = *(const i32x4*)(Ap + kb);
    i32x4 a1 = *(const i32x4*)(Ap2 + kb);
    i32x4 b0 = *(const i32x4*)(Bp + kb);
    i32x4 b1 = *(const i32x4*)(Bp2 + kb);
    __syncthreads();
    *(i32x4*)&Alds[ar][aq] = a0;
    *(i32x4*)&Alds[ar + 64][aq] = a1;
    *(i32x4*)&Blds[ar][aq] = b0;
    *(i32x4*)&Blds[ar + 64][aq] = b1;
    __syncthreads();

    int rr = lane & 15, koff = (lane >> 4) * 8;
    i32x4 af[4], bfv[4];
#pragma unroll
    for (int fm = 0; fm < 4; fm++)
      af[fm] = *(i32x4*)&Alds[wm * 64 + fm * 16 + rr][koff];
#pragma unroll
    for (int fn = 0; fn < 4; fn++)
      bfv[fn] = *(i32x4*)&Blds[wn * 64 + fn * 16 + rr][koff];
#pragma unroll
    for (int fm = 0; fm < 4; fm++)
#pragma unroll
      for (int fn = 0; fn < 4; fn++)
        acc[fm][fn] = mfma_bf16(af[fm], bfv[fn], acc[fm][fn]);
  }

  float* dst = P + (long long)z * 1048576;
  int rq = lane >> 4, rr = lane & 15;
#pragma unroll
  for (int fm = 0; fm < 4; fm++) {
#pragma unroll
    for (int fn = 0; fn < 4; fn++) {
      int col = col0 + wn * 64 + fn * 16 + rr;
#pragma unroll
      for (int r = 0; r < 4; r++) {
        int row = row0 + wm * 64 + fm * 16 + rq * 4 + r;
        dst[(long long)row * 1024 + col] = acc[fm][fn][r];
      }
    }
  }
}

// G16 = bf16(sum_{ks} P[b*4+ks]), mirrored to upper triangle.  Grid (1024,4).
__global__ __launch_bounds__(256) void merge_mirror_G_kernel(
    const float* __restrict__ P, unsigned short* __restrict__ G16a) {
  int i = blockIdx.x;
  int b = blockIdx.y;
  int t = (int)threadIdx.x, j0 = t * 4;
  if (j0 > i) return;
  const float* Pb = P + (long long)(b * 4) * 1048576 + (long long)i * 1024;
  unsigned short* Gb = G16a + (long long)b * 1048576;
  float4 s = {0.f, 0.f, 0.f, 0.f};
#pragma unroll
  for (int z = 0; z < 4; z++) {
    float4 p = *(const float4*)&Pb[(long long)z * 1048576 + j0];
    s.x += p.x; s.y += p.y; s.z += p.z; s.w += p.w;
  }
  float v[4] = {s.x, s.y, s.z, s.w};
#pragma unroll
  for (int e = 0; e < 4; e++) {
    int j = j0 + e;
    if (j > i) break;
    unsigned short g = f2bf(v[e]);
    Gb[(long long)i * 1024 + j] = g;
    if (j < i) Gb[(long long)j * 1024 + i] = g;
  }
}

// ---------------------------------------------------------------------------
// M = C·G (bf16 MFMA, z-batched) — round-9 verbatim.
// ---------------------------------------------------------------------------
__global__ __launch_bounds__(256) void gemm_M_bf16(
    const unsigned short* __restrict__ Ca, const unsigned short* __restrict__ Ga,
    float* __restrict__ Ma) {
  int row0 = blockIdx.y * 64;
  int col0 = blockIdx.x * 64;
  if (col0 > row0) return;
  int b = blockIdx.z;
  const unsigned short* C = Ca + (long long)b * 1048576;
  const unsigned short* G = Ga + (long long)b * 1048576;
  float* M = Ma + (long long)b * 1048576;
  int Kend = row0 + 64;
  __shared__ unsigned short Asl[64][64];
  __shared__ unsigned short Bsl[64][64];
  int t = (int)threadIdx.x, lane = t & 63, wave = t >> 6;
  int wm = wave >> 1, wn = wave & 1;

  f32x4 acc[2][2];
#pragma unroll
  for (int i = 0; i < 2; i++)
#pragma unroll
    for (int j = 0; j < 2; j++) acc[i][j] = (f32x4){0.f, 0.f, 0.f, 0.f};

  int r = t >> 2, c0 = t & 3;
  int sw0 = ((c0 ^ (r & 7))) * 8;
  int sw1 = (((c0 + 4) ^ (r & 7))) * 8;
  const unsigned short* Ap = C + (long long)(row0 + r) * 1024 + c0 * 8;
  const unsigned short* Bp = G + (long long)(col0 + r) * 1024 + c0 * 8;

  for (int kb = 0; kb < Kend; kb += 64) {
    i32x4 a0 = *(const i32x4*)(Ap + kb);
    i32x4 a1 = *(const i32x4*)(Ap + kb + 32);
    i32x4 b0 = *(const i32x4*)(Bp + kb);
    i32x4 b1 = *(const i32x4*)(Bp + kb + 32);
    __syncthreads();
    *(i32x4*)&Asl[r][sw0] = a0;
    *(i32x4*)&Asl[r][sw1] = a1;
    *(i32x4*)&Bsl[r][sw0] = b0;
    *(i32x4*)&Bsl[r][sw1] = b1;
    __syncthreads();

    int rr = lane & 15, co = lane >> 4;
#pragma unroll
    for (int k2 = 0; k2 < 2; k2++) {
      int ch = ((k2 * 4 + co) ^ (rr & 7)) * 8;
      i32x4 af0 = *(i32x4*)&Asl[wm * 32 + rr][ch];
      i32x4 af1 = *(i32x4*)&Asl[wm * 32 + 16 + rr][ch];
      i32x4 bf0 = *(i32x4*)&Bsl[wn * 32 + rr][ch];
      i32x4 bf1 = *(i32x4*)&Bsl[wn * 32 + 16 + rr][ch];
      acc[0][0] = mfma_bf16(af0, bf0, acc[0][0]);
      acc[0][1] = mfma_bf16(af0, bf1, acc[0][1]);
      acc[1][0] = mfma_bf16(af1, bf0, acc[1][0]);
      acc[1][1] = mfma_bf16(af1, bf1, acc[1][1]);
    }
  }

  int rq = lane >> 4, rr = lane & 15;
#pragma unroll
  for (int fm = 0; fm < 2; fm++) {
#pragma unroll
    for (int fn = 0; fn < 2; fn++) {
      int j = col0 + wn * 32 + fn * 16 + rr;
#pragma unroll
      for (int rl = 0; rl < 4; rl++) {
        int i = row0 + wm * 32 + fm * 16 + rq * 4 + rl;
        M[(long long)i * 1024 + j] = acc[fm][fn][rl];
      }
    }
  }
}

// ---------------------------------------------------------------------------
// Fused scldot + b-update + causal softmax (it0/it1).  Grid (1024, 4).
// ssq = sum_{j<=i} c[i,j]·M[i,j]; scl = squash scale; bH (+)= scl·M (j<=i);
// cH16 = causal softmax(bH).  Same math/order as scldot+bupd separately.
// ---------------------------------------------------------------------------
template <int INIT>
__global__ __launch_bounds__(256) void fused_scl_bupd_kernel(
    float* __restrict__ bHa, const float* __restrict__ Ma,
    unsigned short* __restrict__ cH16a) {
  __shared__ float red[4];
  int i = blockIdx.x;
  int b = blockIdx.y;
  float* bH = bHa + (long long)b * 1048576;
  const float* M = Ma + (long long)b * 1048576;
  unsigned short* cH16 = cH16a + (long long)b * 1048576;
  long long base = (long long)i * 1024;
  int t = (int)threadIdx.x, k0 = t * 4;
  float4 m = *(const float4*)&M[base + k0];
  uint2 pc = *(const uint2*)&cH16[base + k0];
  float c0 = bf2f(pc.x & 0xffffu), c1 = bf2f(pc.x >> 16);
  float c2 = bf2f(pc.y & 0xffffu), c3 = bf2f(pc.y >> 16);
  bool m0 = (k0 + 0) <= i, m1 = (k0 + 1) <= i, m2 = (k0 + 2) <= i,
       m3 = (k0 + 3) <= i;
  float acc = 0.f;
  if (m0) acc += c0 * m.x;
  if (m1) acc += c1 * m.y;
  if (m2) acc += c2 * m.z;
  if (m3) acc += c3 * m.w;
  float ssq = blockSum(acc, red);
  float sc = (ssq / (1.f + ssq)) / sqrtf(ssq + SQ_EPS);

  float4 x;
  if (INIT) x = (float4){0.f, 0.f, 0.f, 0.f};
  else x = *(const float4*)&bH[base + k0];
  if (m0) x.x += sc * m.x;
  if (m1) x.y += sc * m.y;
  if (m2) x.z += sc * m.z;
  if (m3) x.w += sc * m.w;
  *(float4*)&bH[base + k0] = x;
  float mx = -3.0e38f;
  if (m0) mx = fmaxf(mx, x.x);
  if (m1) mx = fmaxf(mx, x.y);
  if (m2) mx = fmaxf(mx, x.z);
  if (m3) mx = fmaxf(mx, x.w);
  mx = blockMax(mx, red);
  float e0 = m0 ? expf(x.x - mx) : 0.f;
  float e1 = m1 ? expf(x.y - mx) : 0.f;
  float e2 = m2 ? expf(x.z - mx) : 0.f;
  float e3 = m3 ? expf(x.w - mx) : 0.f;
  float zz = blockSum(e0 + e1 + e2 + e3, red);
  float inv = 1.f / zz;
  uint2 o = {(unsigned int)f2bf(e0 * inv) | ((unsigned int)f2bf(e1 * inv) << 16),
             (unsigned int)f2bf(e2 * inv) | ((unsigned int)f2bf(e3 * inv) << 16)};
  *(uint2*)&cH16[base + k0] = o;
}

// ||s_i||^2 -> scl (it2 only; scl needed by gemm_s_scl).  Grid (1024, 4).
__global__ __launch_bounds__(256) void scldot_kernel(
    const float* __restrict__ Ma, const unsigned short* __restrict__ Ca,
    float* __restrict__ scl) {
  __shared__ float red[4];
  int i = blockIdx.x;
  int b = blockIdx.y;
  const float* M = Ma + (long long)b * 1048576;
  const unsigned short* C = Ca + (long long)b * 1048576;
  int t = (int)threadIdx.x, j0 = t * 4;
  long long base = (long long)i * 1024;
  float4 m = *(const float4*)&M[base + j0];
  uint2 pc = *(const uint2*)&C[base + j0];
  float c0 = bf2f(pc.x & 0xffffu), c1 = bf2f(pc.x >> 16);
  float c2 = bf2f(pc.y & 0xffffu), c3 = bf2f(pc.y >> 16);
  float acc = 0.f;
  if (j0 + 0 <= i) acc += c0 * m.x;
  if (j0 + 1 <= i) acc += c1 * m.y;
  if (j0 + 2 <= i) acc += c2 * m.z;
  if (j0 + 3 <= i) acc += c3 * m.w;
  float ssq = blockSum(acc, red);
  if (t == 0) scl[b * 1024 + i] = (ssq / (1.f + ssq)) / sqrtf(ssq + SQ_EPS);
}

// it=0 coupling.  Grid (1024, 4).
__global__ __launch_bounds__(256) void softmax_uniform_kernel(
    unsigned short* __restrict__ cH16a) {
  int i = blockIdx.x;
  int b = blockIdx.y;
  unsigned short* cH16 = cH16a + (long long)b * 1048576;
  int t = (int)threadIdx.x, k0 = t * 4;
  unsigned short c = f2bf(1.f / (float)(i + 1));
  unsigned short e0 = (k0 + 0) <= i ? c : (unsigned short)0;
  unsigned short e1 = (k0 + 1) <= i ? c : (unsigned short)0;
  unsigned short e2 = (k0 + 2) <= i ? c : (unsigned short)0;
  unsigned short e3 = (k0 + 3) <= i ? c : (unsigned short)0;
  uint2 o = {(unsigned int)e0 | ((unsigned int)e1 << 16),
             (unsigned int)e2 | ((unsigned int)e3 << 16)};
  *(uint2*)&cH16[(long long)i * 1024 + k0] = o;
}

// ---------------------------------------------------------------------------
// Final v (z-batched) — round-9 verbatim.  Grid (64, 8, 4).
// ---------------------------------------------------------------------------
__global__ __launch_bounds__(256) void gemm_s_scl(
    const unsigned short* __restrict__ Ca, const unsigned short* __restrict__ BTa,
    const float* __restrict__ scla, unsigned short* __restrict__ Ca_out) {
  __shared__ unsigned short Alds[128][32];
  __shared__ unsigned short Blds[128][32];
  int b = blockIdx.z;
  const unsigned short* Abf = Ca + (long long)b * 1048576;
  const unsigned short* BT = BTa + (long long)b * 8388608;
  const float* scl = scla + b * 1024;
  unsigned short* Cout = Ca_out + (long long)b * 8388608;
  int rowblk = 7 - (int)blockIdx.y;
  int row0 = rowblk * 128;
  int col0 = blockIdx.x * 128;
  int t = (int)threadIdx.x, lane = t & 63, wave = t >> 6;
  int wm = wave >> 1, wn = wave & 1;
  int Kend = row0 + 128;

  f32x4 acc[4][4];
#pragma unroll
  for (int i = 0; i < 4; i++)
#pragma unroll
    for (int j = 0; j < 4; j++) acc[i][j] = (f32x4){0.f, 0.f, 0.f, 0.f};

  int ar = t >> 2;
  int aq = (t & 3) * 8;

  for (int kb = 0; kb < Kend; kb += 32) {
    i32x4 a0 = *(const i32x4*)&Abf[(long long)(row0 + ar) * 1024 + kb + aq];
    i32x4 a1 = *(const i32x4*)&Abf[(long long)(row0 + ar + 64) * 1024 + kb + aq];
    i32x4 b0 = *(const i32x4*)&BT[(long long)(col0 + ar) * 1024 + kb + aq];
    i32x4 b1 = *(const i32x4*)&BT[(long long)(col0 + ar + 64) * 1024 + kb + aq];
    __syncthreads();
    *(i32x4*)&Alds[ar][aq] = a0;
    *(i32x4*)&Alds[ar + 64][aq] = a1;
    *(i32x4*)&Blds[ar][aq] = b0;
    *(i32x4*)&Blds[ar + 64][aq] = b1;
    __syncthreads();

    int rr = lane & 15, koff = (lane >> 4) * 8;
    i32x4 af[4], bfv[4];
#pragma unroll
    for (int fm = 0; fm < 4; fm++)
      af[fm] = *(i32x4*)&Alds[wm * 64 + fm * 16 + rr][koff];
#pragma unroll
    for (int fn = 0; fn < 4; fn++)
      bfv[fn] = *(i32x4*)&Blds[wn * 64 + fn * 16 + rr][koff];
#pragma unroll
    for (int fm = 0; fm < 4; fm++)
#pragma unroll
      for (int fn = 0; fn < 4; fn++)
        acc[fm][fn] = mfma_bf16(af[fm], bfv[fn], acc[fm][fn]);
  }

  int rq = lane >> 4, rr = lane & 15;
#pragma unroll
  for (int fm = 0; fm < 4; fm++) {
#pragma unroll
    for (int fn = 0; fn < 4; fn++) {
      int col = col0 + wn * 64 + fn * 16 + rr;
#pragma unroll
      for (int r = 0; r < 4; r++) {
        int row = row0 + wm * 64 + fm * 16 + rq * 4 + r;
        Cout[(long long)row * 8192 + col] = f2bf(scl[row] * acc[fm][fn][r]);
      }
    }
  }
}

// ---------------------------------------------------------------------------
// ctx (bf16 MFMA), stores bf16.  Grid (64, 8).
// ---------------------------------------------------------------------------
__global__ __launch_bounds__(256) void gemm_ctx_bf16(
    const unsigned short* __restrict__ w16,
    const unsigned short* __restrict__ VTa, unsigned short* __restrict__ ctx16) {
  int row0 = blockIdx.x * 64;             // global row in [0, 4096)
  int b = blockIdx.x >> 4;
  int h = blockIdx.y;
  const unsigned short* VT = VTa + (long long)b * 524288;
  __shared__ unsigned short Asl[64][68];
  __shared__ unsigned short Bsl[64][68];
  int t = (int)threadIdx.x, lane = t & 63, wave = t >> 6;

  f32x4 acc[4];
#pragma unroll
  for (int i = 0; i < 4; i++) acc[i] = (f32x4){0.f, 0.f, 0.f, 0.f};

  int r = t >> 2, kq = (t & 3) * 8;
  const unsigned short* Ap = w16 + (long long)(row0 + r) * 8192 + h * 1024 + kq;
  const unsigned short* Bp = VT + (long long)(h * 64 + r) * 1024 + kq;

  for (int kb = 0; kb < 1024; kb += 64) {
    i32x4 a0 = *(const i32x4*)(Ap + kb);
    i32x4 a1 = *(const i32x4*)(Ap + kb + 32);
    i32x4 b0 = *(const i32x4*)(Bp + kb);
    i32x4 b1 = *(const i32x4*)(Bp + kb + 32);
    __syncthreads();
    *(i32x4*)&Asl[r][kq] = a0;
    *(i32x4*)&Asl[r][kq + 32] = a1;
    *(i32x4*)&Bsl[r][kq] = b0;
    *(i32x4*)&Bsl[r][kq + 32] = b1;
    __syncthreads();

    int rr = lane & 15, ko = (lane >> 4) * 8;
#pragma unroll
    for (int k2 = 0; k2 < 2; k2++) {
      i32x4 af = *(i32x4*)&Asl[wave * 16 + rr][k2 * 32 + ko];
#pragma unroll
      for (int fn = 0; fn < 4; fn++) {
        i32x4 bf = *(i32x4*)&Bsl[fn * 16 + rr][k2 * 32 + ko];
        acc[fn] = mfma_bf16(af, bf, acc[fn]);
      }
    }
  }

  int rq = lane >> 4, rr = lane & 15;
#pragma unroll
  for (int fn = 0; fn < 4; fn++) {
#pragma unroll
    for (int rl = 0; rl < 4; rl++) {
      int i = row0 + wave * 16 + rq * 4 + rl;
      ctx16[(long long)i * 512 + h * 64 + fn * 16 + rr] = f2bf(acc[fn][rl]);
    }
  }
}

// ---------------------------------------------------------------------------
// Vertical routing — round-9 verbatim.
// ---------------------------------------------------------------------------
__global__ __launch_bounds__(256) void vertical_routing_kernel(
    const unsigned short* __restrict__ u16, float* __restrict__ vV) {
  __shared__ float Ur[8 * 1024];
  __shared__ float red[4];
  __shared__ float red8[32];
  int bq = blockIdx.x;
  int t = (int)threadIdx.x;
  const unsigned short* Ub = u16 + (long long)bq * 8192;
#pragma unroll
  for (int r = 0; r < 8; r++) {
    uint2 p = *(const uint2*)&Ub[(t + 256 * r) * 4];
    Ur[(t + 256 * r) * 4 + 0] = bf2f(p.x & 0xffffu);
    Ur[(t + 256 * r) * 4 + 1] = bf2f(p.x >> 16);
    Ur[(t + 256 * r) * 4 + 2] = bf2f(p.y & 0xffffu);
    Ur[(t + 256 * r) * 4 + 3] = bf2f(p.y >> 16);
  }
  __syncthreads();

  float bh[8] = {0.f, 0.f, 0.f, 0.f, 0.f, 0.f, 0.f, 0.f};
  int k0 = t * 4;
  float4 v4 = {0.f, 0.f, 0.f, 0.f};
  for (int it = 0; it < 3; ++it) {
    float m = bh[0];
#pragma unroll
    for (int h = 1; h < 8; h++) m = fmaxf(m, bh[h]);
    float c[8], zz = 0.f;
#pragma unroll
    for (int h = 0; h < 8; h++) {
      c[h] = expf(bh[h] - m);
      zz += c[h];
    }
    float inv = 1.f / zz;
    float4 s4 = {0.f, 0.f, 0.f, 0.f};
#pragma unroll
    for (int h = 0; h < 8; h++) {
      float4 u = *(float4*)&Ur[h * 1024 + k0];
      float ch = c[h] * inv;
      s4.x = fmaf(ch, u.x, s4.x); s4.y = fmaf(ch, u.y, s4.y);
      s4.z = fmaf(ch, u.z, s4.z); s4.w = fmaf(ch, u.w, s4.w);
    }
    float sq =
        blockSum(s4.x * s4.x + s4.y * s4.y + s4.z * s4.z + s4.w * s4.w, red);
    float sc = (sq / (1.f + sq)) / sqrtf(sq + SQ_EPS);
    v4.x = sc * s4.x; v4.y = sc * s4.y; v4.z = sc * s4.z; v4.w = sc * s4.w;
    if (it < 2) {
      float p[8];
#pragma unroll
      for (int h = 0; h < 8; h++) {
        float4 u = *(float4*)&Ur[h * 1024 + k0];
        p[h] = u.x * v4.x + u.y * v4.y + u.z * v4.z + u.w * v4.w;
      }
      __syncthreads();
#pragma unroll
      for (int h = 0; h < 8; h++) {
        float w = wredSum(p[h]);
        if ((t & 63) == 0) red8[(t >> 6) * 8 + h] = w;
      }
      __syncthreads();
#pragma unroll
      for (int h = 0; h < 8; h++)
        bh[h] += red8[h] + red8[8 + h] + red8[16 + h] + red8[24 + h];
    }
  }
  *(float4*)&vV[(long long)bq * 1024 + k0] = v4;
}

// enhanced softmax — round-9 verbatim.
__global__ __launch_bounds__(256) void enh_softmax_kernel(
    unsigned short* __restrict__ u16, const float* __restrict__ vV,
    const unsigned short* __restrict__ v16) {
  __shared__ float red[4];
  int idx = blockIdx.x;  // B*Q*H
  int h = idx & 7;
  int bq = idx >> 3;
  unsigned short* Urow = u16 + (long long)bq * 8192 + h * 1024;
  const float* va = vV + (long long)bq * 1024;
  const unsigned short* vb = v16 + (long long)bq * 8192 + h * 1024;
  int t = (int)threadIdx.x, k0 = t * 4;
  uint2 pu = *(const uint2*)&Urow[k0];
  float4 a = *(const float4*)&va[k0];
  uint2 pb = *(const uint2*)&vb[k0];
  float x0 = bf2f(pu.x & 0xffffu) + a.x + bf2f(pb.x & 0xffffu);
  float x1 = bf2f(pu.x >> 16) + a.y + bf2f(pb.x >> 16);
  float x2 = bf2f(pu.y & 0xffffu) + a.z + bf2f(pb.y & 0xffffu);
  float x3 = bf2f(pu.y >> 16) + a.w + bf2f(pb.y >> 16);
  float mx = blockMax(fmaxf(fmaxf(x0, x1), fmaxf(x2, x3)), red);
  float e0 = expf(x0 - mx), e1 = expf(x1 - mx), e2 = expf(x2 - mx),
        e3 = expf(x3 - mx);
  float zz = blockSum(e0 + e1 + e2 + e3, red);
  float inv = 1.f / zz;
  uint2 o = {(unsigned int)f2bf(e0 * inv) | ((unsigned int)f2bf(e1 * inv) << 16),
             (unsigned int)f2bf(e2 * inv) | ((unsigned int)f2bf(e3 * inv) << 16)};
  *(uint2*)&Urow[k0] = o;
}

// ---------------------------------------------------------------------------
extern "C" void kernel_launch(void* const* d_in, const int* in_sizes, int n_in,
                              void* d_out, int out_size, void* d_ws,
                              size_t ws_size, hipStream_t stream) {
  (void)in_sizes; (void)n_in; (void)out_size; (void)ws_size;
  const float* x = (const float*)d_in[0];
  const float* Wq = (const float*)d_in[1];
  const float* bq = (const float*)d_in[2];
  const float* Wk = (const float*)d_in[3];
  const float* bk = (const float*)d_in[4];
  const float* Wv = (const float*)d_in[5];
  const float* bv = (const float*)d_in[6];
  const float* Wo = (const float*)d_in[7];
  const float* bo = (const float*)d_in[8];
  float* out = (float*)d_out;
  float* ws = (float*)d_ws;

  unsigned short* u16a = (unsigned short*)(ws);              // 16M fl
  unsigned short* uT16a = (unsigned short*)(ws + 16777216);  // 16M fl
  // OVR region @ 33554432 (16M fl), time-multiplexed:
  float* Qf = ws + 33554432;                                 // 2M
  float* Kf = ws + 35651584;                                 // 2M
  float* Pa = ws + 33554432;                                 // 16M (after scores)
  float* Mbufa = ws + 33554432;                              // 4M (after merge)
  unsigned short* sv16a = (unsigned short*)(ws + 33554432);  // 16M fl (at end)
  float* vVa = ws + 50331648;                                // 4M
  float* bHa = ws + 54525952;                                // 4M
  unsigned short* ctx16 = (unsigned short*)(ws + 54525952);  // overlays bHa
  unsigned short* cH16a = (unsigned short*)(ws + 58720256);  // 2M fl
  unsigned short* G16a = (unsigned short*)(ws + 60817408);   // 2M fl
  unsigned short* V16a = (unsigned short*)(ws + 62914560);   // 1M fl
  unsigned short* VT16a = (unsigned short*)(ws + 63963136);  // 1M fl
  unsigned short* WT16 = (unsigned short*)(ws + 65011712);   // 1M fl (4 W's)
  float* scl = ws + 66060288;                                // 4096
  // total 66,064,384 fl = 252.0 MiB

  // 1-3. prologue
  wtrans_kernel<<<dim3(8, 8, 4), 256, 0, stream>>>(Wq, Wk, Wv, Wo, WT16);
  gemm_qkv_mfma<<<dim3(8, 64, 3), 256, 0, stream>>>(x, WT16, bq, bk, bv, Qf,
                                                    Kf, V16a);
  transpose16_kernel<<<dim3(16, 8, 4), 256, 0, stream>>>(V16a, VT16a, 512,
                                                         1024, 524288, 524288);

  // 4. scores (dual-writes u and u^T), all batches
  gemm_scores_bf16<<<dim3(8, 8, 32), 256, 0, stream>>>(Qf, Kf, u16a, uT16a);

  // 5. vertical routing, all batches
  vertical_routing_kernel<<<dim3(4096), 256, 0, stream>>>(u16a, vVa);

  // 6. G = u·u^T (lower triangle, 128^2 tile, split-K=4); merge + mirror
  gemm_G128_bf16<<<dim3(8, 8, 16), 256, 0, stream>>>(u16a, Pa);
  merge_mirror_G_kernel<<<dim3(1024, 4), 256, 0, stream>>>(Pa, G16a);

  // 7. horizontal routing iterations (all batches per stage)
  softmax_uniform_kernel<<<dim3(1024, 4), 256, 0, stream>>>(cH16a);
  gemm_M_bf16<<<dim3(16, 16, 4), 256, 0, stream>>>(cH16a, G16a, Mbufa);
  fused_scl_bupd_kernel<1><<<dim3(1024, 4), 256, 0, stream>>>(bHa, Mbufa,
                                                              cH16a);
  gemm_M_bf16<<<dim3(16, 16, 4), 256, 0, stream>>>(cH16a, G16a, Mbufa);
  fused_scl_bupd_kernel<0><<<dim3(1024, 4), 256, 0, stream>>>(bHa, Mbufa,
                                                              cH16a);
  gemm_M_bf16<<<dim3(16, 16, 4), 256, 0, stream>>>(cH16a, G16a, Mbufa);
  scldot_kernel<<<dim3(1024, 4), 256, 0, stream>>>(Mbufa, cH16a, scl);

  // 8. final v = scl·(C·u)  (writes sv16a over dead Qf/Kf/Pa/Mbufa)
  gemm_s_scl<<<dim3(64, 8, 4), 256, 0, stream>>>(cH16a, uT16a, scl, sv16a);

  // 9. enhanced + softmax -> w into u16a
  enh_softmax_kernel<<<dim3(32768), 256, 0, stream>>>(u16a, vVa, sv16a);

  // 10. ctx = w x V (bf16 out, writes over dead bHa)
  gemm_ctx_bf16<<<dim3(64, 8), 256, 0, stream>>>(u16a, VT16a, ctx16);

  // 11. out = ctx16 x Wo + bo (bf16 MFMA)
  gemm_out_mfma<<<dim3(8, 64), 256, 0, stream>>>(ctx16, WT16 + 786432, bo,
                                                 out);
}

// Round 11
// 453.883 us; speedup vs baseline: 15.2839x; 1.0846x over previous
//
#include <hip/hip_runtime.h>
#include <math.h>

// ---------------------------------------------------------------------------
// CapsuleRoutingSelfAttention — round 11.
//   * final s factored: R = C·Q (causal), sv = scl·0.125·R·K^T per head
//     (kills gemm_s_scl, the uT dual-write, and the uT16a buffer)
//   * gemm_G: BK=64 + padded LDS [128][72] (conflict-free reads, 2x ILP)
//
// Workspace (float units), 65,540,096 fl = 250.1 MiB (ws = 256 MiB):
//   u16a  [4][1024][8192] bf16 @ 0
//   QT16  [4][512][1024]  bf16 @ 16777216   (1M fl)
//   R16   [4][1024][512]  bf16 @ 17825792   (1M fl)
//   K16   [4096][512]     bf16 @ 18874368   (1M fl)
//   OVR @ 33554432 (16M fl), time-multiplexed:
//     Qf (2M) | Kf @35651584 (2M)   [die after scores]
//     Pa (16M, G partials)          [after scores; die at merge]
//     Mbufa (4M)                    [after merge; dies after it2 scldot]
//     sv16a bf16 (16M fl)           [written by sfinal at the end]
//   vVa @50331648 (4M) | bHa @54525952 (4M); ctx16 bf16 overlays bHa
//   cH16a @58720256 (2M fl) | G16a @60817408 (2M fl)
//   V16a @62914560 (1M fl) | VT16a @63963136 (1M fl)
//   WT16 @65011712 (512K fl, 4 W^T) | scl @65536000 (4096)
// ---------------------------------------------------------------------------

#define SQ_EPS 1e-8f

typedef __attribute__((ext_vector_type(4))) int i32x4;    // 8 bf16
typedef __attribute__((ext_vector_type(4))) float f32x4;

__device__ __forceinline__ float bf2f(unsigned int u) {
  union { unsigned int i; float f; } x;
  x.i = u << 16;
  return x.f;
}
__device__ __forceinline__ unsigned short f2bf(float f) {
  union { float f; unsigned int i; } x;
  x.f = f;
  unsigned int r = x.i + 0x7fffu + ((x.i >> 16) & 1u);
  return (unsigned short)(r >> 16);
}
__device__ __forceinline__ int packbf(float a, float b) {
  return (int)((unsigned int)f2bf(a) | ((unsigned int)f2bf(b) << 16));
}

__device__ __forceinline__ f32x4 mfma_bf16(i32x4 a, i32x4 b, f32x4 c) {
  asm("v_mfma_f32_16x16x32_bf16 %0, %1, %2, %0" : "+v"(c) : "v"(a), "v"(b));
  return c;
}

__device__ __forceinline__ float wredSum(float v) {
#pragma unroll
  for (int off = 32; off > 0; off >>= 1) v += __shfl_xor(v, off);
  return v;
}
__device__ __forceinline__ float wredMax(float v) {
#pragma unroll
  for (int off = 32; off > 0; off >>= 1) v = fmaxf(v, __shfl_xor(v, off));
  return v;
}
__device__ __forceinline__ float blockSum(float v, volatile float* red) {
  v = wredSum(v);
  int wid = threadIdx.x >> 6;
  __syncthreads();
  if ((threadIdx.x & 63) == 0) red[wid] = v;
  __syncthreads();
  return red[0] + red[1] + red[2] + red[3];
}
__device__ __forceinline__ float blockMax(float v, volatile float* red) {
  v = wredMax(v);
  int wid = threadIdx.x >> 6;
  __syncthreads();
  if ((threadIdx.x & 63) == 0) red[wid] = v;
  __syncthreads();
  return fmaxf(fmaxf(red[0], red[1]), fmaxf(red[2], red[3]));
}

// ---------------------------------------------------------------------------
// W^T prep (Wq,Wk,Wv,Wo) — round-10 verbatim.  Grid (8, 8, 4).
// ---------------------------------------------------------------------------
__global__ __launch_bounds__(256) void wtrans_kernel(
    const float* __restrict__ Wq, const float* __restrict__ Wk,
    const float* __restrict__ Wv, const float* __restrict__ Wo,
    unsigned short* __restrict__ WT16) {
  __shared__ unsigned short T[64][72];
  int z = blockIdx.z;
  const float* src = (z == 0) ? Wq : (z == 1) ? Wk : (z == 2) ? Wv : Wo;
  unsigned short* dst = WT16 + (long long)z * 262144;
  int i0 = blockIdx.x * 64;
  int c0 = blockIdx.y * 64;
  int t = (int)threadIdx.x;
  int r = t >> 2, cq = (t & 3) * 16;
#pragma unroll
  for (int j = 0; j < 4; j++) {
    float4 v = *(const float4*)&src[(long long)(i0 + r) * 512 + c0 + cq + j * 4];
    T[r][cq + j * 4 + 0] = f2bf(v.x);
    T[r][cq + j * 4 + 1] = f2bf(v.y);
    T[r][cq + j * 4 + 2] = f2bf(v.z);
    T[r][cq + j * 4 + 3] = f2bf(v.w);
  }
  __syncthreads();
  int c = t >> 2, iq = (t & 3) * 16;
  unsigned short tmp[16];
#pragma unroll
  for (int j = 0; j < 16; j++) tmp[j] = T[iq + j][c];
  *(i32x4*)&dst[(long long)(c0 + c) * 512 + i0 + iq] = *(i32x4*)&tmp[0];
  *(i32x4*)&dst[(long long)(c0 + c) * 512 + i0 + iq + 8] = *(i32x4*)&tmp[8];
}

// ---------------------------------------------------------------------------
// QKV (bf16 MFMA, all batches) — round-10 + K16 bf16 dual-write at z==1.
// ---------------------------------------------------------------------------
__global__ __launch_bounds__(256) void gemm_qkv_mfma(
    const float* __restrict__ x, const unsigned short* __restrict__ WT16,
    const float* __restrict__ bq, const float* __restrict__ bk,
    const float* __restrict__ bv, float* __restrict__ Qf,
    float* __restrict__ Kf, unsigned short* __restrict__ K16,
    unsigned short* __restrict__ V16) {
  __shared__ unsigned short Asl[64][68];
  __shared__ unsigned short Bsl[64][68];
  int z = blockIdx.z;
  const unsigned short* WT = WT16 + (long long)z * 262144;
  const float* bias = (z == 0) ? bq : (z == 1) ? bk : bv;

  int row0 = blockIdx.y * 64;
  int col0 = blockIdx.x * 64;
  int t = (int)threadIdx.x, lane = t & 63, wave = t >> 6;
  int wm = wave >> 1, wn = wave & 1;

  f32x4 acc[2][2];
#pragma unroll
  for (int i = 0; i < 2; i++)
#pragma unroll
    for (int j = 0; j < 2; j++) acc[i][j] = (f32x4){0.f, 0.f, 0.f, 0.f};

  int r = t >> 2, kq = (t & 3) * 8;
  const float* Ap = x + (long long)(row0 + r) * 512 + kq;
  const unsigned short* Bp = WT + (long long)(col0 + r) * 512 + kq;

  for (int kb = 0; kb < 512; kb += 64) {
    float4 a0 = *(const float4*)(Ap + kb);
    float4 a1 = *(const float4*)(Ap + kb + 4);
    float4 a2 = *(const float4*)(Ap + kb + 32);
    float4 a3 = *(const float4*)(Ap + kb + 36);
    i32x4 b0 = *(const i32x4*)(Bp + kb);
    i32x4 b1 = *(const i32x4*)(Bp + kb + 32);
    __syncthreads();
    i32x4 pa0 = {packbf(a0.x, a0.y), packbf(a0.z, a0.w), packbf(a1.x, a1.y),
                 packbf(a1.z, a1.w)};
    i32x4 pa1 = {packbf(a2.x, a2.y), packbf(a2.z, a2.w), packbf(a3.x, a3.y),
                 packbf(a3.z, a3.w)};
    *(i32x4*)&Asl[r][kq] = pa0;
    *(i32x4*)&Asl[r][kq + 32] = pa1;
    *(i32x4*)&Bsl[r][kq] = b0;
    *(i32x4*)&Bsl[r][kq + 32] = b1;
    __syncthreads();

    int rr = lane & 15, ko = (lane >> 4) * 8;
#pragma unroll
    for (int k2 = 0; k2 < 2; k2++) {
      i32x4 af0 = *(i32x4*)&Asl[wm * 32 + rr][k2 * 32 + ko];
      i32x4 af1 = *(i32x4*)&Asl[wm * 32 + 16 + rr][k2 * 32 + ko];
      i32x4 bf0 = *(i32x4*)&Bsl[wn * 32 + rr][k2 * 32 + ko];
      i32x4 bf1 = *(i32x4*)&Bsl[wn * 32 + 16 + rr][k2 * 32 + ko];
      acc[0][0] = mfma_bf16(af0, bf0, acc[0][0]);
      acc[0][1] = mfma_bf16(af0, bf1, acc[0][1]);
      acc[1][0] = mfma_bf16(af1, bf0, acc[1][0]);
      acc[1][1] = mfma_bf16(af1, bf1, acc[1][1]);
    }
  }

  int rq = lane >> 4, rr = lane & 15;
#pragma unroll
  for (int fm = 0; fm < 2; fm++) {
#pragma unroll
    for (int fn = 0; fn < 2; fn++) {
      int col = col0 + wn * 32 + fn * 16 + rr;
      float bb = bias[col];
#pragma unroll
      for (int rl = 0; rl < 4; rl++) {
        int row = row0 + wm * 32 + fm * 16 + rq * 4 + rl;
        float v = acc[fm][fn][rl] + bb;
        if (z == 2) {
          V16[(long long)row * 512 + col] = f2bf(v);
        } else if (z == 1) {
          Kf[(long long)row * 512 + col] = v;
          K16[(long long)row * 512 + col] = f2bf(v);
        } else {
          Qf[(long long)row * 512 + col] = v;
        }
      }
    }
  }
}

// ---------------------------------------------------------------------------
// Out-projection (bf16 MFMA) — round-10 verbatim.  Grid (8, 64).
// ---------------------------------------------------------------------------
__global__ __launch_bounds__(256) void gemm_out_mfma(
    const unsigned short* __restrict__ A16,   // ctx16 [4096,512]
    const unsigned short* __restrict__ WoT,   // [512,512] bf16 (n,k)
    const float* __restrict__ bo, float* __restrict__ out) {
  __shared__ unsigned short Asl[64][68];
  __shared__ unsigned short Bsl[64][68];
  int row0 = blockIdx.y * 64;
  int col0 = blockIdx.x * 64;
  int t = (int)threadIdx.x, lane = t & 63, wave = t >> 6;
  int wm = wave >> 1, wn = wave & 1;

  f32x4 acc[2][2];
#pragma unroll
  for (int i = 0; i < 2; i++)
#pragma unroll
    for (int j = 0; j < 2; j++) acc[i][j] = (f32x4){0.f, 0.f, 0.f, 0.f};

  int r = t >> 2, kq = (t & 3) * 8;
  const unsigned short* Ap = A16 + (long long)(row0 + r) * 512 + kq;
  const unsigned short* Bp = WoT + (long long)(col0 + r) * 512 + kq;

  for (int kb = 0; kb < 512; kb += 64) {
    i32x4 a0 = *(const i32x4*)(Ap + kb);
    i32x4 a1 = *(const i32x4*)(Ap + kb + 32);
    i32x4 b0 = *(const i32x4*)(Bp + kb);
    i32x4 b1 = *(const i32x4*)(Bp + kb + 32);
    __syncthreads();
    *(i32x4*)&Asl[r][kq] = a0;
    *(i32x4*)&Asl[r][kq + 32] = a1;
    *(i32x4*)&Bsl[r][kq] = b0;
    *(i32x4*)&Bsl[r][kq + 32] = b1;
    __syncthreads();

    int rr = lane & 15, ko = (lane >> 4) * 8;
#pragma unroll
    for (int k2 = 0; k2 < 2; k2++) {
      i32x4 af0 = *(i32x4*)&Asl[wm * 32 + rr][k2 * 32 + ko];
      i32x4 af1 = *(i32x4*)&Asl[wm * 32 + 16 + rr][k2 * 32 + ko];
      i32x4 bf0 = *(i32x4*)&Bsl[wn * 32 + rr][k2 * 32 + ko];
      i32x4 bf1 = *(i32x4*)&Bsl[wn * 32 + 16 + rr][k2 * 32 + ko];
      acc[0][0] = mfma_bf16(af0, bf0, acc[0][0]);
      acc[0][1] = mfma_bf16(af0, bf1, acc[0][1]);
      acc[1][0] = mfma_bf16(af1, bf0, acc[1][0]);
      acc[1][1] = mfma_bf16(af1, bf1, acc[1][1]);
    }
  }

  int rq = lane >> 4, rr = lane & 15;
#pragma unroll
  for (int fm = 0; fm < 2; fm++) {
#pragma unroll
    for (int fn = 0; fn < 2; fn++) {
      int col = col0 + wn * 32 + fn * 16 + rr;
      float bb = bo[col];
#pragma unroll
      for (int rl = 0; rl < 4; rl++) {
        int row = row0 + wm * 32 + fm * 16 + rq * 4 + rl;
        out[(long long)row * 512 + col] = acc[fm][fn][rl] + bb;
      }
    }
  }
}

// ---------------------------------------------------------------------------
// sv = scl·0.125·R·K^T per head (gemm_out mold, K=64 single-shot).
// Grid (16, 16, 32): z = b*8+h.
// ---------------------------------------------------------------------------
__global__ __launch_bounds__(256) void gemm_sfinal(
    const unsigned short* __restrict__ R16a,   // [4][1024,512]
    const unsigned short* __restrict__ K16a,   // [4][1024,512]
    const float* __restrict__ scla, unsigned short* __restrict__ sv16a) {
  __shared__ unsigned short Asl[64][68];
  __shared__ unsigned short Bsl[64][68];
  int z = blockIdx.z;
  int b = z >> 3, h = z & 7;
  const unsigned short* A16 = R16a + (long long)b * 524288;
  const unsigned short* Bm = K16a + (long long)b * 524288;
  const float* scl = scla + b * 1024;
  unsigned short* sv = sv16a + (long long)b * 8388608;
  int row0 = blockIdx.y * 64;
  int col0 = blockIdx.x * 64;
  int t = (int)threadIdx.x, lane = t & 63, wave = t >> 6;
  int wm = wave >> 1, wn = wave & 1;

  f32x4 acc[2][2];
#pragma unroll
  for (int i = 0; i < 2; i++)
#pragma unroll
    for (int j = 0; j < 2; j++) acc[i][j] = (f32x4){0.f, 0.f, 0.f, 0.f};

  int r = t >> 2, kq = (t & 3) * 8;
  const unsigned short* Ap = A16 + (long long)(row0 + r) * 512 + h * 64 + kq;
  const unsigned short* Bp = Bm + (long long)(col0 + r) * 512 + h * 64 + kq;

  for (int kb = 0; kb < 64; kb += 64) {
    i32x4 a0 = *(const i32x4*)(Ap + kb);
    i32x4 a1 = *(const i32x4*)(Ap + kb + 32);
    i32x4 b0 = *(const i32x4*)(Bp + kb);
    i32x4 b1 = *(const i32x4*)(Bp + kb + 32);
    __syncthreads();
    *(i32x4*)&Asl[r][kq] = a0;
    *(i32x4*)&Asl[r][kq + 32] = a1;
    *(i32x4*)&Bsl[r][kq] = b0;
    *(i32x4*)&Bsl[r][kq + 32] = b1;
    __syncthreads();

    int rr = lane & 15, ko = (lane >> 4) * 8;
#pragma unroll
    for (int k2 = 0; k2 < 2; k2++) {
      i32x4 af0 = *(i32x4*)&Asl[wm * 32 + rr][k2 * 32 + ko];
      i32x4 af1 = *(i32x4*)&Asl[wm * 32 + 16 + rr][k2 * 32 + ko];
      i32x4 bf0 = *(i32x4*)&Bsl[wn * 32 + rr][k2 * 32 + ko];
      i32x4 bf1 = *(i32x4*)&Bsl[wn * 32 + 16 + rr][k2 * 32 + ko];
      acc[0][0] = mfma_bf16(af0, bf0, acc[0][0]);
      acc[0][1] = mfma_bf16(af0, bf1, acc[0][1]);
      acc[1][0] = mfma_bf16(af1, bf0, acc[1][0]);
      acc[1][1] = mfma_bf16(af1, bf1, acc[1][1]);
    }
  }

  int rq = lane >> 4, rr = lane & 15;
#pragma unroll
  for (int fm = 0; fm < 2; fm++) {
#pragma unroll
    for (int fn = 0; fn < 2; fn++) {
      int col = col0 + wn * 32 + fn * 16 + rr;
#pragma unroll
      for (int rl = 0; rl < 4; rl++) {
        int row = row0 + wm * 32 + fm * 16 + rq * 4 + rl;
        sv[(long long)row * 8192 + h * 1024 + col] =
            f2bf(0.125f * scl[row] * acc[fm][fn][rl]);
      }
    }
  }
}

// ---------------------------------------------------------------------------
// Scores (fp32 compute, bf16 out) — round-10 minus the uT dual-write.
// Grid (8, 8, 32): z = b*8 + h.
// ---------------------------------------------------------------------------
__global__ __launch_bounds__(256) void gemm_scores_bf16(
    const float* __restrict__ Qf, const float* __restrict__ Kf,
    unsigned short* __restrict__ u16a) {
  __shared__ float As[8][132];
  __shared__ float Bs[8][132];
  int z = blockIdx.z;
  int b = z >> 3, h = z & 7;
  const float* A = Qf + (long long)b * 524288 + h * 64;
  const float* B = Kf + (long long)b * 524288 + h * 64;
  unsigned short* C16 = u16a + (long long)b * 8388608 + h * 1024;

  int row0 = blockIdx.y * 128;
  int col0 = blockIdx.x * 128;
  int tid = (int)threadIdx.x;
  int tx = tid & 15, ty = tid >> 4;
  int arow = tid >> 1;
  int akc = (tid & 1) * 4;

  float acc[8][8];
#pragma unroll
  for (int i = 0; i < 8; i++)
#pragma unroll
    for (int j = 0; j < 8; j++) acc[i][j] = 0.f;

  const float* Aptr = A + (long long)(row0 + arow) * 512 + akc;
  const float* Bptr = B + (long long)(col0 + arow) * 512 + akc;

  for (int kb = 0; kb < 64; kb += 8) {
    float4 av = *(const float4*)(Aptr + kb);
    float4 bv = *(const float4*)(Bptr + kb);
    __syncthreads();
    As[akc + 0][arow] = av.x; As[akc + 1][arow] = av.y;
    As[akc + 2][arow] = av.z; As[akc + 3][arow] = av.w;
    Bs[akc + 0][arow] = bv.x; Bs[akc + 1][arow] = bv.y;
    Bs[akc + 2][arow] = bv.z; Bs[akc + 3][arow] = bv.w;
    __syncthreads();

#pragma unroll
    for (int k = 0; k < 8; k++) {
      float a[8], b2[8];
#pragma unroll
      for (int c = 0; c < 2; c++) {
        float4 q = *(float4*)&As[k][ty * 8 + c * 4];
        a[c * 4 + 0] = q.x; a[c * 4 + 1] = q.y;
        a[c * 4 + 2] = q.z; a[c * 4 + 3] = q.w;
      }
#pragma unroll
      for (int c = 0; c < 2; c++) {
        float4 q = *(float4*)&Bs[k][c * 64 + tx * 4];
        b2[c * 4 + 0] = q.x; b2[c * 4 + 1] = q.y;
        b2[c * 4 + 2] = q.z; b2[c * 4 + 3] = q.w;
      }
#pragma unroll
      for (int i = 0; i < 8; i++)
#pragma unroll
        for (int j = 0; j < 8; j++) acc[i][j] = fmaf(a[i], b2[j], acc[i][j]);
    }
  }

#pragma unroll
  for (int i = 0; i < 8; i++) {
    long long r = row0 + ty * 8 + i;
#pragma unroll
    for (int c = 0; c < 2; c++) {
      int col = col0 + c * 64 + tx * 4;
      unsigned int lo = (unsigned int)f2bf(0.125f * acc[i][c * 4 + 0]) |
                        ((unsigned int)f2bf(0.125f * acc[i][c * 4 + 1]) << 16);
      unsigned int hi = (unsigned int)f2bf(0.125f * acc[i][c * 4 + 2]) |
                        ((unsigned int)f2bf(0.125f * acc[i][c * 4 + 3]) << 16);
      uint2 o = {lo, hi};
      *(uint2*)&C16[r * 8192 + col] = o;
    }
  }
}

// ---------------------------------------------------------------------------
// bf16 transpose (V), z-batched — round-10 verbatim.
// ---------------------------------------------------------------------------
__global__ __launch_bounds__(256) void transpose16_kernel(
    const unsigned short* __restrict__ src, unsigned short* __restrict__ dst,
    int ldS, int ldD, long long zsS, long long zsD) {
  __shared__ unsigned short T[64][72];
  src += (long long)blockIdx.z * zsS;
  dst += (long long)blockIdx.z * zsD;
  int i0 = blockIdx.x * 64;
  int c0 = blockIdx.y * 64;
  int t = (int)threadIdx.x;
  int r = t >> 2, cq = (t & 3) * 16;
  i32x4 v0 = *(const i32x4*)&src[(long long)(i0 + r) * ldS + c0 + cq];
  i32x4 v1 = *(const i32x4*)&src[(long long)(i0 + r) * ldS + c0 + cq + 8];
  *(i32x4*)&T[r][cq] = v0;
  *(i32x4*)&T[r][cq + 8] = v1;
  __syncthreads();
  int c = t >> 2, iq = (t & 3) * 16;
  unsigned short tmp[16];
#pragma unroll
  for (int j = 0; j < 16; j++) tmp[j] = T[iq + j][c];
  *(i32x4*)&dst[(long long)(c0 + c) * ldD + i0 + iq] = *(i32x4*)&tmp[0];
  *(i32x4*)&dst[(long long)(c0 + c) * ldD + i0 + iq + 8] = *(i32x4*)&tmp[8];
}

// f32 -> bf16 transpose (round-4-proven mold + z strides).  Grid (16, 8, 4).
__global__ __launch_bounds__(256) void transpose_f32_bf16_kernel(
    const float* __restrict__ src, unsigned short* __restrict__ dst,
    int ldS, int ldD, long long zsS, long long zsD) {
  __shared__ unsigned short T[64][72];
  src += (long long)blockIdx.z * zsS;
  dst += (long long)blockIdx.z * zsD;
  int i0 = blockIdx.x * 64;
  int c0 = blockIdx.y * 64;
  int t = (int)threadIdx.x;
  int r = t >> 2, cq = (t & 3) * 16;
#pragma unroll
  for (int j = 0; j < 4; j++) {
    float4 v = *(const float4*)&src[(long long)(i0 + r) * ldS + c0 + cq + j * 4];
    T[r][cq + j * 4 + 0] = f2bf(v.x);
    T[r][cq + j * 4 + 1] = f2bf(v.y);
    T[r][cq + j * 4 + 2] = f2bf(v.z);
    T[r][cq + j * 4 + 3] = f2bf(v.w);
  }
  __syncthreads();
  int c = t >> 2, iq = (t & 3) * 16;
  unsigned short tmp[16];
#pragma unroll
  for (int j = 0; j < 16; j++) tmp[j] = T[iq + j][c];
  *(i32x4*)&dst[(long long)(c0 + c) * ldD + i0 + iq] = *(i32x4*)&tmp[0];
  *(i32x4*)&dst[(long long)(c0 + c) * ldD + i0 + iq + 8] = *(i32x4*)&tmp[8];
}

// ---------------------------------------------------------------------------
// G = u·u^T lower triangle (bf16 MFMA, 128x128 tile, BK=64, split-K=4).
// Padded LDS [128][72] -> conflict-free b128 reads.  Grid (8, 8, 16).
// ---------------------------------------------------------------------------
__global__ __launch_bounds__(256) void gemm_G128_bf16(
    const unsigned short* __restrict__ U16a, float* __restrict__ P) {
  __shared__ unsigned short Alds[128][72];
  __shared__ unsigned short Blds[128][72];
  int row0 = blockIdx.y * 128;
  int col0 = blockIdx.x * 128;
  if (col0 > row0) return;
  int z = blockIdx.z;
  int b = z >> 2, ks = z & 3;
  const unsigned short* U = U16a + (long long)b * 8388608;
  int t = (int)threadIdx.x, lane = t & 63, wave = t >> 6;
  int wm = wave >> 1, wn = wave & 1;

  f32x4 acc[4][4];
#pragma unroll
  for (int i = 0; i < 4; i++)
#pragma unroll
    for (int j = 0; j < 4; j++) acc[i][j] = (f32x4){0.f, 0.f, 0.f, 0.f};

  int ar = t >> 2;           // 0..63
  int aq = (t & 3) * 16;     // 0, 16, 32, 48
  const unsigned short* Ap = U + (long long)(row0 + ar) * 8192 + ks * 2048 + aq;
  const unsigned short* Ap2 = Ap + 64LL * 8192;
  const unsigned short* Bp = U + (long long)(col0 + ar) * 8192 + ks * 2048 + aq;
  const unsigned short* Bp2 = Bp + 64LL * 8192;

  for (int kb = 0; kb < 2048; kb += 64) {
    i32x4 a0 = *(const i32x4*)(Ap + kb);
    i32x4 a1 = *(const i32x4*)(Ap + kb + 8);
    i32x4 a2 = *(const i32x4*)(Ap2 + kb);
    i32x4 a3 = *(const i32x4*)(Ap2 + kb + 8);
    i32x4 b0 = *(const i32x4*)(Bp + kb);
    i32x4 b1 = *(const i32x4*)(Bp + kb + 8);
    i32x4 b2 = *(const i32x4*)(Bp2 + kb);
    i32x4 b3 = *(const i32x4*)(Bp2 + kb + 8);
    __syncthreads();
    *(i32x4*)&Alds[ar][aq] = a0;
    *(i32x4*)&Alds[ar][aq + 8] = a1;
    *(i32x4*)&Alds[ar + 64][aq] = a2;
    *(i32x4*)&Alds[ar + 64][aq + 8] = a3;
    *(i32x4*)&Blds[ar][aq] = b0;
    *(i32x4*)&Blds[ar][aq + 8] = b1;
    *(i32x4*)&Blds[ar + 64][aq] = b2;
    *(i32x4*)&Blds[ar + 64][aq + 8] = b3;
    __syncthreads();

    int rr = lane & 15, ko = (lane >> 4) * 8;
#pragma unroll
    for (int k2 = 0; k2 < 2; k2++) {
      i32x4 af[4], bfv[4];
#pragma unroll
      for (int fm = 0; fm < 4; fm++)
        af[fm] = *(i32x4*)&Alds[wm * 64 + fm * 16 + rr][k2 * 32 + ko];
#pragma unroll
      for (int fn = 0; fn < 4; fn++)
        bfv[fn] = *(i32x4*)&Blds[wn * 64 + fn * 16 + rr][k2 * 32 + ko];
#pragma unroll
      for (int fm = 0; fm < 4; fm++)
#pragma unroll
        for (int fn = 0; fn < 4; fn++)
          acc[fm][fn] = mfma_bf16(af[fm], bfv[fn], acc[fm][fn]);
    }
  }

  float* dst = P + (long long)z * 1048576;
  int rq = lane >> 4, rr = lane & 15;
#pragma unroll
  for (int fm = 0; fm < 4; fm++) {
#pragma unroll
    for (int fn = 0; fn < 4; fn++) {
      int col = col0 + wn * 64 + fn * 16 + rr;
#pragma unroll
      for (int r = 0; r < 4; r++) {
        int row = row0 + wm * 64 + fm * 16 + rq * 4 + r;
        dst[(long long)row * 1024 + col] = acc[fm][fn][r];
      }
    }
  }
}

// G16 = bf16(sum_{ks} P[b*4+ks]), mirrored — round-10 verbatim. Grid (1024,4).
__global__ __launch_bounds__(256) void merge_mirror_G_kernel(
    const float* __restrict__ P, unsigned short* __restrict__ G16a) {
  int i = blockIdx.x;
  int b = blockIdx.y;
  int t = (int)threadIdx.x, j0 = t * 4;
  if (j0 > i) return;
  const float* Pb = P + (long long)(b * 4) * 1048576 + (long long)i * 1024;
  unsigned short* Gb = G16a + (long long)b * 1048576;
  float4 s = {0.f, 0.f, 0.f, 0.f};
#pragma unroll
  for (int z = 0; z < 4; z++) {
    float4 p = *(const float4*)&Pb[(long long)z * 1048576 + j0];
    s.x += p.x; s.y += p.y; s.z += p.z; s.w += p.w;
  }
  float v[4] = {s.x, s.y, s.z, s.w};
#pragma unroll
  for (int e = 0; e < 4; e++) {
    int j = j0 + e;
    if (j > i) break;
    unsigned short g = f2bf(v[e]);
    Gb[(long long)i * 1024 + j] = g;
    if (j < i) Gb[(long long)j * 1024 + i] = g;
  }
}

// ---------------------------------------------------------------------------
// M = C·G (bf16 MFMA, z-batched) — round-10 verbatim.
// ---------------------------------------------------------------------------
__global__ __launch_bounds__(256) void gemm_M_bf16(
    const unsigned short* __restrict__ Ca, const unsigned short* __restrict__ Ga,
    float* __restrict__ Ma) {
  int row0 = blockIdx.y * 64;
  int col0 = blockIdx.x * 64;
  if (col0 > row0) return;
  int b = blockIdx.z;
  const unsigned short* C = Ca + (long long)b * 1048576;
  const unsigned short* G = Ga + (long long)b * 1048576;
  float* M = Ma + (long long)b * 1048576;
  int Kend = row0 + 64;
  __shared__ unsigned short Asl[64][64];
  __shared__ unsigned short Bsl[64][64];
  int t = (int)threadIdx.x, lane = t & 63, wave = t >> 6;
  int wm = wave >> 1, wn = wave & 1;

  f32x4 acc[2][2];
#pragma unroll
  for (int i = 0; i < 2; i++)
#pragma unroll
    for (int j = 0; j < 2; j++) acc[i][j] = (f32x4){0.f, 0.f, 0.f, 0.f};

  int r = t >> 2, c0 = t & 3;
  int sw0 = ((c0 ^ (r & 7))) * 8;
  int sw1 = (((c0 + 4) ^ (r & 7))) * 8;
  const unsigned short* Ap = C + (long long)(row0 + r) * 1024 + c0 * 8;
  const unsigned short* Bp = G + (long long)(col0 + r) * 1024 + c0 * 8;

  for (int kb = 0; kb < Kend; kb += 64) {
    i32x4 a0 = *(const i32x4*)(Ap + kb);
    i32x4 a1 = *(const i32x4*)(Ap + kb + 32);
    i32x4 b0 = *(const i32x4*)(Bp + kb);
    i32x4 b1 = *(const i32x4*)(Bp + kb + 32);
    __syncthreads();
    *(i32x4*)&Asl[r][sw0] = a0;
    *(i32x4*)&Asl[r][sw1] = a1;
    *(i32x4*)&Bsl[r][sw0] = b0;
    *(i32x4*)&Bsl[r][sw1] = b1;
    __syncthreads();

    int rr = lane & 15, co = lane >> 4;
#pragma unroll
    for (int k2 = 0; k2 < 2; k2++) {
      int ch = ((k2 * 4 + co) ^ (rr & 7)) * 8;
      i32x4 af0 = *(i32x4*)&Asl[wm * 32 + rr][ch];
      i32x4 af1 = *(i32x4*)&Asl[wm * 32 + 16 + rr][ch];
      i32x4 bf0 = *(i32x4*)&Bsl[wn * 32 + rr][ch];
      i32x4 bf1 = *(i32x4*)&Bsl[wn * 32 + 16 + rr][ch];
      acc[0][0] = mfma_bf16(af0, bf0, acc[0][0]);
      acc[0][1] = mfma_bf16(af0, bf1, acc[0][1]);
      acc[1][0] = mfma_bf16(af1, bf0, acc[1][0]);
      acc[1][1] = mfma_bf16(af1, bf1, acc[1][1]);
    }
  }

  int rq = lane >> 4, rr = lane & 15;
#pragma unroll
  for (int fm = 0; fm < 2; fm++) {
#pragma unroll
    for (int fn = 0; fn < 2; fn++) {
      int j = col0 + wn * 32 + fn * 16 + rr;
#pragma unroll
      for (int rl = 0; rl < 4; rl++) {
        int i = row0 + wm * 32 + fm * 16 + rq * 4 + rl;
        M[(long long)i * 1024 + j] = acc[fm][fn][rl];
      }
    }
  }
}

// ---------------------------------------------------------------------------
// Fused scldot + b-update + causal softmax (it0/it1) — round-10 verbatim.
// ---------------------------------------------------------------------------
template <int INIT>
__global__ __launch_bounds__(256) void fused_scl_bupd_kernel(
    float* __restrict__ bHa, const float* __restrict__ Ma,
    unsigned short* __restrict__ cH16a) {
  __shared__ float red[4];
  int i = blockIdx.x;
  int b = blockIdx.y;
  float* bH = bHa + (long long)b * 1048576;
  const float* M = Ma + (long long)b * 1048576;
  unsigned short* cH16 = cH16a + (long long)b * 1048576;
  long long base = (long long)i * 1024;
  int t = (int)threadIdx.x, k0 = t * 4;
  float4 m = *(const float4*)&M[base + k0];
  uint2 pc = *(const uint2*)&cH16[base + k0];
  float c0 = bf2f(pc.x & 0xffffu), c1 = bf2f(pc.x >> 16);
  float c2 = bf2f(pc.y & 0xffffu), c3 = bf2f(pc.y >> 16);
  bool m0 = (k0 + 0) <= i, m1 = (k0 + 1) <= i, m2 = (k0 + 2) <= i,
       m3 = (k0 + 3) <= i;
  float acc = 0.f;
  if (m0) acc += c0 * m.x;
  if (m1) acc += c1 * m.y;
  if (m2) acc += c2 * m.z;
  if (m3) acc += c3 * m.w;
  float ssq = blockSum(acc, red);
  float sc = (ssq / (1.f + ssq)) / sqrtf(ssq + SQ_EPS);

  float4 x;
  if (INIT) x = (float4){0.f, 0.f, 0.f, 0.f};
  else x = *(const float4*)&bH[base + k0];
  if (m0) x.x += sc * m.x;
  if (m1) x.y += sc * m.y;
  if (m2) x.z += sc * m.z;
  if (m3) x.w += sc * m.w;
  *(float4*)&bH[base + k0] = x;
  float mx = -3.0e38f;
  if (m0) mx = fmaxf(mx, x.x);
  if (m1) mx = fmaxf(mx, x.y);
  if (m2) mx = fmaxf(mx, x.z);
  if (m3) mx = fmaxf(mx, x.w);
  mx = blockMax(mx, red);
  float e0 = m0 ? expf(x.x - mx) : 0.f;
  float e1 = m1 ? expf(x.y - mx) : 0.f;
  float e2 = m2 ? expf(x.z - mx) : 0.f;
  float e3 = m3 ? expf(x.w - mx) : 0.f;
  float zz = blockSum(e0 + e1 + e2 + e3, red);
  float inv = 1.f / zz;
  uint2 o = {(unsigned int)f2bf(e0 * inv) | ((unsigned int)f2bf(e1 * inv) << 16),
             (unsigned int)f2bf(e2 * inv) | ((unsigned int)f2bf(e3 * inv) << 16)};
  *(uint2*)&cH16[base + k0] = o;
}

// ||s_i||^2 -> scl (it2) — round-10 verbatim.  Grid (1024, 4).
__global__ __launch_bounds__(256) void scldot_kernel(
    const float* __restrict__ Ma, const unsigned short* __restrict__ Ca,
    float* __restrict__ scl) {
  __shared__ float red[4];
  int i = blockIdx.x;
  int b = blockIdx.y;
  const float* M = Ma + (long long)b * 1048576;
  const unsigned short* C = Ca + (long long)b * 1048576;
  int t = (int)threadIdx.x, j0 = t * 4;
  long long base = (long long)i * 1024;
  float4 m = *(const float4*)&M[base + j0];
  uint2 pc = *(const uint2*)&C[base + j0];
  float c0 = bf2f(pc.x & 0xffffu), c1 = bf2f(pc.x >> 16);
  float c2 = bf2f(pc.y & 0xffffu), c3 = bf2f(pc.y >> 16);
  float acc = 0.f;
  if (j0 + 0 <= i) acc += c0 * m.x;
  if (j0 + 1 <= i) acc += c1 * m.y;
  if (j0 + 2 <= i) acc += c2 * m.z;
  if (j0 + 3 <= i) acc += c3 * m.w;
  float ssq = blockSum(acc, red);
  if (t == 0) scl[b * 1024 + i] = (ssq / (1.f + ssq)) / sqrtf(ssq + SQ_EPS);
}

// it=0 coupling — round-10 verbatim.  Grid (1024, 4).
__global__ __launch_bounds__(256) void softmax_uniform_kernel(
    unsigned short* __restrict__ cH16a) {
  int i = blockIdx.x;
  int b = blockIdx.y;
  unsigned short* cH16 = cH16a + (long long)b * 1048576;
  int t = (int)threadIdx.x, k0 = t * 4;
  unsigned short c = f2bf(1.f / (float)(i + 1));
  unsigned short e0 = (k0 + 0) <= i ? c : (unsigned short)0;
  unsigned short e1 = (k0 + 1) <= i ? c : (unsigned short)0;
  unsigned short e2 = (k0 + 2) <= i ? c : (unsigned short)0;
  unsigned short e3 = (k0 + 3) <= i ? c : (unsigned short)0;
  uint2 o = {(unsigned int)e0 | ((unsigned int)e1 << 16),
             (unsigned int)e2 | ((unsigned int)e3 << 16)};
  *(uint2*)&cH16[(long long)i * 1024 + k0] = o;
}

// ---------------------------------------------------------------------------
// R = C·Q (causal): gemm_s mold, BT = QT16 [512,1024], N=512, out ld 512.
// Grid (4, 8, 4).
// ---------------------------------------------------------------------------
__global__ __launch_bounds__(256) void gemm_R_bf16(
    const unsigned short* __restrict__ Ca, const unsigned short* __restrict__ QTa,
    unsigned short* __restrict__ R16a) {
  __shared__ unsigned short Alds[128][32];
  __shared__ unsigned short Blds[128][32];
  int b = blockIdx.z;
  const unsigned short* Abf = Ca + (long long)b * 1048576;
  const unsigned short* BT = QTa + (long long)b * 524288;
  unsigned short* Cout = R16a + (long long)b * 524288;
  int rowblk = 7 - (int)blockIdx.y;
  int row0 = rowblk * 128;
  int col0 = blockIdx.x * 128;
  int t = (int)threadIdx.x, lane = t & 63, wave = t >> 6;
  int wm = wave >> 1, wn = wave & 1;
  int Kend = row0 + 128;

  f32x4 acc[4][4];
#pragma unroll
  for (int i = 0; i < 4; i++)
#pragma unroll
    for (int j = 0; j < 4; j++) acc[i][j] = (f32x4){0.f, 0.f, 0.f, 0.f};

  int ar = t >> 2;
  int aq = (t & 3) * 8;

  for (int kb = 0; kb < Kend; kb += 32) {
    i32x4 a0 = *(const i32x4*)&Abf[(long long)(row0 + ar) * 1024 + kb + aq];
    i32x4 a1 = *(const i32x4*)&Abf[(long long)(row0 + ar + 64) * 1024 + kb + aq];
    i32x4 b0 = *(const i32x4*)&BT[(long long)(col0 + ar) * 1024 + kb + aq];
    i32x4 b1 = *(const i32x4*)&BT[(long long)(col0 + ar + 64) * 1024 + kb + aq];
    __syncthreads();
    *(i32x4*)&Alds[ar][aq] = a0;
    *(i32x4*)&Alds[ar + 64][aq] = a1;
    *(i32x4*)&Blds[ar][aq] = b0;
    *(i32x4*)&Blds[ar + 64][aq] = b1;
    __syncthreads();

    int rr = lane & 15, koff = (lane >> 4) * 8;
    i32x4 af[4], bfv[4];
#pragma unroll
    for (int fm = 0; fm < 4; fm++)
      af[fm] = *(i32x4*)&Alds[wm * 64 + fm * 16 + rr][koff];
#pragma unroll
    for (int fn = 0; fn < 4; fn++)
      bfv[fn] = *(i32x4*)&Blds[wn * 64 + fn * 16 + rr][koff];
#pragma unroll
    for (int fm = 0; fm < 4; fm++)
#pragma unroll
      for (int fn = 0; fn < 4; fn++)
        acc[fm][fn] = mfma_bf16(af[fm], bfv[fn], acc[fm][fn]);
  }

  int rq = lane >> 4, rr = lane & 15;
#pragma unroll
  for (int fm = 0; fm < 4; fm++) {
#pragma unroll
    for (int fn = 0; fn < 4; fn++) {
      int col = col0 + wn * 64 + fn * 16 + rr;
#pragma unroll
      for (int r = 0; r < 4; r++) {
        int row = row0 + wm * 64 + fm * 16 + rq * 4 + r;
        Cout[(long long)row * 512 + col] = f2bf(acc[fm][fn][r]);
      }
    }
  }
}

// ---------------------------------------------------------------------------
// ctx (bf16 MFMA, bf16 out) — round-10 verbatim.  Grid (64, 8).
// ---------------------------------------------------------------------------
__global__ __launch_bounds__(256) void gemm_ctx_bf16(
    const unsigned short* __restrict__ w16,
    const unsigned short* __restrict__ VTa, unsigned short* __restrict__ ctx16) {
  int row0 = blockIdx.x * 64;
  int b = blockIdx.x >> 4;
  int h = blockIdx.y;
  const unsigned short* VT = VTa + (long long)b * 524288;
  __shared__ unsigned short Asl[64][68];
  __shared__ unsigned short Bsl[64][68];
  int t = (int)threadIdx.x, lane = t & 63, wave = t >> 6;

  f32x4 acc[4];
#pragma unroll
  for (int i = 0; i < 4; i++) acc[i] = (f32x4){0.f, 0.f, 0.f, 0.f};

  int r = t >> 2, kq = (t & 3) * 8;
  const unsigned short* Ap = w16 + (long long)(row0 + r) * 8192 + h * 1024 + kq;
  const unsigned short* Bp = VT + (long long)(h * 64 + r) * 1024 + kq;

  for (int kb = 0; kb < 1024; kb += 64) {
    i32x4 a0 = *(const i32x4*)(Ap + kb);
    i32x4 a1 = *(const i32x4*)(Ap + kb + 32);
    i32x4 b0 = *(const i32x4*)(Bp + kb);
    i32x4 b1 = *(const i32x4*)(Bp + kb + 32);
    __syncthreads();
    *(i32x4*)&Asl[r][kq] = a0;
    *(i32x4*)&Asl[r][kq + 32] = a1;
    *(i32x4*)&Bsl[r][kq] = b0;
    *(i32x4*)&Bsl[r][kq + 32] = b1;
    __syncthreads();

    int rr = lane & 15, ko = (lane >> 4) * 8;
#pragma unroll
    for (int k2 = 0; k2 < 2; k2++) {
      i32x4 af = *(i32x4*)&Asl[wave * 16 + rr][k2 * 32 + ko];
#pragma unroll
      for (int fn = 0; fn < 4; fn++) {
        i32x4 bf = *(i32x4*)&Bsl[fn * 16 + rr][k2 * 32 + ko];
        acc[fn] = mfma_bf16(af, bf, acc[fn]);
      }
    }
  }

  int rq = lane >> 4, rr = lane & 15;
#pragma unroll
  for (int fn = 0; fn < 4; fn++) {
#pragma unroll
    for (int rl = 0; rl < 4; rl++) {
      int i = row0 + wave * 16 + rq * 4 + rl;
      ctx16[(long long)i * 512 + h * 64 + fn * 16 + rr] = f2bf(acc[fn][rl]);
    }
  }
}

// ---------------------------------------------------------------------------
// Vertical routing — round-10 verbatim.  Grid 4096.
// ---------------------------------------------------------------------------
__global__ __launch_bounds__(256) void vertical_routing_kernel(
    const unsigned short* __restrict__ u16, float* __restrict__ vV) {
  __shared__ float Ur[8 * 1024];
  __shared__ float red[4];
  __shared__ float red8[32];
  int bq = blockIdx.x;
  int t = (int)threadIdx.x;
  const unsigned short* Ub = u16 + (long long)bq * 8192;
#pragma unroll
  for (int r = 0; r < 8; r++) {
    uint2 p = *(const uint2*)&Ub[(t + 256 * r) * 4];
    Ur[(t + 256 * r) * 4 + 0] = bf2f(p.x & 0xffffu);
    Ur[(t + 256 * r) * 4 + 1] = bf2f(p.x >> 16);
    Ur[(t + 256 * r) * 4 + 2] = bf2f(p.y & 0xffffu);
    Ur[(t + 256 * r) * 4 + 3] = bf2f(p.y >> 16);
  }
  __syncthreads();

  float bh[8] = {0.f, 0.f, 0.f, 0.f, 0.f, 0.f, 0.f, 0.f};
  int k0 = t * 4;
  float4 v4 = {0.f, 0.f, 0.f, 0.f};
  for (int it = 0; it < 3; ++it) {
    float m = bh[0];
#pragma unroll
    for (int h = 1; h < 8; h++) m = fmaxf(m, bh[h]);
    float c[8], zz = 0.f;
#pragma unroll
    for (int h = 0; h < 8; h++) {
      c[h] = expf(bh[h] - m);
      zz += c[h];
    }
    float inv = 1.f / zz;
    float4 s4 = {0.f, 0.f, 0.f, 0.f};
#pragma unroll
    for (int h = 0; h < 8; h++) {
      float4 u = *(float4*)&Ur[h * 1024 + k0];
      float ch = c[h] * inv;
      s4.x = fmaf(ch, u.x, s4.x); s4.y = fmaf(ch, u.y, s4.y);
      s4.z = fmaf(ch, u.z, s4.z); s4.w = fmaf(ch, u.w, s4.w);
    }
    float sq =
        blockSum(s4.x * s4.x + s4.y * s4.y + s4.z * s4.z + s4.w * s4.w, red);
    float sc = (sq / (1.f + sq)) / sqrtf(sq + SQ_EPS);
    v4.x = sc * s4.x; v4.y = sc * s4.y; v4.z = sc * s4.z; v4.w = sc * s4.w;
    if (it < 2) {
      float p[8];
#pragma unroll
      for (int h = 0; h < 8; h++) {
        float4 u = *(float4*)&Ur[h * 1024 + k0];
        p[h] = u.x * v4.x + u.y * v4.y + u.z * v4.z + u.w * v4.w;
      }
      __syncthreads();
#pragma unroll
      for (int h = 0; h < 8; h++) {
        float w = wredSum(p[h]);
        if ((t & 63) == 0) red8[(t >> 6) * 8 + h] = w;
      }
      __syncthreads();
#pragma unroll
      for (int h = 0; h < 8; h++)
        bh[h] += red8[h] + red8[8 + h] + red8[16 + h] + red8[24 + h];
    }
  }
  *(float4*)&vV[(long long)bq * 1024 + k0] = v4;
}

// enhanced softmax — round-10 verbatim.  Grid 32768.
__global__ __launch_bounds__(256) void enh_softmax_kernel(
    unsigned short* __restrict__ u16, const float* __restrict__ vV,
    const unsigned short* __restrict__ v16) {
  __shared__ float red[4];
  int idx = blockIdx.x;  // B*Q*H
  int h = idx & 7;
  int bq = idx >> 3;
  unsigned short* Urow = u16 + (long long)bq * 8192 + h * 1024;
  const float* va = vV + (long long)bq * 1024;
  const unsigned short* vb = v16 + (long long)bq * 8192 + h * 1024;
  int t = (int)threadIdx.x, k0 = t * 4;
  uint2 pu = *(const uint2*)&Urow[k0];
  float4 a = *(const float4*)&va[k0];
  uint2 pb = *(const uint2*)&vb[k0];
  float x0 = bf2f(pu.x & 0xffffu) + a.x + bf2f(pb.x & 0xffffu);
  float x1 = bf2f(pu.x >> 16) + a.y + bf2f(pb.x >> 16);
  float x2 = bf2f(pu.y & 0xffffu) + a.z + bf2f(pb.y & 0xffffu);
  float x3 = bf2f(pu.y >> 16) + a.w + bf2f(pb.y >> 16);
  float mx = blockMax(fmaxf(fmaxf(x0, x1), fmaxf(x2, x3)), red);
  float e0 = expf(x0 - mx), e1 = expf(x1 - mx), e2 = expf(x2 - mx),
        e3 = expf(x3 - mx);
  float zz = blockSum(e0 + e1 + e2 + e3, red);
  float inv = 1.f / zz;
  uint2 o = {(unsigned int)f2bf(e0 * inv) | ((unsigned int)f2bf(e1 * inv) << 16),
             (unsigned int)f2bf(e2 * inv) | ((unsigned int)f2bf(e3 * inv) << 16)};
  *(uint2*)&Urow[k0] = o;
}

// ---------------------------------------------------------------------------
extern "C" void kernel_launch(void* const* d_in, const int* in_sizes, int n_in,
                              void* d_out, int out_size, void* d_ws,
                              size_t ws_size, hipStream_t stream) {
  (void)in_sizes; (void)n_in; (void)out_size; (void)ws_size;
  const float* x = (const float*)d_in[0];
  const float* Wq = (const float*)d_in[1];
  const float* bq = (const float*)d_in[2];
  const float* Wk = (const float*)d_in[3];
  const float* bk = (const float*)d_in[4];
  const float* Wv = (const float*)d_in[5];
  const float* bv = (const float*)d_in[6];
  const float* Wo = (const float*)d_in[7];
  const float* bo = (const float*)d_in[8];
  float* out = (float*)d_out;
  float* ws = (float*)d_ws;

  unsigned short* u16a = (unsigned short*)(ws);              // 16M fl
  unsigned short* QT16 = (unsigned short*)(ws + 16777216);   // 1M fl
  unsigned short* R16 = (unsigned short*)(ws + 17825792);    // 1M fl
  unsigned short* K16 = (unsigned short*)(ws + 18874368);    // 1M fl
  // OVR region @ 33554432 (16M fl), time-multiplexed:
  float* Qf = ws + 33554432;                                 // 2M
  float* Kf = ws + 35651584;                                 // 2M
  float* Pa = ws + 33554432;                                 // 16M (after scores)
  float* Mbufa = ws + 33554432;                              // 4M (after merge)
  unsigned short* sv16a = (unsigned short*)(ws + 33554432);  // 16M fl (at end)
  float* vVa = ws + 50331648;                                // 4M
  float* bHa = ws + 54525952;                                // 4M
  unsigned short* ctx16 = (unsigned short*)(ws + 54525952);  // overlays bHa
  unsigned short* cH16a = (unsigned short*)(ws + 58720256);  // 2M fl
  unsigned short* G16a = (unsigned short*)(ws + 60817408);   // 2M fl
  unsigned short* V16a = (unsigned short*)(ws + 62914560);   // 1M fl
  unsigned short* VT16a = (unsigned short*)(ws + 63963136);  // 1M fl
  unsigned short* WT16 = (unsigned short*)(ws + 65011712);   // 512K fl
  float* scl = ws + 65536000;                                // 4096
  // total 65,540,096 fl = 250.1 MiB

  // 1-4. prologue
  wtrans_kernel<<<dim3(8, 8, 4), 256, 0, stream>>>(Wq, Wk, Wv, Wo, WT16);
  gemm_qkv_mfma<<<dim3(8, 64, 3), 256, 0, stream>>>(x, WT16, bq, bk, bv, Qf,
                                                    Kf, K16, V16a);
  transpose16_kernel<<<dim3(16, 8, 4), 256, 0, stream>>>(V16a, VT16a, 512,
                                                         1024, 524288, 524288);
  transpose_f32_bf16_kernel<<<dim3(16, 8, 4), 256, 0, stream>>>(
      Qf, QT16, 512, 1024, 524288, 524288);

  // 5. scores -> u16 only, all batches
  gemm_scores_bf16<<<dim3(8, 8, 32), 256, 0, stream>>>(Qf, Kf, u16a);

  // 6. vertical routing, all batches
  vertical_routing_kernel<<<dim3(4096), 256, 0, stream>>>(u16a, vVa);

  // 7. G = u·u^T (lower triangle, 128^2 tile, BK=64); merge + mirror
  gemm_G128_bf16<<<dim3(8, 8, 16), 256, 0, stream>>>(u16a, Pa);
  merge_mirror_G_kernel<<<dim3(1024, 4), 256, 0, stream>>>(Pa, G16a);

  // 8. horizontal routing iterations (all batches per stage)
  softmax_uniform_kernel<<<dim3(1024, 4), 256, 0, stream>>>(cH16a);
  gemm_M_bf16<<<dim3(16, 16, 4), 256, 0, stream>>>(cH16a, G16a, Mbufa);
  fused_scl_bupd_kernel<1><<<dim3(1024, 4), 256, 0, stream>>>(bHa, Mbufa,
                                                              cH16a);
  gemm_M_bf16<<<dim3(16, 16, 4), 256, 0, stream>>>(cH16a, G16a, Mbufa);
  fused_scl_bupd_kernel<0><<<dim3(1024, 4), 256, 0, stream>>>(bHa, Mbufa,
                                                              cH16a);
  gemm_M_bf16<<<dim3(16, 16, 4), 256, 0, stream>>>(cH16a, G16a, Mbufa);
  scldot_kernel<<<dim3(1024, 4), 256, 0, stream>>>(Mbufa, cH16a, scl);

  // 9. factored final s: R = C·Q (causal), sv = scl·0.125·R·K^T
  gemm_R_bf16<<<dim3(4, 8, 4), 256, 0, stream>>>(cH16a, QT16, R16);
  gemm_sfinal<<<dim3(16, 16, 32), 256, 0, stream>>>(R16, K16, scl, sv16a);

  // 10. enhanced + softmax -> w into u16a
  enh_softmax_kernel<<<dim3(32768), 256, 0, stream>>>(u16a, vVa, sv16a);

  // 11. ctx = w x V (bf16 out, writes over dead bHa)
  gemm_ctx_bf16<<<dim3(64, 8), 256, 0, stream>>>(u16a, VT16a, ctx16);

  // 12. out = ctx16 x Wo + bo (bf16 MFMA)
  gemm_out_mfma<<<dim3(8, 64), 256, 0, stream>>>(ctx16, WT16 + 786432, bo,
                                                 out);
}